// Round 11
// baseline (1495.690 us; speedup 1.0000x reference)
//
#include <hip/hip_runtime.h>
#include <hip/hip_bf16.h>
#include <math.h>

// Tree-LSTM "LogicEncoder": D=10, N=1023 nodes, B=128, LD=256, K=2.
// Round 11:
//  - Revert round-10's AST=34 (16B reads overlap at 17-dword stride -> 2x
//    bank conflicts, 394->474us). Back to AST=40, __launch_bounds__(256,2).
//  - NEW: pre-split activations to bf16x3 planes (split_x once for x_embed;
//    leaf/mfma epilogues emit h planes). Removes the ~200 VALU pack ops per
//    thread-iter from the hot loop (VALUBusy 34% ~= MfmaUtil 35% in r9) and
//    the 8x redundant per-gy re-splitting. c stays fp32 (bitwise-same math).
//  - Fallback ladder on ws_size: presplit -> r9 pack kernel -> fp32.

#define NNODES 1023
#define BATCH  128
#define LDIM   256

typedef __attribute__((ext_vector_type(8))) short short8;
typedef __attribute__((ext_vector_type(4))) float f32x4;

__device__ __forceinline__ float sigmoidf_(float x) {
    return 1.f / (1.f + expf(-x));
}

// fp32 -> 3x bf16, round-to-nearest-even at each stage; residuals exact.
__device__ __forceinline__ void split3(float x, ushort& h, ushort& m, ushort& l) {
    unsigned u = __float_as_uint(x);
    unsigned hu = (u + 0x7FFFu + ((u >> 16) & 1u)) & 0xFFFF0000u;
    h = (ushort)(hu >> 16);
    float r = x - __uint_as_float(hu);
    unsigned ur = __float_as_uint(r);
    unsigned mu = (ur + 0x7FFFu + ((ur >> 16) & 1u)) & 0xFFFF0000u;
    m = (ushort)(mu >> 16);
    float r2 = r - __uint_as_float(mu);
    unsigned u2 = __float_as_uint(r2);
    l = (ushort)((u2 + 0x7FFFu + ((u2 >> 16) & 1u)) >> 16);
}

// pair-split, BY-VALUE result (no reference outputs in hot paths)
struct P3 { unsigned h, m, l; };
__device__ __forceinline__ P3 pack2v(float x0, float x1) {
    ushort h0, m0, l0, h1, m1, l1;
    split3(x0, h0, m0, l0);
    split3(x1, h1, m1, l1);
    P3 r;
    r.h = (unsigned)h0 | ((unsigned)h1 << 16);
    r.m = (unsigned)m0 | ((unsigned)m1 << 16);
    r.l = (unsigned)l0 | ((unsigned)l1 << 16);
    return r;
}

// ---------------------------------------------------------------------------
// Pack Wbig (768x1024) + bias_big(1024) + Wleaf(256x512) + bias_leaf(512).
__global__ __launch_bounds__(256) void build_weights(
    const float* __restrict__ Wix, const float* __restrict__ bix,
    const float* __restrict__ Wfx, const float* __restrict__ bfx,
    const float* __restrict__ Wux, const float* __restrict__ bux,
    const float* __restrict__ Wi,  const float* __restrict__ bi,
    const float* __restrict__ Wf,  const float* __restrict__ bf,
    const float* __restrict__ Wu,  const float* __restrict__ bu,
    const float* __restrict__ Wcx, const float* __restrict__ bcx,
    const float* __restrict__ Wox, const float* __restrict__ box,
    float* __restrict__ Wbig, float* __restrict__ bias_big,
    float* __restrict__ Wleaf, float* __restrict__ bias_leaf)
{
    int i = blockIdx.x * blockDim.x + threadIdx.x;
    if (i < 768 * 1024) {
        int k = i >> 10, n = i & 1023;
        int g = n >> 8, nn = n & 255;
        float v;
        if (g == 0) {
            v = (k < 256) ? Wix[k * 256 + nn]
              : (k < 512) ? Wi[(k - 256) * 256 + nn]
                          : Wi[65536 + (k - 512) * 256 + nn];
        } else if (g == 1) {
            v = (k < 256) ? Wux[k * 256 + nn]
              : (k < 512) ? Wu[(k - 256) * 256 + nn]
                          : Wu[65536 + (k - 512) * 256 + nn];
        } else {
            int kf = g - 2;  // f0 / f1
            v = (k < 256) ? Wfx[k * 256 + nn]
              : (k < 512) ? Wf[((kf * 2 + 0) * 256 + (k - 256)) * 256 + nn]
                          : Wf[((kf * 2 + 1) * 256 + (k - 512)) * 256 + nn];
        }
        Wbig[i] = v;
        return;
    }
    i -= 768 * 1024;
    if (i < 1024) {
        int g = i >> 8, nn = i & 255;
        float v;
        if (g == 0)      v = bix[nn] + bi[nn] + bi[256 + nn];
        else if (g == 1) v = bux[nn] + bu[nn] + bu[256 + nn];
        else if (g == 2) v = bfx[nn] + bf[nn] + bf[256 + nn];
        else             v = bfx[nn] + bf[512 + nn] + bf[768 + nn];
        bias_big[i] = v;
        return;
    }
    i -= 1024;
    if (i < 256 * 512) {
        int k = i >> 9, n = i & 511;
        Wleaf[i] = (n < 256) ? Wcx[k * 256 + n] : Wox[k * 256 + (n - 256)];
        return;
    }
    i -= 256 * 512;
    if (i < 512) {
        bias_leaf[i] = (i < 256) ? bcx[i] : box[i - 256];
    }
}

// ---------------------------------------------------------------------------
// Split Wbig into 3 bf16 planes TRANSPOSED: Wt_s[n][k] (1024 x 768).
__global__ __launch_bounds__(256) void split_weights_T(
    const float* __restrict__ Wbig,
    ushort* __restrict__ Wth, ushort* __restrict__ Wtm, ushort* __restrict__ Wtl)
{
    __shared__ float sh[32][33];
    const int k0 = blockIdx.x * 32, n0 = blockIdx.y * 32;
    const int t = threadIdx.x;
    {
        int r = t >> 3, c4 = (t & 7) * 4;
        float4 v = *(const float4*)&Wbig[(size_t)(k0 + r) * 1024 + n0 + c4];
        sh[r][c4] = v.x; sh[r][c4 + 1] = v.y; sh[r][c4 + 2] = v.z; sh[r][c4 + 3] = v.w;
    }
    __syncthreads();
    int n = t >> 3, kc = (t & 7) * 4;
    ushort oh[4], om[4], ol[4];
#pragma unroll
    for (int j = 0; j < 4; ++j)
        split3(sh[kc + j][n], oh[j], om[j], ol[j]);
    size_t o = (size_t)(n0 + n) * 768 + k0 + kc;
    *(ushort4*)&Wth[o] = make_ushort4(oh[0], oh[1], oh[2], oh[3]);
    *(ushort4*)&Wtm[o] = make_ushort4(om[0], om[1], om[2], om[3]);
    *(ushort4*)&Wtl[o] = make_ushort4(ol[0], ol[1], ol[2], ol[3]);
}

// ---------------------------------------------------------------------------
// Split x_embed (nodes 0..510 only, node-major output) into 3 bf16 planes.
// xs_s[(node*128+b)*256+d]. grid 16352 blocks x 256 thr, 1 float4 each.
__global__ __launch_bounds__(256) void split_x(
    const float* __restrict__ x_embed,
    ushort* __restrict__ xs0, ushort* __restrict__ xs1, ushort* __restrict__ xs2)
{
    int q = blockIdx.x * 256 + threadIdx.x;
    if (q >= 511 * 128 * 64) return;
    int d4 = (q & 63) * 4;
    int b = (q >> 6) & 127;
    int node = q >> 13;
    float4 v = *(const float4*)&x_embed[((size_t)b * NNODES + node) * LDIM + d4];
    float vv[4] = {v.x, v.y, v.z, v.w};
    ushort sh[4], sm[4], sl[4];
#pragma unroll
    for (int j = 0; j < 4; ++j) split3(vv[j], sh[j], sm[j], sl[j]);
    size_t o = ((size_t)node * BATCH + b) * LDIM + d4;
    *(ushort4*)&xs0[o] = make_ushort4(sh[0], sh[1], sh[2], sh[3]);
    *(ushort4*)&xs1[o] = make_ushort4(sm[0], sm[1], sm[2], sm[3]);
    *(ushort4*)&xs2[o] = make_ushort4(sl[0], sl[1], sl[2], sl[3]);
}

// ---------------------------------------------------------------------------
// PRESPLIT bf16x3 MFMA level kernel: A=weights, B=activations (pre-split
// planes — no pack VALU in the loop). grid (W, 8), AST=40, 2 blocks/CU.
__global__ __launch_bounds__(256, 2) void mfma_level_ps(
    const ushort* __restrict__ xs0, const ushort* __restrict__ xs1,
    const ushort* __restrict__ xs2,
    const ushort* __restrict__ hi0, const ushort* __restrict__ hi1,
    const ushort* __restrict__ hi2,
    const float* __restrict__ cChild,
    const ushort* __restrict__ Wth, const ushort* __restrict__ Wtm,
    const ushort* __restrict__ Wtl,
    const float* __restrict__ bias,
    float* __restrict__ hOut,
    ushort* __restrict__ ho0, ushort* __restrict__ ho1, ushort* __restrict__ ho2,
    float* __restrict__ cOut, int nstart)
{
    constexpr int AST = 40;
    __shared__ __align__(16) ushort Wlds[3][128 * AST];
    __shared__ __align__(16) ushort Vlds[3][128 * AST];

    const int tid  = threadIdx.x;
    const int node = blockIdx.x;                  // fastest -> XCD-pinned node
    const int gy   = blockIdx.y;
    const int lane = tid & 63, wid = tid >> 6;
    const int ni = wid & 1, bw = wid >> 1;
    const int srow = tid & 127, shalf = tid >> 7;

    const size_t xoff = ((size_t)(nstart + node) * BATCH + srow) * LDIM;
    const size_t loff = ((size_t)(2 * node) * BATCH + srow) * LDIM;
    const size_t roff = loff + (size_t)BATCH * LDIM;
    const size_t nb = (size_t)(((srow >> 5) << 8) + gy * 32 + (srow & 31)) * 768;
    const ushort* w0 = Wth + nb;
    const ushort* w1 = Wtm + nb;
    const ushort* w2 = Wtl + nb;

    f32x4 acc[4][4];
#pragma unroll
    for (int g = 0; g < 4; ++g)
#pragma unroll
        for (int t2 = 0; t2 < 4; ++t2) acc[g][t2] = (f32x4){0.f, 0.f, 0.f, 0.f};

    // staging registers — named, never address-taken
    int4 v00, v01, v10, v11, v20, v21;
    int4 w00, w01, w10, w11, w20, w21;

#define TREE_LOADS(IT)                                                         \
    {                                                                          \
        const int seg_  = (IT) >> 3;                                           \
        const size_t o_ = (seg_ == 0 ? xoff : (seg_ == 1 ? loff : roff))       \
                          + ((IT) & 7) * 32 + shalf * 16;                      \
        const ushort* p0_ = (seg_ == 0) ? xs0 : hi0;                           \
        const ushort* p1_ = (seg_ == 0) ? xs1 : hi1;                           \
        const ushort* p2_ = (seg_ == 0) ? xs2 : hi2;                           \
        v00 = *(const int4*)(p0_ + o_); v01 = *(const int4*)(p0_ + o_ + 8);    \
        v10 = *(const int4*)(p1_ + o_); v11 = *(const int4*)(p1_ + o_ + 8);    \
        v20 = *(const int4*)(p2_ + o_); v21 = *(const int4*)(p2_ + o_ + 8);    \
        const int bko_ = (IT) * 32 + shalf * 16;                               \
        w00 = *(const int4*)(w0 + bko_); w01 = *(const int4*)(w0 + bko_ + 8);  \
        w10 = *(const int4*)(w1 + bko_); w11 = *(const int4*)(w1 + bko_ + 8);  \
        w20 = *(const int4*)(w2 + bko_); w21 = *(const int4*)(w2 + bko_ + 8);  \
    }

    TREE_LOADS(0);
    for (int it = 0; it < 24; ++it) {
        if (it) __syncthreads();
        {
            const int base = srow * AST + shalf * 16;
            *(int4*)&Vlds[0][base]     = v00;
            *(int4*)&Vlds[0][base + 8] = v01;
            *(int4*)&Vlds[1][base]     = v10;
            *(int4*)&Vlds[1][base + 8] = v11;
            *(int4*)&Vlds[2][base]     = v20;
            *(int4*)&Vlds[2][base + 8] = v21;
            *(int4*)&Wlds[0][base]     = w00;
            *(int4*)&Wlds[0][base + 8] = w01;
            *(int4*)&Wlds[1][base]     = w10;
            *(int4*)&Wlds[1][base + 8] = w11;
            *(int4*)&Wlds[2][base]     = w20;
            *(int4*)&Wlds[2][base + 8] = w21;
        }
        __syncthreads();
        if (it + 1 < 24) TREE_LOADS(it + 1);
        {
            short8 vf[4][3];
#pragma unroll
            for (int Nt = 0; Nt < 4; ++Nt) {
                const int rb = (bw * 64 + Nt * 16 + (lane & 15)) * AST + (lane >> 4) * 8;
#pragma unroll
                for (int s = 0; s < 3; ++s) vf[Nt][s] = *(const short8*)&Vlds[s][rb];
            }
#pragma unroll
            for (int g = 0; g < 4; ++g) {
                const int cb = (g * 32 + ni * 16 + (lane & 15)) * AST + (lane >> 4) * 8;
                short8 wh = *(const short8*)&Wlds[0][cb];
                short8 wm = *(const short8*)&Wlds[1][cb];
                short8 wl = *(const short8*)&Wlds[2][cb];
#pragma unroll
                for (int Nt = 0; Nt < 4; ++Nt)
                    acc[g][Nt] = __builtin_amdgcn_mfma_f32_16x16x32_bf16(wl, vf[Nt][0], acc[g][Nt], 0, 0, 0);
#pragma unroll
                for (int Nt = 0; Nt < 4; ++Nt)
                    acc[g][Nt] = __builtin_amdgcn_mfma_f32_16x16x32_bf16(wh, vf[Nt][2], acc[g][Nt], 0, 0, 0);
#pragma unroll
                for (int Nt = 0; Nt < 4; ++Nt)
                    acc[g][Nt] = __builtin_amdgcn_mfma_f32_16x16x32_bf16(wm, vf[Nt][1], acc[g][Nt], 0, 0, 0);
#pragma unroll
                for (int Nt = 0; Nt < 4; ++Nt)
                    acc[g][Nt] = __builtin_amdgcn_mfma_f32_16x16x32_bf16(wm, vf[Nt][0], acc[g][Nt], 0, 0, 0);
#pragma unroll
                for (int Nt = 0; Nt < 4; ++Nt)
                    acc[g][Nt] = __builtin_amdgcn_mfma_f32_16x16x32_bf16(wh, vf[Nt][1], acc[g][Nt], 0, 0, 0);
#pragma unroll
                for (int Nt = 0; Nt < 4; ++Nt)
                    acc[g][Nt] = __builtin_amdgcn_mfma_f32_16x16x32_bf16(wh, vf[Nt][0], acc[g][Nt], 0, 0, 0);
            }
        }
    }
#undef TREE_LOADS

    // ----- fused LSTM epilogue (fp32 c-path; writes fp32 h + h planes) -----
    const int nc = gy * 32 + ni * 16 + ((lane >> 4) << 2);
    const size_t cLb = (size_t)(2 * node) * BATCH * LDIM;
    const size_t cRb = cLb + (size_t)BATCH * LDIM;
    const size_t ob  = (size_t)node * BATCH * LDIM;
    const float4 bi4 = *(const float4*)&bias[nc];
    const float4 bu4 = *(const float4*)&bias[256 + nc];
    const float4 b04 = *(const float4*)&bias[512 + nc];
    const float4 b14 = *(const float4*)&bias[768 + nc];
    const float bi_[4] = {bi4.x, bi4.y, bi4.z, bi4.w};
    const float bu_[4] = {bu4.x, bu4.y, bu4.z, bu4.w};
    const float b0_[4] = {b04.x, b04.y, b04.z, b04.w};
    const float b1_[4] = {b14.x, b14.y, b14.z, b14.w};
#pragma unroll
    for (int Nt = 0; Nt < 4; ++Nt) {
        const int b = bw * 64 + Nt * 16 + (lane & 15);
        float4 cL = *(const float4*)&cChild[cLb + (size_t)b * LDIM + nc];
        float4 cR = *(const float4*)&cChild[cRb + (size_t)b * LDIM + nc];
        float cl4[4] = {cL.x, cL.y, cL.z, cL.w};
        float cr4[4] = {cR.x, cR.y, cR.z, cR.w};
        float4 c4, h4;
        float* cp = (float*)&c4; float* hp = (float*)&h4;
        ushort sh[4], sm[4], sl[4];
#pragma unroll
        for (int j = 0; j < 4; ++j) {
            float gi = sigmoidf_(acc[0][Nt][j] + bi_[j]);
            float gu = tanhf(acc[1][Nt][j] + bu_[j]);
            float f0 = acc[2][Nt][j] + b0_[j];
            float f1 = acc[3][Nt][j] + b1_[j];
            float c  = gi * gu + f0 * cl4[j] + f1 * cr4[j];
            float h  = tanhf(c);
            cp[j] = c;
            hp[j] = h;
            split3(h, sh[j], sm[j], sl[j]);
        }
        size_t po = ob + (size_t)b * LDIM + nc;
        *(float4*)&cOut[po] = c4;
        *(float4*)&hOut[po] = h4;
        *(ushort4*)&ho0[po] = make_ushort4(sh[0], sh[1], sh[2], sh[3]);
        *(ushort4*)&ho1[po] = make_ushort4(sm[0], sm[1], sm[2], sm[3]);
        *(ushort4*)&ho2[po] = make_ushort4(sl[0], sl[1], sl[2], sl[3]);
    }
}

// ---------------------------------------------------------------------------
// PACK bf16x3 MFMA level kernel (round-9 proven fallback: splits on the fly).
__global__ __launch_bounds__(256, 2) void mfma_level_pack(
    const float* __restrict__ x_embed,
    const float* __restrict__ hChild, const float* __restrict__ cChild,
    const ushort* __restrict__ Wth, const ushort* __restrict__ Wtm,
    const ushort* __restrict__ Wtl,
    const float* __restrict__ bias,
    float* __restrict__ hOut, float* __restrict__ cOut, int nstart)
{
    constexpr int AST = 40;
    __shared__ __align__(16) ushort Wlds[3][128 * AST];
    __shared__ __align__(16) ushort Vlds[3][128 * AST];

    const int tid  = threadIdx.x;
    const int node = blockIdx.x;
    const int gy   = blockIdx.y;
    const int lane = tid & 63, wid = tid >> 6;
    const int ni = wid & 1, bw = wid >> 1;
    const int srow = tid & 127, shalf = tid >> 7;

    const float* aX = x_embed + ((size_t)srow * NNODES + (nstart + node)) * LDIM;
    const float* aL = hChild + ((size_t)(2 * node) * BATCH + srow) * LDIM;
    const float* aR = aL + (size_t)BATCH * LDIM;
    const size_t nb = (size_t)(((srow >> 5) << 8) + gy * 32 + (srow & 31)) * 768;
    const ushort* w0 = Wth + nb;
    const ushort* w1 = Wtm + nb;
    const ushort* w2 = Wtl + nb;

    f32x4 acc[4][4];
#pragma unroll
    for (int g = 0; g < 4; ++g)
#pragma unroll
        for (int t2 = 0; t2 < 4; ++t2) acc[g][t2] = (f32x4){0.f, 0.f, 0.f, 0.f};

    float4 a0, a1, a2, a3;
    int4 w00, w01, w10, w11, w20, w21;

#define TREE_LOADS(IT)                                                         \
    {                                                                          \
        const int seg_  = (IT) >> 3;                                           \
        const int koff_ = ((IT) & 7) * 32 + shalf * 16;                        \
        const float* ap_ = (seg_ == 0) ? aX : (seg_ == 1) ? aL : aR;           \
        ap_ += koff_;                                                          \
        a0 = *(const float4*)(ap_);                                            \
        a1 = *(const float4*)(ap_ + 4);                                        \
        a2 = *(const float4*)(ap_ + 8);                                        \
        a3 = *(const float4*)(ap_ + 12);                                       \
        const int bko_ = (IT) * 32 + shalf * 16;                               \
        w00 = *(const int4*)(w0 + bko_); w01 = *(const int4*)(w0 + bko_ + 8);  \
        w10 = *(const int4*)(w1 + bko_); w11 = *(const int4*)(w1 + bko_ + 8);  \
        w20 = *(const int4*)(w2 + bko_); w21 = *(const int4*)(w2 + bko_ + 8);  \
    }

    TREE_LOADS(0);
    for (int it = 0; it < 24; ++it) {
        if (it) __syncthreads();
        {
            P3 p0 = pack2v(a0.x, a0.y), p1 = pack2v(a0.z, a0.w);
            P3 p2 = pack2v(a1.x, a1.y), p3 = pack2v(a1.z, a1.w);
            P3 p4 = pack2v(a2.x, a2.y), p5 = pack2v(a2.z, a2.w);
            P3 p6 = pack2v(a3.x, a3.y), p7 = pack2v(a3.z, a3.w);
            const int base = srow * AST + shalf * 16;
            *(int4*)&Vlds[0][base]     = make_int4((int)p0.h, (int)p1.h, (int)p2.h, (int)p3.h);
            *(int4*)&Vlds[0][base + 8] = make_int4((int)p4.h, (int)p5.h, (int)p6.h, (int)p7.h);
            *(int4*)&Vlds[1][base]     = make_int4((int)p0.m, (int)p1.m, (int)p2.m, (int)p3.m);
            *(int4*)&Vlds[1][base + 8] = make_int4((int)p4.m, (int)p5.m, (int)p6.m, (int)p7.m);
            *(int4*)&Vlds[2][base]     = make_int4((int)p0.l, (int)p1.l, (int)p2.l, (int)p3.l);
            *(int4*)&Vlds[2][base + 8] = make_int4((int)p4.l, (int)p5.l, (int)p6.l, (int)p7.l);
            *(int4*)&Wlds[0][base]     = w00;
            *(int4*)&Wlds[0][base + 8] = w01;
            *(int4*)&Wlds[1][base]     = w10;
            *(int4*)&Wlds[1][base + 8] = w11;
            *(int4*)&Wlds[2][base]     = w20;
            *(int4*)&Wlds[2][base + 8] = w21;
        }
        __syncthreads();
        if (it + 1 < 24) TREE_LOADS(it + 1);
        {
            short8 vf[4][3];
#pragma unroll
            for (int Nt = 0; Nt < 4; ++Nt) {
                const int rb = (bw * 64 + Nt * 16 + (lane & 15)) * AST + (lane >> 4) * 8;
#pragma unroll
                for (int s = 0; s < 3; ++s) vf[Nt][s] = *(const short8*)&Vlds[s][rb];
            }
#pragma unroll
            for (int g = 0; g < 4; ++g) {
                const int cb = (g * 32 + ni * 16 + (lane & 15)) * AST + (lane >> 4) * 8;
                short8 wh = *(const short8*)&Wlds[0][cb];
                short8 wm = *(const short8*)&Wlds[1][cb];
                short8 wl = *(const short8*)&Wlds[2][cb];
#pragma unroll
                for (int Nt = 0; Nt < 4; ++Nt)
                    acc[g][Nt] = __builtin_amdgcn_mfma_f32_16x16x32_bf16(wl, vf[Nt][0], acc[g][Nt], 0, 0, 0);
#pragma unroll
                for (int Nt = 0; Nt < 4; ++Nt)
                    acc[g][Nt] = __builtin_amdgcn_mfma_f32_16x16x32_bf16(wh, vf[Nt][2], acc[g][Nt], 0, 0, 0);
#pragma unroll
                for (int Nt = 0; Nt < 4; ++Nt)
                    acc[g][Nt] = __builtin_amdgcn_mfma_f32_16x16x32_bf16(wm, vf[Nt][1], acc[g][Nt], 0, 0, 0);
#pragma unroll
                for (int Nt = 0; Nt < 4; ++Nt)
                    acc[g][Nt] = __builtin_amdgcn_mfma_f32_16x16x32_bf16(wm, vf[Nt][0], acc[g][Nt], 0, 0, 0);
#pragma unroll
                for (int Nt = 0; Nt < 4; ++Nt)
                    acc[g][Nt] = __builtin_amdgcn_mfma_f32_16x16x32_bf16(wh, vf[Nt][1], acc[g][Nt], 0, 0, 0);
#pragma unroll
                for (int Nt = 0; Nt < 4; ++Nt)
                    acc[g][Nt] = __builtin_amdgcn_mfma_f32_16x16x32_bf16(wh, vf[Nt][0], acc[g][Nt], 0, 0, 0);
            }
        }
    }
#undef TREE_LOADS

    const int nc = gy * 32 + ni * 16 + ((lane >> 4) << 2);
    const size_t cLb = (size_t)(2 * node) * BATCH * LDIM;
    const size_t cRb = cLb + (size_t)BATCH * LDIM;
    const size_t ob  = (size_t)node * BATCH * LDIM;
    const float4 bi4 = *(const float4*)&bias[nc];
    const float4 bu4 = *(const float4*)&bias[256 + nc];
    const float4 b04 = *(const float4*)&bias[512 + nc];
    const float4 b14 = *(const float4*)&bias[768 + nc];
    const float bi_[4] = {bi4.x, bi4.y, bi4.z, bi4.w};
    const float bu_[4] = {bu4.x, bu4.y, bu4.z, bu4.w};
    const float b0_[4] = {b04.x, b04.y, b04.z, b04.w};
    const float b1_[4] = {b14.x, b14.y, b14.z, b14.w};
#pragma unroll
    for (int Nt = 0; Nt < 4; ++Nt) {
        const int b = bw * 64 + Nt * 16 + (lane & 15);
        float4 cL = *(const float4*)&cChild[cLb + (size_t)b * LDIM + nc];
        float4 cR = *(const float4*)&cChild[cRb + (size_t)b * LDIM + nc];
        float cl4[4] = {cL.x, cL.y, cL.z, cL.w};
        float cr4[4] = {cR.x, cR.y, cR.z, cR.w};
        float4 c4, h4;
        float* cp = (float*)&c4; float* hp = (float*)&h4;
#pragma unroll
        for (int j = 0; j < 4; ++j) {
            float gi = sigmoidf_(acc[0][Nt][j] + bi_[j]);
            float gu = tanhf(acc[1][Nt][j] + bu_[j]);
            float f0 = acc[2][Nt][j] + b0_[j];
            float f1 = acc[3][Nt][j] + b1_[j];
            float c  = gi * gu + f0 * cl4[j] + f1 * cr4[j];
            cp[j] = c;
            hp[j] = tanhf(c);
        }
        *(float4*)&cOut[ob + (size_t)b * LDIM + nc] = c4;
        *(float4*)&hOut[ob + (size_t)b * LDIM + nc] = h4;
    }
}

// ---------------------------------------------------------------------------
// Leaf kernel (round-1/4 proven) + optional h-plane emission. grid (1024, 4).
__global__ __launch_bounds__(256) void leaf_kernel(
    const float* __restrict__ x_embed,
    const float* __restrict__ Wleaf, const float* __restrict__ bias_leaf,
    float* __restrict__ hOut, float* __restrict__ cOut,
    ushort* __restrict__ hp0, ushort* __restrict__ hp1, ushort* __restrict__ hp2,
    int writePlanes)
{
    __shared__ float As[16 * 68];
    __shared__ float Bs[2 * 16 * 64];
    float acc[2][4][4] = {};
    const int tid = threadIdx.x;
    const int ty = tid >> 4, tx = tid & 15;
    const int row0 = blockIdx.x * 64;
    const int n0 = blockIdx.y * 64;
    const int w = row0 >> 7;
    const int ar = tid >> 2;
    const int kq = (tid & 3) * 4;
    const int b = (row0 + ar) & 127;
    const float* xrow = x_embed + ((size_t)b * NNODES + 511 + w) * LDIM;

    for (int k0 = 0; k0 < 256; k0 += 16) {
        float4 av = *(const float4*)(xrow + k0 + kq);
        As[(kq + 0) * 68 + ar] = av.x;
        As[(kq + 1) * 68 + ar] = av.y;
        As[(kq + 2) * 68 + ar] = av.z;
        As[(kq + 3) * 68 + ar] = av.w;
#pragma unroll
        for (int q = 0; q < 2; ++q) {
            int L = q * 256 + tid;
            int g = L >> 8, kk = (L >> 4) & 15, n4 = (L & 15) * 4;
            float4 bv = *(const float4*)(Wleaf + (size_t)(k0 + kk) * 512 + g * 256 + n0 + n4);
            *(float4*)&Bs[(g * 16 + kk) * 64 + n4] = bv;
        }
        __syncthreads();
#pragma unroll
        for (int kk = 0; kk < 16; ++kk) {
            float4 a = *(const float4*)&As[kk * 68 + ty * 4];
            float av4[4] = {a.x, a.y, a.z, a.w};
#pragma unroll
            for (int g = 0; g < 2; ++g) {
                float4 bb = *(const float4*)&Bs[(g * 16 + kk) * 64 + tx * 4];
                float bv4[4] = {bb.x, bb.y, bb.z, bb.w};
#pragma unroll
                for (int ii = 0; ii < 4; ++ii)
#pragma unroll
                    for (int jj = 0; jj < 4; ++jj)
                        acc[g][ii][jj] += av4[ii] * bv4[jj];
            }
        }
        __syncthreads();
    }
#pragma unroll
    for (int ii = 0; ii < 4; ++ii) {
        int r = row0 + ty * 4 + ii;
        int nc = n0 + tx * 4;
        float4 c4, h4;
        float* cp = (float*)&c4; float* hp = (float*)&h4;
        ushort sh[4], sm[4], sl[4];
#pragma unroll
        for (int jj = 0; jj < 4; ++jj) {
            int n = nc + jj;
            float ac = acc[0][ii][jj] + bias_leaf[n];
            float ao = acc[1][ii][jj] + bias_leaf[256 + n];
            float h = sigmoidf_(ao) * tanhf(ac);
            cp[jj] = ac;
            hp[jj] = h;
            split3(h, sh[jj], sm[jj], sl[jj]);
        }
        size_t po = (size_t)r * LDIM + nc;
        *(float4*)&cOut[po] = c4;
        *(float4*)&hOut[po] = h4;
        if (writePlanes) {
            *(ushort4*)&hp0[po] = make_ushort4(sh[0], sh[1], sh[2], sh[3]);
            *(ushort4*)&hp1[po] = make_ushort4(sm[0], sm[1], sm[2], sm[3]);
            *(ushort4*)&hp2[po] = make_ushort4(sl[0], sl[1], sl[2], sl[3]);
        }
    }
}

// ---------------------------------------------------------------------------
// fp32 level kernel (round-1/4 proven). grid (W*2, 4), block 256.
__global__ __launch_bounds__(256) void level_kernel(
    const float* __restrict__ x_embed,
    const float* __restrict__ hChild, const float* __restrict__ cChild,
    const float* __restrict__ Wbig, const float* __restrict__ bias_big,
    float* __restrict__ hOut, float* __restrict__ cOut,
    int nstart)
{
    __shared__ float As[16 * 68];
    __shared__ float Bs[4 * 16 * 64];
    float acc[4][4][4] = {};
    const int tid = threadIdx.x;
    const int ty = tid >> 4, tx = tid & 15;
    const int row0 = blockIdx.x * 64;
    const int n0 = blockIdx.y * 64;
    const int w = row0 >> 7;
    const int ar = tid >> 2;
    const int kq = (tid & 3) * 4;
    const int b = (row0 + ar) & 127;
    const float* srcX = x_embed + ((size_t)b * NNODES + nstart + w) * LDIM;
    const float* srcL = hChild + ((size_t)(2 * w) * BATCH + b) * LDIM;
    const float* srcR = hChild + ((size_t)(2 * w + 1) * BATCH + b) * LDIM;

    for (int k0 = 0; k0 < 768; k0 += 16) {
        int seg = k0 >> 8, off = k0 & 255;
        const float* src = (seg == 0) ? srcX : (seg == 1) ? srcL : srcR;
        float4 av = *(const float4*)(src + off + kq);
        As[(kq + 0) * 68 + ar] = av.x;
        As[(kq + 1) * 68 + ar] = av.y;
        As[(kq + 2) * 68 + ar] = av.z;
        As[(kq + 3) * 68 + ar] = av.w;
#pragma unroll
        for (int q = 0; q < 4; ++q) {
            int L = q * 256 + tid;
            int g = L >> 8, kk = (L >> 4) & 15, n4 = (L & 15) * 4;
            float4 bv = *(const float4*)(Wbig + (size_t)(k0 + kk) * 1024 + g * 256 + n0 + n4);
            *(float4*)&Bs[(g * 16 + kk) * 64 + n4] = bv;
        }
        __syncthreads();
#pragma unroll
        for (int kk = 0; kk < 16; ++kk) {
            float4 a = *(const float4*)&As[kk * 68 + ty * 4];
            float av4[4] = {a.x, a.y, a.z, a.w};
#pragma unroll
            for (int g = 0; g < 4; ++g) {
                float4 bb = *(const float4*)&Bs[(g * 16 + kk) * 64 + tx * 4];
                float bv4[4] = {bb.x, bb.y, bb.z, bb.w};
#pragma unroll
                for (int ii = 0; ii < 4; ++ii)
#pragma unroll
                    for (int jj = 0; jj < 4; ++jj)
                        acc[g][ii][jj] += av4[ii] * bv4[jj];
            }
        }
        __syncthreads();
    }
    const size_t cLbase = ((size_t)(2 * w) * BATCH) * LDIM;
    const size_t cRbase = ((size_t)(2 * w + 1) * BATCH) * LDIM;
#pragma unroll
    for (int ii = 0; ii < 4; ++ii) {
        int r = row0 + ty * 4 + ii;
        int bb2 = r & 127;
        int nc = n0 + tx * 4;
        float4 cL = *(const float4*)&cChild[cLbase + (size_t)bb2 * LDIM + nc];
        float4 cR = *(const float4*)&cChild[cRbase + (size_t)bb2 * LDIM + nc];
        float cl4[4] = {cL.x, cL.y, cL.z, cL.w};
        float cr4[4] = {cR.x, cR.y, cR.z, cR.w};
        float4 c4, h4;
        float* cp = (float*)&c4; float* hp = (float*)&h4;
#pragma unroll
        for (int jj = 0; jj < 4; ++jj) {
            int n = nc + jj;
            float gi = sigmoidf_(acc[0][ii][jj] + bias_big[n]);
            float gu = tanhf(acc[1][ii][jj] + bias_big[256 + n]);
            float f0 = acc[2][ii][jj] + bias_big[512 + n];
            float f1 = acc[3][ii][jj] + bias_big[768 + n];
            float c = gi * gu + f0 * cl4[jj] + f1 * cr4[jj];
            cp[jj] = c;
            hp[jj] = tanhf(c);
        }
        *(float4*)&cOut[(size_t)r * LDIM + nc] = c4;
        *(float4*)&hOut[(size_t)r * LDIM + nc] = h4;
    }
}

// ---------------------------------------------------------------------------
// Split-K partial (TM=4, one 256-wide K segment per blockIdx.z). grid (W*2,4,3).
__global__ __launch_bounds__(256) void gemm_part4(
    const float* __restrict__ x_embed, const float* __restrict__ hChild,
    const float* __restrict__ Wbig,
    float* __restrict__ part, int nstart, int rowsTotal)
{
    __shared__ float As[16 * 68];
    __shared__ float Bs[4 * 16 * 64];
    float acc[4][4][4] = {};
    const int tid = threadIdx.x;
    const int ty = tid >> 4, tx = tid & 15;
    const int row0 = blockIdx.x * 64;
    const int n0 = blockIdx.y * 64;
    const int seg = blockIdx.z;
    const int w = row0 >> 7;
    const int ar = tid >> 2;
    const int kq = (tid & 3) * 4;
    const int b = (row0 + ar) & 127;
    const float* src =
        (seg == 0) ? x_embed + ((size_t)b * NNODES + nstart + w) * LDIM
                   : hChild + ((size_t)(2 * w + (seg - 1)) * BATCH + b) * LDIM;

    for (int k0 = 0; k0 < 256; k0 += 16) {
        float4 av = *(const float4*)(src + k0 + kq);
        As[(kq + 0) * 68 + ar] = av.x;
        As[(kq + 1) * 68 + ar] = av.y;
        As[(kq + 2) * 68 + ar] = av.z;
        As[(kq + 3) * 68 + ar] = av.w;
#pragma unroll
        for (int q = 0; q < 4; ++q) {
            int L = q * 256 + tid;
            int g = L >> 8, kk = (L >> 4) & 15, n4 = (L & 15) * 4;
            float4 bv = *(const float4*)(Wbig + (size_t)(seg * 256 + k0 + kk) * 1024
                                         + g * 256 + n0 + n4);
            *(float4*)&Bs[(g * 16 + kk) * 64 + n4] = bv;
        }
        __syncthreads();
#pragma unroll
        for (int kk = 0; kk < 16; ++kk) {
            float4 a = *(const float4*)&As[kk * 68 + ty * 4];
            float av4[4] = {a.x, a.y, a.z, a.w};
#pragma unroll
            for (int g = 0; g < 4; ++g) {
                float4 bb = *(const float4*)&Bs[(g * 16 + kk) * 64 + tx * 4];
                float bv4[4] = {bb.x, bb.y, bb.z, bb.w};
#pragma unroll
                for (int ii = 0; ii < 4; ++ii)
#pragma unroll
                    for (int jj = 0; jj < 4; ++jj)
                        acc[g][ii][jj] += av4[ii] * bv4[jj];
            }
        }
        __syncthreads();
    }
#pragma unroll
    for (int ii = 0; ii < 4; ++ii) {
        int r = row0 + ty * 4 + ii;
        size_t base = ((size_t)seg * rowsTotal + r) * 1024 + n0 + tx * 4;
#pragma unroll
        for (int g = 0; g < 4; ++g)
            *(float4*)&part[base + g * 256] = *(float4*)acc[g][ii];
    }
}

// ---------------------------------------------------------------------------
// Combine 3 split-K partials + LSTM epilogue. grid (rows/4), block 256.
__global__ __launch_bounds__(256) void combine_eps(
    const float* __restrict__ part, const float* __restrict__ cChild,
    const float* __restrict__ bias,
    float* __restrict__ hOut, float* __restrict__ cOut, int rowsTotal)
{
    int idx = blockIdx.x * 256 + threadIdx.x;
    int row = idx >> 6, n = (idx & 63) * 4;
    size_t sseg = (size_t)rowsTotal * 1024;
    const float* p0 = part + (size_t)row * 1024 + n;
    float s[4][4];
#pragma unroll
    for (int g = 0; g < 4; ++g) {
        float4 a = *(const float4*)(p0 + g * 256);
        float4 b = *(const float4*)(p0 + sseg + g * 256);
        float4 c = *(const float4*)(p0 + 2 * sseg + g * 256);
        s[g][0] = a.x + b.x + c.x; s[g][1] = a.y + b.y + c.y;
        s[g][2] = a.z + b.z + c.z; s[g][3] = a.w + b.w + c.w;
    }
    int node = row >> 7, b = row & 127;
    float4 cL = *(const float4*)&cChild[((size_t)(2 * node) * BATCH + b) * LDIM + n];
    float4 cR = *(const float4*)&cChild[((size_t)(2 * node + 1) * BATCH + b) * LDIM + n];
    float cl4[4] = {cL.x, cL.y, cL.z, cL.w};
    float cr4[4] = {cR.x, cR.y, cR.z, cR.w};
    float4 c4, h4;
    float* cp = (float*)&c4; float* hp = (float*)&h4;
#pragma unroll
    for (int jj = 0; jj < 4; ++jj) {
        int nn = n + jj;
        float gi = sigmoidf_(s[0][jj] + bias[nn]);
        float gu = tanhf(s[1][jj] + bias[256 + nn]);
        float f0 = s[2][jj] + bias[512 + nn];
        float f1 = s[3][jj] + bias[768 + nn];
        float c = gi * gu + f0 * cl4[jj] + f1 * cr4[jj];
        cp[jj] = c;
        hp[jj] = tanhf(c);
    }
    *(float4*)&cOut[(size_t)row * LDIM + n] = c4;
    *(float4*)&hOut[(size_t)row * LDIM + n] = h4;
}

// ---------------------------------------------------------------------------
// Final: out[b][n] = tanh([init | c_root | h_root] @ Woend + boend). grid 128.
__global__ __launch_bounds__(256) void final_kernel(
    const float* __restrict__ init_emb,
    const float* __restrict__ cRoot, const float* __restrict__ hRoot,
    const float* __restrict__ Woend, const float* __restrict__ boend,
    float* __restrict__ out)
{
    __shared__ float sv[768];
    int b = blockIdx.x, t = threadIdx.x;
    sv[t]       = init_emb[(size_t)b * 256 + t];
    sv[256 + t] = cRoot[(size_t)b * 256 + t];
    sv[512 + t] = hRoot[(size_t)b * 256 + t];
    __syncthreads();
    float acc = boend[t];
#pragma unroll 4
    for (int d = 0; d < 768; ++d)
        acc += sv[d] * Woend[(size_t)d * 256 + t];
    out[(size_t)b * 256 + t] = tanhf(acc);
}

// ---------------------------------------------------------------------------
extern "C" void kernel_launch(void* const* d_in, const int* in_sizes, int n_in,
                              void* d_out, int out_size, void* d_ws, size_t ws_size,
                              hipStream_t stream)
{
    const float* x_embed  = (const float*)d_in[0];
    const float* init_emb = (const float*)d_in[1];
    const float* Wcx = (const float*)d_in[2];  const float* bcx = (const float*)d_in[3];
    const float* Wox = (const float*)d_in[4];  const float* box = (const float*)d_in[5];
    const float* Wix = (const float*)d_in[6];  const float* bix = (const float*)d_in[7];
    const float* Wfx = (const float*)d_in[8];  const float* bfx = (const float*)d_in[9];
    const float* Wux = (const float*)d_in[10]; const float* bux = (const float*)d_in[11];
    const float* Wi  = (const float*)d_in[12]; const float* bi  = (const float*)d_in[13];
    const float* Wf  = (const float*)d_in[14]; const float* bf  = (const float*)d_in[15];
    const float* Wu  = (const float*)d_in[16]; const float* bu  = (const float*)d_in[17];
    const float* Woend = (const float*)d_in[18]; const float* boend = (const float*)d_in[19];
    float* out = (float*)d_out;
    float* ws  = (float*)d_ws;

    size_t off = 0;
    float* hA = ws + off; off += (size_t)512 * 128 * 256;
    float* cA = ws + off; off += (size_t)512 * 128 * 256;
    float* hB = ws + off; off += (size_t)256 * 128 * 256;
    float* cB = ws + off; off += (size_t)256 * 128 * 256;
    float* Wbig      = ws + off; off += (size_t)768 * 1024;
    float* bias_big  = ws + off; off += 1024;
    float* Wleaf     = ws + off; off += (size_t)256 * 512;
    float* bias_leaf = ws + off; off += 512;
    // bf16 weight splits, transposed [n][k]
    ushort* Wth = (ushort*)(ws + off); off += (size_t)768 * 1024 / 2;
    ushort* Wtm = (ushort*)(ws + off); off += (size_t)768 * 1024 / 2;
    ushort* Wtl = (ushort*)(ws + off); off += (size_t)768 * 1024 / 2;
    size_t mfma_need = off * sizeof(float);
    // h planes (A: 512 nodes, B: 256 nodes) and x planes (nodes 0..510)
    const size_t hpa_sz = (size_t)512 * 128 * 256 / 2;  // floats per plane
    const size_t hpb_sz = (size_t)256 * 128 * 256 / 2;
    const size_t xs_sz  = (size_t)511 * 128 * 256 / 2;
    ushort* hpA[3]; ushort* hpB[3]; ushort* xs[3];
    for (int s = 0; s < 3; ++s) { hpA[s] = (ushort*)(ws + off); off += hpa_sz; }
    for (int s = 0; s < 3; ++s) { hpB[s] = (ushort*)(ws + off); off += hpb_sz; }
    for (int s = 0; s < 3; ++s) { xs[s]  = (ushort*)(ws + off); off += xs_sz; }
    size_t presplit_need = off * sizeof(float);
    size_t part_off = off;
    float* part = ws + part_off;

    bool presplit_ok = presplit_need <= ws_size;
    bool mfma_ok = mfma_need <= ws_size;

    {
        int total = 768 * 1024 + 1024 + 256 * 512 + 512;
        int blocks = (total + 255) / 256;
        build_weights<<<blocks, 256, 0, stream>>>(
            Wix, bix, Wfx, bfx, Wux, bux, Wi, bi, Wf, bf, Wu, bu,
            Wcx, bcx, Wox, box, Wbig, bias_big, Wleaf, bias_leaf);
    }
    if (mfma_ok) {
        split_weights_T<<<dim3(24, 32), 256, 0, stream>>>(Wbig, Wth, Wtm, Wtl);
    }
    if (presplit_ok) {
        split_x<<<(511 * 128 * 64 + 255) / 256, 256, 0, stream>>>(
            x_embed, xs[0], xs[1], xs[2]);
    }

    leaf_kernel<<<dim3(1024, 4), 256, 0, stream>>>(
        x_embed, Wleaf, bias_leaf, hA, cA,
        hpA[0], hpA[1], hpA[2], presplit_ok ? 1 : 0);

    float* hbufs[2] = {hA, hB};
    float* cbufs[2] = {cA, cB};
    ushort* hp0bufs[2] = {hpA[0], hpB[0]};
    ushort* hp1bufs[2] = {hpA[1], hpB[1]};
    ushort* hp2bufs[2] = {hpA[2], hpB[2]};
    int child = 0;  // leaves in A
    for (int lvl = 8; lvl >= 0; --lvl) {
        int W = 1 << lvl, s = W - 1;
        int outb = child ^ 1;
        size_t rows = (size_t)W * 128;
        bool split = (W <= 16) &&
                     ((part_off + 3 * rows * 1024) * sizeof(float) <= ws_size);
        if (lvl >= 5 && presplit_ok) {
            mfma_level_ps<<<dim3(W, 8), 256, 0, stream>>>(
                xs[0], xs[1], xs[2],
                hp0bufs[child], hp1bufs[child], hp2bufs[child],
                cbufs[child], Wth, Wtm, Wtl, bias_big,
                hbufs[outb], hp0bufs[outb], hp1bufs[outb], hp2bufs[outb],
                cbufs[outb], s);
        } else if (lvl >= 5 && mfma_ok) {
            mfma_level_pack<<<dim3(W, 8), 256, 0, stream>>>(
                x_embed, hbufs[child], cbufs[child], Wth, Wtm, Wtl, bias_big,
                hbufs[outb], cbufs[outb], s);
        } else if (split) {
            gemm_part4<<<dim3(W * 2, 4, 3), 256, 0, stream>>>(
                x_embed, hbufs[child], Wbig, part, s, (int)rows);
            combine_eps<<<(int)(rows / 4), 256, 0, stream>>>(
                part, cbufs[child], bias_big, hbufs[outb], cbufs[outb], (int)rows);
        } else {
            level_kernel<<<dim3(W * 2, 4), 256, 0, stream>>>(
                x_embed, hbufs[child], cbufs[child], Wbig, bias_big,
                hbufs[outb], cbufs[outb], s);
        }
        child = outb;
    }

    final_kernel<<<128, 256, 0, stream>>>(init_emb, cbufs[child], hbufs[child],
                                          Woend, boend, out);
}

// Round 12
// 1124.348 us; speedup vs baseline: 1.3303x; 1.3303x over previous
//
#include <hip/hip_runtime.h>
#include <hip/hip_bf16.h>
#include <math.h>

// Tree-LSTM "LogicEncoder": D=10, N=1023 nodes, B=128, LD=256, K=2.
// Round 12: revert to round-9 champion (pack-on-the-fly bf16x3 MFMA levels,
// 1272us) — rounds 10 (AST=34 bank conflicts) and 11 (presplit = +50% traffic)
// both regressed. NEW: leaf_mfma = NG=2/NSEG=1 variant of the proven pack
// kernel (in the operand-swapped layout each lane holds BOTH c and o for the
// same (col,b) -> fully in-lane leaf epilogue, float4 stores). LDS 46KB ->
// 3 blocks/CU. fp32 leaf kept as ws-gated fallback.

#define NNODES 1023
#define BATCH  128
#define LDIM   256

typedef __attribute__((ext_vector_type(8))) short short8;
typedef __attribute__((ext_vector_type(4))) float f32x4;

__device__ __forceinline__ float sigmoidf_(float x) {
    return 1.f / (1.f + expf(-x));
}

// fp32 -> 3x bf16, round-to-nearest-even at each stage; residuals exact.
__device__ __forceinline__ void split3(float x, ushort& h, ushort& m, ushort& l) {
    unsigned u = __float_as_uint(x);
    unsigned hu = (u + 0x7FFFu + ((u >> 16) & 1u)) & 0xFFFF0000u;
    h = (ushort)(hu >> 16);
    float r = x - __uint_as_float(hu);
    unsigned ur = __float_as_uint(r);
    unsigned mu = (ur + 0x7FFFu + ((ur >> 16) & 1u)) & 0xFFFF0000u;
    m = (ushort)(mu >> 16);
    float r2 = r - __uint_as_float(mu);
    unsigned u2 = __float_as_uint(r2);
    l = (ushort)((u2 + 0x7FFFu + ((u2 >> 16) & 1u)) >> 16);
}

// pair-split, BY-VALUE result (no reference outputs in hot paths)
struct P3 { unsigned h, m, l; };
__device__ __forceinline__ P3 pack2v(float x0, float x1) {
    ushort h0, m0, l0, h1, m1, l1;
    split3(x0, h0, m0, l0);
    split3(x1, h1, m1, l1);
    P3 r;
    r.h = (unsigned)h0 | ((unsigned)h1 << 16);
    r.m = (unsigned)m0 | ((unsigned)m1 << 16);
    r.l = (unsigned)l0 | ((unsigned)l1 << 16);
    return r;
}

// ---------------------------------------------------------------------------
// Pack Wbig (768x1024) + bias_big(1024) + Wleaf(256x512) + bias_leaf(512).
__global__ __launch_bounds__(256) void build_weights(
    const float* __restrict__ Wix, const float* __restrict__ bix,
    const float* __restrict__ Wfx, const float* __restrict__ bfx,
    const float* __restrict__ Wux, const float* __restrict__ bux,
    const float* __restrict__ Wi,  const float* __restrict__ bi,
    const float* __restrict__ Wf,  const float* __restrict__ bf,
    const float* __restrict__ Wu,  const float* __restrict__ bu,
    const float* __restrict__ Wcx, const float* __restrict__ bcx,
    const float* __restrict__ Wox, const float* __restrict__ box,
    float* __restrict__ Wbig, float* __restrict__ bias_big,
    float* __restrict__ Wleaf, float* __restrict__ bias_leaf)
{
    int i = blockIdx.x * blockDim.x + threadIdx.x;
    if (i < 768 * 1024) {
        int k = i >> 10, n = i & 1023;
        int g = n >> 8, nn = n & 255;
        float v;
        if (g == 0) {
            v = (k < 256) ? Wix[k * 256 + nn]
              : (k < 512) ? Wi[(k - 256) * 256 + nn]
                          : Wi[65536 + (k - 512) * 256 + nn];
        } else if (g == 1) {
            v = (k < 256) ? Wux[k * 256 + nn]
              : (k < 512) ? Wu[(k - 256) * 256 + nn]
                          : Wu[65536 + (k - 512) * 256 + nn];
        } else {
            int kf = g - 2;  // f0 / f1
            v = (k < 256) ? Wfx[k * 256 + nn]
              : (k < 512) ? Wf[((kf * 2 + 0) * 256 + (k - 256)) * 256 + nn]
                          : Wf[((kf * 2 + 1) * 256 + (k - 512)) * 256 + nn];
        }
        Wbig[i] = v;
        return;
    }
    i -= 768 * 1024;
    if (i < 1024) {
        int g = i >> 8, nn = i & 255;
        float v;
        if (g == 0)      v = bix[nn] + bi[nn] + bi[256 + nn];
        else if (g == 1) v = bux[nn] + bu[nn] + bu[256 + nn];
        else if (g == 2) v = bfx[nn] + bf[nn] + bf[256 + nn];
        else             v = bfx[nn] + bf[512 + nn] + bf[768 + nn];
        bias_big[i] = v;
        return;
    }
    i -= 1024;
    if (i < 256 * 512) {
        int k = i >> 9, n = i & 511;
        Wleaf[i] = (n < 256) ? Wcx[k * 256 + n] : Wox[k * 256 + (n - 256)];
        return;
    }
    i -= 256 * 512;
    if (i < 512) {
        bias_leaf[i] = (i < 256) ? bcx[i] : box[i - 256];
    }
}

// ---------------------------------------------------------------------------
// Split Wbig into 3 bf16 planes TRANSPOSED: Wt_s[n][k] (1024 x 768).
__global__ __launch_bounds__(256) void split_weights_T(
    const float* __restrict__ Wbig,
    ushort* __restrict__ Wth, ushort* __restrict__ Wtm, ushort* __restrict__ Wtl)
{
    __shared__ float sh[32][33];
    const int k0 = blockIdx.x * 32, n0 = blockIdx.y * 32;
    const int t = threadIdx.x;
    {
        int r = t >> 3, c4 = (t & 7) * 4;
        float4 v = *(const float4*)&Wbig[(size_t)(k0 + r) * 1024 + n0 + c4];
        sh[r][c4] = v.x; sh[r][c4 + 1] = v.y; sh[r][c4 + 2] = v.z; sh[r][c4 + 3] = v.w;
    }
    __syncthreads();
    int n = t >> 3, kc = (t & 7) * 4;
    ushort oh[4], om[4], ol[4];
#pragma unroll
    for (int j = 0; j < 4; ++j)
        split3(sh[kc + j][n], oh[j], om[j], ol[j]);
    size_t o = (size_t)(n0 + n) * 768 + k0 + kc;
    *(ushort4*)&Wth[o] = make_ushort4(oh[0], oh[1], oh[2], oh[3]);
    *(ushort4*)&Wtm[o] = make_ushort4(om[0], om[1], om[2], om[3]);
    *(ushort4*)&Wtl[o] = make_ushort4(ol[0], ol[1], ol[2], ol[3]);
}

// ---------------------------------------------------------------------------
// Split Wleaf (256x512) into 3 bf16 planes TRANSPOSED: Lt_s[n][k] (512 x 256).
// grid (8, 16) = (256/32, 512/32).
__global__ __launch_bounds__(256) void split_wleaf_T(
    const float* __restrict__ Wleaf,
    ushort* __restrict__ Lth, ushort* __restrict__ Ltm, ushort* __restrict__ Ltl)
{
    __shared__ float sh[32][33];
    const int k0 = blockIdx.x * 32, n0 = blockIdx.y * 32;
    const int t = threadIdx.x;
    {
        int r = t >> 3, c4 = (t & 7) * 4;
        float4 v = *(const float4*)&Wleaf[(size_t)(k0 + r) * 512 + n0 + c4];
        sh[r][c4] = v.x; sh[r][c4 + 1] = v.y; sh[r][c4 + 2] = v.z; sh[r][c4 + 3] = v.w;
    }
    __syncthreads();
    int n = t >> 3, kc = (t & 7) * 4;
    ushort oh[4], om[4], ol[4];
#pragma unroll
    for (int j = 0; j < 4; ++j)
        split3(sh[kc + j][n], oh[j], om[j], ol[j]);
    size_t o = (size_t)(n0 + n) * 256 + k0 + kc;
    *(ushort4*)&Lth[o] = make_ushort4(oh[0], oh[1], oh[2], oh[3]);
    *(ushort4*)&Ltm[o] = make_ushort4(om[0], om[1], om[2], om[3]);
    *(ushort4*)&Ltl[o] = make_ushort4(ol[0], ol[1], ol[2], ol[3]);
}

// ---------------------------------------------------------------------------
// bf16x3 MFMA level kernel (round-9 proven, byte-identical).
// grid (W, 8): blockIdx.x = node (node%8 -> XCD), blockIdx.y = gy. AST=40.
__global__ __launch_bounds__(256, 2) void mfma_level_pack(
    const float* __restrict__ x_embed,
    const float* __restrict__ hChild, const float* __restrict__ cChild,
    const ushort* __restrict__ Wth, const ushort* __restrict__ Wtm,
    const ushort* __restrict__ Wtl,
    const float* __restrict__ bias,
    float* __restrict__ hOut, float* __restrict__ cOut, int nstart)
{
    constexpr int AST = 40;
    __shared__ __align__(16) ushort Wlds[3][128 * AST];
    __shared__ __align__(16) ushort Vlds[3][128 * AST];

    const int tid  = threadIdx.x;
    const int node = blockIdx.x;
    const int gy   = blockIdx.y;
    const int lane = tid & 63, wid = tid >> 6;
    const int ni = wid & 1, bw = wid >> 1;
    const int srow = tid & 127, shalf = tid >> 7;

    const float* aX = x_embed + ((size_t)srow * NNODES + (nstart + node)) * LDIM;
    const float* aL = hChild + ((size_t)(2 * node) * BATCH + srow) * LDIM;
    const float* aR = aL + (size_t)BATCH * LDIM;
    const size_t nb = (size_t)(((srow >> 5) << 8) + gy * 32 + (srow & 31)) * 768;
    const ushort* w0 = Wth + nb;
    const ushort* w1 = Wtm + nb;
    const ushort* w2 = Wtl + nb;

    f32x4 acc[4][4];
#pragma unroll
    for (int g = 0; g < 4; ++g)
#pragma unroll
        for (int t2 = 0; t2 < 4; ++t2) acc[g][t2] = (f32x4){0.f, 0.f, 0.f, 0.f};

    float4 a0, a1, a2, a3;
    int4 w00, w01, w10, w11, w20, w21;

#define TREE_LOADS(IT)                                                         \
    {                                                                          \
        const int seg_  = (IT) >> 3;                                           \
        const int koff_ = ((IT) & 7) * 32 + shalf * 16;                        \
        const float* ap_ = (seg_ == 0) ? aX : (seg_ == 1) ? aL : aR;           \
        ap_ += koff_;                                                          \
        a0 = *(const float4*)(ap_);                                            \
        a1 = *(const float4*)(ap_ + 4);                                        \
        a2 = *(const float4*)(ap_ + 8);                                        \
        a3 = *(const float4*)(ap_ + 12);                                       \
        const int bko_ = (IT) * 32 + shalf * 16;                               \
        w00 = *(const int4*)(w0 + bko_); w01 = *(const int4*)(w0 + bko_ + 8);  \
        w10 = *(const int4*)(w1 + bko_); w11 = *(const int4*)(w1 + bko_ + 8);  \
        w20 = *(const int4*)(w2 + bko_); w21 = *(const int4*)(w2 + bko_ + 8);  \
    }

    TREE_LOADS(0);
    for (int it = 0; it < 24; ++it) {
        if (it) __syncthreads();
        {
            P3 p0 = pack2v(a0.x, a0.y), p1 = pack2v(a0.z, a0.w);
            P3 p2 = pack2v(a1.x, a1.y), p3 = pack2v(a1.z, a1.w);
            P3 p4 = pack2v(a2.x, a2.y), p5 = pack2v(a2.z, a2.w);
            P3 p6 = pack2v(a3.x, a3.y), p7 = pack2v(a3.z, a3.w);
            const int base = srow * AST + shalf * 16;
            *(int4*)&Vlds[0][base]     = make_int4((int)p0.h, (int)p1.h, (int)p2.h, (int)p3.h);
            *(int4*)&Vlds[0][base + 8] = make_int4((int)p4.h, (int)p5.h, (int)p6.h, (int)p7.h);
            *(int4*)&Vlds[1][base]     = make_int4((int)p0.m, (int)p1.m, (int)p2.m, (int)p3.m);
            *(int4*)&Vlds[1][base + 8] = make_int4((int)p4.m, (int)p5.m, (int)p6.m, (int)p7.m);
            *(int4*)&Vlds[2][base]     = make_int4((int)p0.l, (int)p1.l, (int)p2.l, (int)p3.l);
            *(int4*)&Vlds[2][base + 8] = make_int4((int)p4.l, (int)p5.l, (int)p6.l, (int)p7.l);
            *(int4*)&Wlds[0][base]     = w00;
            *(int4*)&Wlds[0][base + 8] = w01;
            *(int4*)&Wlds[1][base]     = w10;
            *(int4*)&Wlds[1][base + 8] = w11;
            *(int4*)&Wlds[2][base]     = w20;
            *(int4*)&Wlds[2][base + 8] = w21;
        }
        __syncthreads();
        if (it + 1 < 24) TREE_LOADS(it + 1);
        {
            short8 vf[4][3];
#pragma unroll
            for (int Nt = 0; Nt < 4; ++Nt) {
                const int rb = (bw * 64 + Nt * 16 + (lane & 15)) * AST + (lane >> 4) * 8;
#pragma unroll
                for (int s = 0; s < 3; ++s) vf[Nt][s] = *(const short8*)&Vlds[s][rb];
            }
#pragma unroll
            for (int g = 0; g < 4; ++g) {
                const int cb = (g * 32 + ni * 16 + (lane & 15)) * AST + (lane >> 4) * 8;
                short8 wh = *(const short8*)&Wlds[0][cb];
                short8 wm = *(const short8*)&Wlds[1][cb];
                short8 wl = *(const short8*)&Wlds[2][cb];
#pragma unroll
                for (int Nt = 0; Nt < 4; ++Nt)
                    acc[g][Nt] = __builtin_amdgcn_mfma_f32_16x16x32_bf16(wl, vf[Nt][0], acc[g][Nt], 0, 0, 0);
#pragma unroll
                for (int Nt = 0; Nt < 4; ++Nt)
                    acc[g][Nt] = __builtin_amdgcn_mfma_f32_16x16x32_bf16(wh, vf[Nt][2], acc[g][Nt], 0, 0, 0);
#pragma unroll
                for (int Nt = 0; Nt < 4; ++Nt)
                    acc[g][Nt] = __builtin_amdgcn_mfma_f32_16x16x32_bf16(wm, vf[Nt][1], acc[g][Nt], 0, 0, 0);
#pragma unroll
                for (int Nt = 0; Nt < 4; ++Nt)
                    acc[g][Nt] = __builtin_amdgcn_mfma_f32_16x16x32_bf16(wm, vf[Nt][0], acc[g][Nt], 0, 0, 0);
#pragma unroll
                for (int Nt = 0; Nt < 4; ++Nt)
                    acc[g][Nt] = __builtin_amdgcn_mfma_f32_16x16x32_bf16(wh, vf[Nt][1], acc[g][Nt], 0, 0, 0);
#pragma unroll
                for (int Nt = 0; Nt < 4; ++Nt)
                    acc[g][Nt] = __builtin_amdgcn_mfma_f32_16x16x32_bf16(wh, vf[Nt][0], acc[g][Nt], 0, 0, 0);
            }
        }
    }
#undef TREE_LOADS

    const int nc = gy * 32 + ni * 16 + ((lane >> 4) << 2);
    const size_t cLb = (size_t)(2 * node) * BATCH * LDIM;
    const size_t cRb = cLb + (size_t)BATCH * LDIM;
    const size_t ob  = (size_t)node * BATCH * LDIM;
    const float4 bi4 = *(const float4*)&bias[nc];
    const float4 bu4 = *(const float4*)&bias[256 + nc];
    const float4 b04 = *(const float4*)&bias[512 + nc];
    const float4 b14 = *(const float4*)&bias[768 + nc];
    const float bi_[4] = {bi4.x, bi4.y, bi4.z, bi4.w};
    const float bu_[4] = {bu4.x, bu4.y, bu4.z, bu4.w};
    const float b0_[4] = {b04.x, b04.y, b04.z, b04.w};
    const float b1_[4] = {b14.x, b14.y, b14.z, b14.w};
#pragma unroll
    for (int Nt = 0; Nt < 4; ++Nt) {
        const int b = bw * 64 + Nt * 16 + (lane & 15);
        float4 cL = *(const float4*)&cChild[cLb + (size_t)b * LDIM + nc];
        float4 cR = *(const float4*)&cChild[cRb + (size_t)b * LDIM + nc];
        float cl4[4] = {cL.x, cL.y, cL.z, cL.w};
        float cr4[4] = {cR.x, cR.y, cR.z, cR.w};
        float4 c4, h4;
        float* cp = (float*)&c4; float* hp = (float*)&h4;
#pragma unroll
        for (int j = 0; j < 4; ++j) {
            float gi = sigmoidf_(acc[0][Nt][j] + bi_[j]);
            float gu = tanhf(acc[1][Nt][j] + bu_[j]);
            float f0 = acc[2][Nt][j] + b0_[j];
            float f1 = acc[3][Nt][j] + b1_[j];
            float c  = gi * gu + f0 * cl4[j] + f1 * cr4[j];
            cp[j] = c;
            hp[j] = tanhf(c);
        }
        *(float4*)&cOut[ob + (size_t)b * LDIM + nc] = c4;
        *(float4*)&hOut[ob + (size_t)b * LDIM + nc] = h4;
    }
}

// ---------------------------------------------------------------------------
// bf16x3 MFMA LEAF kernel: NG=2 ([c|o]), NSEG=1 (x only), NIT=8.
// grid (512, 8): blockIdx.x = leaf-local node ln (real node = 511+ln),
// blockIdx.y = gy. Wlds has 64 rows ([c cols 0-31 | o cols 32-63]) -> 46KB
// LDS -> 3 blocks/CU. Each lane holds c (g=0) and o (g=1) for the SAME
// (col, b) -> in-lane leaf epilogue, float4 stores.
__global__ __launch_bounds__(256, 3) void leaf_mfma(
    const float* __restrict__ x_embed,
    const ushort* __restrict__ Lth, const ushort* __restrict__ Ltm,
    const ushort* __restrict__ Ltl,
    const float* __restrict__ bias_leaf,
    float* __restrict__ hOut, float* __restrict__ cOut)
{
    constexpr int AST = 40;
    __shared__ __align__(16) ushort Wlds[3][64 * AST];
    __shared__ __align__(16) ushort Vlds[3][128 * AST];

    const int tid = threadIdx.x;
    const int ln  = blockIdx.x;                   // leaf-local node 0..511
    const int gy  = blockIdx.y;
    const int lane = tid & 63, wid = tid >> 6;
    const int ni = wid & 1, bw = wid >> 1;
    const int srow = tid & 127, shalf = tid >> 7;
    const int wrow = tid & 63, whalf = (tid >> 6) & 1;   // weight staging (tid<128)

    const float* aX = x_embed + ((size_t)srow * NNODES + (511 + ln)) * LDIM;
    // weight row: n_local wrow -> phys col (wrow>>5)*256 + gy*32 + (wrow&31)
    const size_t nbw = (size_t)(((wrow >> 5) << 8) + gy * 32 + (wrow & 31)) * 256;
    const ushort* l0 = Lth + nbw;
    const ushort* l1 = Ltm + nbw;
    const ushort* l2 = Ltl + nbw;

    f32x4 acc[2][4];
#pragma unroll
    for (int g = 0; g < 2; ++g)
#pragma unroll
        for (int t2 = 0; t2 < 4; ++t2) acc[g][t2] = (f32x4){0.f, 0.f, 0.f, 0.f};

    float4 a0, a1, a2, a3;
    int4 w00, w01, w10, w11, w20, w21;

#define LEAF_LOADS(IT)                                                         \
    {                                                                          \
        const float* ap_ = aX + (IT) * 32 + shalf * 16;                        \
        a0 = *(const float4*)(ap_);                                            \
        a1 = *(const float4*)(ap_ + 4);                                        \
        a2 = *(const float4*)(ap_ + 8);                                        \
        a3 = *(const float4*)(ap_ + 12);                                       \
        if (tid < 128) {                                                       \
            const int bko_ = (IT) * 32 + whalf * 16;                           \
            w00 = *(const int4*)(l0 + bko_); w01 = *(const int4*)(l0 + bko_ + 8); \
            w10 = *(const int4*)(l1 + bko_); w11 = *(const int4*)(l1 + bko_ + 8); \
            w20 = *(const int4*)(l2 + bko_); w21 = *(const int4*)(l2 + bko_ + 8); \
        }                                                                      \
    }

    LEAF_LOADS(0);
    for (int it = 0; it < 8; ++it) {
        if (it) __syncthreads();
        {
            P3 p0 = pack2v(a0.x, a0.y), p1 = pack2v(a0.z, a0.w);
            P3 p2 = pack2v(a1.x, a1.y), p3 = pack2v(a1.z, a1.w);
            P3 p4 = pack2v(a2.x, a2.y), p5 = pack2v(a2.z, a2.w);
            P3 p6 = pack2v(a3.x, a3.y), p7 = pack2v(a3.z, a3.w);
            const int base = srow * AST + shalf * 16;
            *(int4*)&Vlds[0][base]     = make_int4((int)p0.h, (int)p1.h, (int)p2.h, (int)p3.h);
            *(int4*)&Vlds[0][base + 8] = make_int4((int)p4.h, (int)p5.h, (int)p6.h, (int)p7.h);
            *(int4*)&Vlds[1][base]     = make_int4((int)p0.m, (int)p1.m, (int)p2.m, (int)p3.m);
            *(int4*)&Vlds[1][base + 8] = make_int4((int)p4.m, (int)p5.m, (int)p6.m, (int)p7.m);
            *(int4*)&Vlds[2][base]     = make_int4((int)p0.l, (int)p1.l, (int)p2.l, (int)p3.l);
            *(int4*)&Vlds[2][base + 8] = make_int4((int)p4.l, (int)p5.l, (int)p6.l, (int)p7.l);
            if (tid < 128) {
                const int bw_ = wrow * AST + whalf * 16;
                *(int4*)&Wlds[0][bw_]     = w00;
                *(int4*)&Wlds[0][bw_ + 8] = w01;
                *(int4*)&Wlds[1][bw_]     = w10;
                *(int4*)&Wlds[1][bw_ + 8] = w11;
                *(int4*)&Wlds[2][bw_]     = w20;
                *(int4*)&Wlds[2][bw_ + 8] = w21;
            }
        }
        __syncthreads();
        if (it + 1 < 8) LEAF_LOADS(it + 1);
        {
            short8 vf[4][3];
#pragma unroll
            for (int Nt = 0; Nt < 4; ++Nt) {
                const int rb = (bw * 64 + Nt * 16 + (lane & 15)) * AST + (lane >> 4) * 8;
#pragma unroll
                for (int s = 0; s < 3; ++s) vf[Nt][s] = *(const short8*)&Vlds[s][rb];
            }
#pragma unroll
            for (int g = 0; g < 2; ++g) {
                const int cb = (g * 32 + ni * 16 + (lane & 15)) * AST + (lane >> 4) * 8;
                short8 wh = *(const short8*)&Wlds[0][cb];
                short8 wm = *(const short8*)&Wlds[1][cb];
                short8 wl = *(const short8*)&Wlds[2][cb];
#pragma unroll
                for (int Nt = 0; Nt < 4; ++Nt)
                    acc[g][Nt] = __builtin_amdgcn_mfma_f32_16x16x32_bf16(wl, vf[Nt][0], acc[g][Nt], 0, 0, 0);
#pragma unroll
                for (int Nt = 0; Nt < 4; ++Nt)
                    acc[g][Nt] = __builtin_amdgcn_mfma_f32_16x16x32_bf16(wh, vf[Nt][2], acc[g][Nt], 0, 0, 0);
#pragma unroll
                for (int Nt = 0; Nt < 4; ++Nt)
                    acc[g][Nt] = __builtin_amdgcn_mfma_f32_16x16x32_bf16(wm, vf[Nt][1], acc[g][Nt], 0, 0, 0);
#pragma unroll
                for (int Nt = 0; Nt < 4; ++Nt)
                    acc[g][Nt] = __builtin_amdgcn_mfma_f32_16x16x32_bf16(wm, vf[Nt][0], acc[g][Nt], 0, 0, 0);
#pragma unroll
                for (int Nt = 0; Nt < 4; ++Nt)
                    acc[g][Nt] = __builtin_amdgcn_mfma_f32_16x16x32_bf16(wh, vf[Nt][1], acc[g][Nt], 0, 0, 0);
#pragma unroll
                for (int Nt = 0; Nt < 4; ++Nt)
                    acc[g][Nt] = __builtin_amdgcn_mfma_f32_16x16x32_bf16(wh, vf[Nt][0], acc[g][Nt], 0, 0, 0);
            }
        }
    }
#undef LEAF_LOADS

    // ----- leaf epilogue (fully in-lane: acc[0]=c lin, acc[1]=o lin) -----
    const int nc = gy * 32 + ni * 16 + ((lane >> 4) << 2);   // out col quad
    const size_t ob = (size_t)ln * BATCH * LDIM;
    const float4 bc4 = *(const float4*)&bias_leaf[nc];
    const float4 bo4 = *(const float4*)&bias_leaf[256 + nc];
    const float bc_[4] = {bc4.x, bc4.y, bc4.z, bc4.w};
    const float bo_[4] = {bo4.x, bo4.y, bo4.z, bo4.w};
#pragma unroll
    for (int Nt = 0; Nt < 4; ++Nt) {
        const int b = bw * 64 + Nt * 16 + (lane & 15);
        float4 c4, h4;
        float* cp = (float*)&c4; float* hp = (float*)&h4;
#pragma unroll
        for (int j = 0; j < 4; ++j) {
            float c = acc[0][Nt][j] + bc_[j];
            float o = acc[1][Nt][j] + bo_[j];
            cp[j] = c;
            hp[j] = sigmoidf_(o) * tanhf(c);
        }
        size_t po = ob + (size_t)b * LDIM + nc;
        *(float4*)&cOut[po] = c4;
        *(float4*)&hOut[po] = h4;
    }
}

// ---------------------------------------------------------------------------
// Leaf kernel (round-1/4 proven fp32 fallback). grid (1024, 4), block 256.
__global__ __launch_bounds__(256) void leaf_kernel(
    const float* __restrict__ x_embed,
    const float* __restrict__ Wleaf, const float* __restrict__ bias_leaf,
    float* __restrict__ hOut, float* __restrict__ cOut)
{
    __shared__ float As[16 * 68];
    __shared__ float Bs[2 * 16 * 64];
    float acc[2][4][4] = {};
    const int tid = threadIdx.x;
    const int ty = tid >> 4, tx = tid & 15;
    const int row0 = blockIdx.x * 64;
    const int n0 = blockIdx.y * 64;
    const int w = row0 >> 7;
    const int ar = tid >> 2;
    const int kq = (tid & 3) * 4;
    const int b = (row0 + ar) & 127;
    const float* xrow = x_embed + ((size_t)b * NNODES + 511 + w) * LDIM;

    for (int k0 = 0; k0 < 256; k0 += 16) {
        float4 av = *(const float4*)(xrow + k0 + kq);
        As[(kq + 0) * 68 + ar] = av.x;
        As[(kq + 1) * 68 + ar] = av.y;
        As[(kq + 2) * 68 + ar] = av.z;
        As[(kq + 3) * 68 + ar] = av.w;
#pragma unroll
        for (int q = 0; q < 2; ++q) {
            int L = q * 256 + tid;
            int g = L >> 8, kk = (L >> 4) & 15, n4 = (L & 15) * 4;
            float4 bv = *(const float4*)(Wleaf + (size_t)(k0 + kk) * 512 + g * 256 + n0 + n4);
            *(float4*)&Bs[(g * 16 + kk) * 64 + n4] = bv;
        }
        __syncthreads();
#pragma unroll
        for (int kk = 0; kk < 16; ++kk) {
            float4 a = *(const float4*)&As[kk * 68 + ty * 4];
            float av4[4] = {a.x, a.y, a.z, a.w};
#pragma unroll
            for (int g = 0; g < 2; ++g) {
                float4 bb = *(const float4*)&Bs[(g * 16 + kk) * 64 + tx * 4];
                float bv4[4] = {bb.x, bb.y, bb.z, bb.w};
#pragma unroll
                for (int ii = 0; ii < 4; ++ii)
#pragma unroll
                    for (int jj = 0; jj < 4; ++jj)
                        acc[g][ii][jj] += av4[ii] * bv4[jj];
            }
        }
        __syncthreads();
    }
#pragma unroll
    for (int ii = 0; ii < 4; ++ii) {
        int r = row0 + ty * 4 + ii;
        int nc = n0 + tx * 4;
        float4 c4, h4;
        float* cp = (float*)&c4; float* hp = (float*)&h4;
#pragma unroll
        for (int jj = 0; jj < 4; ++jj) {
            int n = nc + jj;
            float ac = acc[0][ii][jj] + bias_leaf[n];
            float ao = acc[1][ii][jj] + bias_leaf[256 + n];
            cp[jj] = ac;
            hp[jj] = sigmoidf_(ao) * tanhf(ac);
        }
        *(float4*)&cOut[(size_t)r * LDIM + nc] = c4;
        *(float4*)&hOut[(size_t)r * LDIM + nc] = h4;
    }
}

// ---------------------------------------------------------------------------
// fp32 level kernel (round-1/4 proven). grid (W*2, 4), block 256.
__global__ __launch_bounds__(256) void level_kernel(
    const float* __restrict__ x_embed,
    const float* __restrict__ hChild, const float* __restrict__ cChild,
    const float* __restrict__ Wbig, const float* __restrict__ bias_big,
    float* __restrict__ hOut, float* __restrict__ cOut,
    int nstart)
{
    __shared__ float As[16 * 68];
    __shared__ float Bs[4 * 16 * 64];
    float acc[4][4][4] = {};
    const int tid = threadIdx.x;
    const int ty = tid >> 4, tx = tid & 15;
    const int row0 = blockIdx.x * 64;
    const int n0 = blockIdx.y * 64;
    const int w = row0 >> 7;
    const int ar = tid >> 2;
    const int kq = (tid & 3) * 4;
    const int b = (row0 + ar) & 127;
    const float* srcX = x_embed + ((size_t)b * NNODES + nstart + w) * LDIM;
    const float* srcL = hChild + ((size_t)(2 * w) * BATCH + b) * LDIM;
    const float* srcR = hChild + ((size_t)(2 * w + 1) * BATCH + b) * LDIM;

    for (int k0 = 0; k0 < 768; k0 += 16) {
        int seg = k0 >> 8, off = k0 & 255;
        const float* src = (seg == 0) ? srcX : (seg == 1) ? srcL : srcR;
        float4 av = *(const float4*)(src + off + kq);
        As[(kq + 0) * 68 + ar] = av.x;
        As[(kq + 1) * 68 + ar] = av.y;
        As[(kq + 2) * 68 + ar] = av.z;
        As[(kq + 3) * 68 + ar] = av.w;
#pragma unroll
        for (int q = 0; q < 4; ++q) {
            int L = q * 256 + tid;
            int g = L >> 8, kk = (L >> 4) & 15, n4 = (L & 15) * 4;
            float4 bv = *(const float4*)(Wbig + (size_t)(k0 + kk) * 1024 + g * 256 + n0 + n4);
            *(float4*)&Bs[(g * 16 + kk) * 64 + n4] = bv;
        }
        __syncthreads();
#pragma unroll
        for (int kk = 0; kk < 16; ++kk) {
            float4 a = *(const float4*)&As[kk * 68 + ty * 4];
            float av4[4] = {a.x, a.y, a.z, a.w};
#pragma unroll
            for (int g = 0; g < 4; ++g) {
                float4 bb = *(const float4*)&Bs[(g * 16 + kk) * 64 + tx * 4];
                float bv4[4] = {bb.x, bb.y, bb.z, bb.w};
#pragma unroll
                for (int ii = 0; ii < 4; ++ii)
#pragma unroll
                    for (int jj = 0; jj < 4; ++jj)
                        acc[g][ii][jj] += av4[ii] * bv4[jj];
            }
        }
        __syncthreads();
    }
    const size_t cLbase = ((size_t)(2 * w) * BATCH) * LDIM;
    const size_t cRbase = ((size_t)(2 * w + 1) * BATCH) * LDIM;
#pragma unroll
    for (int ii = 0; ii < 4; ++ii) {
        int r = row0 + ty * 4 + ii;
        int bb2 = r & 127;
        int nc = n0 + tx * 4;
        float4 cL = *(const float4*)&cChild[cLbase + (size_t)bb2 * LDIM + nc];
        float4 cR = *(const float4*)&cChild[cRbase + (size_t)bb2 * LDIM + nc];
        float cl4[4] = {cL.x, cL.y, cL.z, cL.w};
        float cr4[4] = {cR.x, cR.y, cR.z, cR.w};
        float4 c4, h4;
        float* cp = (float*)&c4; float* hp = (float*)&h4;
#pragma unroll
        for (int jj = 0; jj < 4; ++jj) {
            int n = nc + jj;
            float gi = sigmoidf_(acc[0][ii][jj] + bias_big[n]);
            float gu = tanhf(acc[1][ii][jj] + bias_big[256 + n]);
            float f0 = acc[2][ii][jj] + bias_big[512 + n];
            float f1 = acc[3][ii][jj] + bias_big[768 + n];
            float c = gi * gu + f0 * cl4[jj] + f1 * cr4[jj];
            cp[jj] = c;
            hp[jj] = tanhf(c);
        }
        *(float4*)&cOut[(size_t)r * LDIM + nc] = c4;
        *(float4*)&hOut[(size_t)r * LDIM + nc] = h4;
    }
}

// ---------------------------------------------------------------------------
// Split-K partial (TM=4, one 256-wide K segment per blockIdx.z). grid (W*2,4,3).
__global__ __launch_bounds__(256) void gemm_part4(
    const float* __restrict__ x_embed, const float* __restrict__ hChild,
    const float* __restrict__ Wbig,
    float* __restrict__ part, int nstart, int rowsTotal)
{
    __shared__ float As[16 * 68];
    __shared__ float Bs[4 * 16 * 64];
    float acc[4][4][4] = {};
    const int tid = threadIdx.x;
    const int ty = tid >> 4, tx = tid & 15;
    const int row0 = blockIdx.x * 64;
    const int n0 = blockIdx.y * 64;
    const int seg = blockIdx.z;
    const int w = row0 >> 7;
    const int ar = tid >> 2;
    const int kq = (tid & 3) * 4;
    const int b = (row0 + ar) & 127;
    const float* src =
        (seg == 0) ? x_embed + ((size_t)b * NNODES + nstart + w) * LDIM
                   : hChild + ((size_t)(2 * w + (seg - 1)) * BATCH + b) * LDIM;

    for (int k0 = 0; k0 < 256; k0 += 16) {
        float4 av = *(const float4*)(src + k0 + kq);
        As[(kq + 0) * 68 + ar] = av.x;
        As[(kq + 1) * 68 + ar] = av.y;
        As[(kq + 2) * 68 + ar] = av.z;
        As[(kq + 3) * 68 + ar] = av.w;
#pragma unroll
        for (int q = 0; q < 4; ++q) {
            int L = q * 256 + tid;
            int g = L >> 8, kk = (L >> 4) & 15, n4 = (L & 15) * 4;
            float4 bv = *(const float4*)(Wbig + (size_t)(seg * 256 + k0 + kk) * 1024
                                         + g * 256 + n0 + n4);
            *(float4*)&Bs[(g * 16 + kk) * 64 + n4] = bv;
        }
        __syncthreads();
#pragma unroll
        for (int kk = 0; kk < 16; ++kk) {
            float4 a = *(const float4*)&As[kk * 68 + ty * 4];
            float av4[4] = {a.x, a.y, a.z, a.w};
#pragma unroll
            for (int g = 0; g < 4; ++g) {
                float4 bb = *(const float4*)&Bs[(g * 16 + kk) * 64 + tx * 4];
                float bv4[4] = {bb.x, bb.y, bb.z, bb.w};
#pragma unroll
                for (int ii = 0; ii < 4; ++ii)
#pragma unroll
                    for (int jj = 0; jj < 4; ++jj)
                        acc[g][ii][jj] += av4[ii] * bv4[jj];
            }
        }
        __syncthreads();
    }
#pragma unroll
    for (int ii = 0; ii < 4; ++ii) {
        int r = row0 + ty * 4 + ii;
        size_t base = ((size_t)seg * rowsTotal + r) * 1024 + n0 + tx * 4;
#pragma unroll
        for (int g = 0; g < 4; ++g)
            *(float4*)&part[base + g * 256] = *(float4*)acc[g][ii];
    }
}

// ---------------------------------------------------------------------------
// Combine 3 split-K partials + LSTM epilogue. grid (rows/4), block 256.
__global__ __launch_bounds__(256) void combine_eps(
    const float* __restrict__ part, const float* __restrict__ cChild,
    const float* __restrict__ bias,
    float* __restrict__ hOut, float* __restrict__ cOut, int rowsTotal)
{
    int idx = blockIdx.x * 256 + threadIdx.x;
    int row = idx >> 6, n = (idx & 63) * 4;
    size_t sseg = (size_t)rowsTotal * 1024;
    const float* p0 = part + (size_t)row * 1024 + n;
    float s[4][4];
#pragma unroll
    for (int g = 0; g < 4; ++g) {
        float4 a = *(const float4*)(p0 + g * 256);
        float4 b = *(const float4*)(p0 + sseg + g * 256);
        float4 c = *(const float4*)(p0 + 2 * sseg + g * 256);
        s[g][0] = a.x + b.x + c.x; s[g][1] = a.y + b.y + c.y;
        s[g][2] = a.z + b.z + c.z; s[g][3] = a.w + b.w + c.w;
    }
    int node = row >> 7, b = row & 127;
    float4 cL = *(const float4*)&cChild[((size_t)(2 * node) * BATCH + b) * LDIM + n];
    float4 cR = *(const float4*)&cChild[((size_t)(2 * node + 1) * BATCH + b) * LDIM + n];
    float cl4[4] = {cL.x, cL.y, cL.z, cL.w};
    float cr4[4] = {cR.x, cR.y, cR.z, cR.w};
    float4 c4, h4;
    float* cp = (float*)&c4; float* hp = (float*)&h4;
#pragma unroll
    for (int jj = 0; jj < 4; ++jj) {
        int nn = n + jj;
        float gi = sigmoidf_(s[0][jj] + bias[nn]);
        float gu = tanhf(s[1][jj] + bias[256 + nn]);
        float f0 = s[2][jj] + bias[512 + nn];
        float f1 = s[3][jj] + bias[768 + nn];
        float c = gi * gu + f0 * cl4[jj] + f1 * cr4[jj];
        cp[jj] = c;
        hp[jj] = tanhf(c);
    }
    *(float4*)&cOut[(size_t)row * LDIM + n] = c4;
    *(float4*)&hOut[(size_t)row * LDIM + n] = h4;
}

// ---------------------------------------------------------------------------
// Final: out[b][n] = tanh([init | c_root | h_root] @ Woend + boend). grid 128.
__global__ __launch_bounds__(256) void final_kernel(
    const float* __restrict__ init_emb,
    const float* __restrict__ cRoot, const float* __restrict__ hRoot,
    const float* __restrict__ Woend, const float* __restrict__ boend,
    float* __restrict__ out)
{
    __shared__ float sv[768];
    int b = blockIdx.x, t = threadIdx.x;
    sv[t]       = init_emb[(size_t)b * 256 + t];
    sv[256 + t] = cRoot[(size_t)b * 256 + t];
    sv[512 + t] = hRoot[(size_t)b * 256 + t];
    __syncthreads();
    float acc = boend[t];
#pragma unroll 4
    for (int d = 0; d < 768; ++d)
        acc += sv[d] * Woend[(size_t)d * 256 + t];
    out[(size_t)b * 256 + t] = tanhf(acc);
}

// ---------------------------------------------------------------------------
extern "C" void kernel_launch(void* const* d_in, const int* in_sizes, int n_in,
                              void* d_out, int out_size, void* d_ws, size_t ws_size,
                              hipStream_t stream)
{
    const float* x_embed  = (const float*)d_in[0];
    const float* init_emb = (const float*)d_in[1];
    const float* Wcx = (const float*)d_in[2];  const float* bcx = (const float*)d_in[3];
    const float* Wox = (const float*)d_in[4];  const float* box = (const float*)d_in[5];
    const float* Wix = (const float*)d_in[6];  const float* bix = (const float*)d_in[7];
    const float* Wfx = (const float*)d_in[8];  const float* bfx = (const float*)d_in[9];
    const float* Wux = (const float*)d_in[10]; const float* bux = (const float*)d_in[11];
    const float* Wi  = (const float*)d_in[12]; const float* bi  = (const float*)d_in[13];
    const float* Wf  = (const float*)d_in[14]; const float* bf  = (const float*)d_in[15];
    const float* Wu  = (const float*)d_in[16]; const float* bu  = (const float*)d_in[17];
    const float* Woend = (const float*)d_in[18]; const float* boend = (const float*)d_in[19];
    float* out = (float*)d_out;
    float* ws  = (float*)d_ws;

    size_t off = 0;
    float* hA = ws + off; off += (size_t)512 * 128 * 256;
    float* cA = ws + off; off += (size_t)512 * 128 * 256;
    float* hB = ws + off; off += (size_t)256 * 128 * 256;
    float* cB = ws + off; off += (size_t)256 * 128 * 256;
    float* Wbig      = ws + off; off += (size_t)768 * 1024;
    float* bias_big  = ws + off; off += 1024;
    float* Wleaf     = ws + off; off += (size_t)256 * 512;
    float* bias_leaf = ws + off; off += 512;
    // bf16 weight splits, transposed [n][k]
    ushort* Wth = (ushort*)(ws + off); off += (size_t)768 * 1024 / 2;
    ushort* Wtm = (ushort*)(ws + off); off += (size_t)768 * 1024 / 2;
    ushort* Wtl = (ushort*)(ws + off); off += (size_t)768 * 1024 / 2;
    // leaf weight splits, transposed [n=512][k=256]
    ushort* Lth = (ushort*)(ws + off); off += (size_t)512 * 256 / 2;
    ushort* Ltm = (ushort*)(ws + off); off += (size_t)512 * 256 / 2;
    ushort* Ltl = (ushort*)(ws + off); off += (size_t)512 * 256 / 2;
    size_t mfma_need = off * sizeof(float);
    size_t part_off = off;
    float* part = ws + part_off;

    bool mfma_ok = mfma_need <= ws_size;

    {
        int total = 768 * 1024 + 1024 + 256 * 512 + 512;
        int blocks = (total + 255) / 256;
        build_weights<<<blocks, 256, 0, stream>>>(
            Wix, bix, Wfx, bfx, Wux, bux, Wi, bi, Wf, bf, Wu, bu,
            Wcx, bcx, Wox, box, Wbig, bias_big, Wleaf, bias_leaf);
    }
    if (mfma_ok) {
        split_weights_T<<<dim3(24, 32), 256, 0, stream>>>(Wbig, Wth, Wtm, Wtl);
        split_wleaf_T<<<dim3(8, 16), 256, 0, stream>>>(Wleaf, Lth, Ltm, Ltl);
    }

    if (mfma_ok) {
        leaf_mfma<<<dim3(512, 8), 256, 0, stream>>>(
            x_embed, Lth, Ltm, Ltl, bias_leaf, hA, cA);
    } else {
        leaf_kernel<<<dim3(1024, 4), 256, 0, stream>>>(
            x_embed, Wleaf, bias_leaf, hA, cA);
    }

    float* hbufs[2] = {hA, hB};
    float* cbufs[2] = {cA, cB};
    int child = 0;  // leaves in A
    for (int lvl = 8; lvl >= 0; --lvl) {
        int W = 1 << lvl, s = W - 1;
        int outb = child ^ 1;
        size_t rows = (size_t)W * 128;
        bool split = (W <= 16) &&
                     ((part_off + 3 * rows * 1024) * sizeof(float) <= ws_size);
        if (lvl >= 5 && mfma_ok) {
            mfma_level_pack<<<dim3(W, 8), 256, 0, stream>>>(
                x_embed, hbufs[child], cbufs[child], Wth, Wtm, Wtl, bias_big,
                hbufs[outb], cbufs[outb], s);
        } else if (split) {
            gemm_part4<<<dim3(W * 2, 4, 3), 256, 0, stream>>>(
                x_embed, hbufs[child], Wbig, part, s, (int)rows);
            combine_eps<<<(int)(rows / 4), 256, 0, stream>>>(
                part, cbufs[child], bias_big, hbufs[outb], cbufs[outb], (int)rows);
        } else {
            level_kernel<<<dim3(W * 2, 4), 256, 0, stream>>>(
                x_embed, hbufs[child], cbufs[child], Wbig, bias_big,
                hbufs[outb], cbufs[outb], s);
        }
        child = outb;
    }

    final_kernel<<<128, 256, 0, stream>>>(init_emb, cbufs[child], hbufs[child],
                                          Woend, boend, out);
}

// Round 13
// 1087.504 us; speedup vs baseline: 1.3753x; 1.0339x over previous
//
#include <hip/hip_runtime.h>
#include <hip/hip_bf16.h>
#include <math.h>

// Tree-LSTM "LogicEncoder": D=10, N=1023 nodes, B=128, LD=256, K=2.
// Round 13: SINGLE CHANGE vs round 12 — pack2v now uses v_cvt_pk_bf16_f32
// (HW RNE f32->bf16 pair convert, inline asm; no builtin on gfx950).
// Per pair: 3 cvt_pk + 2 expand + 4 sub = ~11 VALU ops vs ~36 for the manual
// RNE split — the pack was ~600 cyc/iter vs MFMA's 466 (VALUBusy 34.7 ~=
// MfmaUtil 35.8 in r12). RNE matches split3 bitwise -> absmax unchanged.
// Residual subtractions are exact (8-bit-mantissa remainders fit fp32).
// Everything else byte-identical to round 12.

#define NNODES 1023
#define BATCH  128
#define LDIM   256

typedef __attribute__((ext_vector_type(8))) short short8;
typedef __attribute__((ext_vector_type(4))) float f32x4;

__device__ __forceinline__ float sigmoidf_(float x) {
    return 1.f / (1.f + expf(-x));
}

// fp32 -> 3x bf16, round-to-nearest-even at each stage; residuals exact.
// (kept for one-time weight-split kernels)
__device__ __forceinline__ void split3(float x, ushort& h, ushort& m, ushort& l) {
    unsigned u = __float_as_uint(x);
    unsigned hu = (u + 0x7FFFu + ((u >> 16) & 1u)) & 0xFFFF0000u;
    h = (ushort)(hu >> 16);
    float r = x - __uint_as_float(hu);
    unsigned ur = __float_as_uint(r);
    unsigned mu = (ur + 0x7FFFu + ((ur >> 16) & 1u)) & 0xFFFF0000u;
    m = (ushort)(mu >> 16);
    float r2 = r - __uint_as_float(mu);
    unsigned u2 = __float_as_uint(r2);
    l = (ushort)((u2 + 0x7FFFu + ((u2 >> 16) & 1u)) >> 16);
}

// HW pair convert: dst = [bf16(hi) : bf16(lo)], RNE (same as split3).
__device__ __forceinline__ unsigned cvt_pk_bf16(float lo, float hi) {
    unsigned r;
    asm("v_cvt_pk_bf16_f32 %0, %1, %2" : "=v"(r) : "v"(lo), "v"(hi));
    return r;
}

// pair-split via cvt_pk, BY-VALUE result (no reference outputs in hot paths)
struct P3 { unsigned h, m, l; };
__device__ __forceinline__ P3 pack2v(float x0, float x1) {
    P3 p;
    p.h = cvt_pk_bf16(x0, x1);
    float h0 = __uint_as_float(p.h << 16);
    float h1 = __uint_as_float(p.h & 0xFFFF0000u);
    float r0 = x0 - h0, r1 = x1 - h1;
    p.m = cvt_pk_bf16(r0, r1);
    float m0 = __uint_as_float(p.m << 16);
    float m1 = __uint_as_float(p.m & 0xFFFF0000u);
    p.l = cvt_pk_bf16(r0 - m0, r1 - m1);
    return p;
}

// ---------------------------------------------------------------------------
// Pack Wbig (768x1024) + bias_big(1024) + Wleaf(256x512) + bias_leaf(512).
__global__ __launch_bounds__(256) void build_weights(
    const float* __restrict__ Wix, const float* __restrict__ bix,
    const float* __restrict__ Wfx, const float* __restrict__ bfx,
    const float* __restrict__ Wux, const float* __restrict__ bux,
    const float* __restrict__ Wi,  const float* __restrict__ bi,
    const float* __restrict__ Wf,  const float* __restrict__ bf,
    const float* __restrict__ Wu,  const float* __restrict__ bu,
    const float* __restrict__ Wcx, const float* __restrict__ bcx,
    const float* __restrict__ Wox, const float* __restrict__ box,
    float* __restrict__ Wbig, float* __restrict__ bias_big,
    float* __restrict__ Wleaf, float* __restrict__ bias_leaf)
{
    int i = blockIdx.x * blockDim.x + threadIdx.x;
    if (i < 768 * 1024) {
        int k = i >> 10, n = i & 1023;
        int g = n >> 8, nn = n & 255;
        float v;
        if (g == 0) {
            v = (k < 256) ? Wix[k * 256 + nn]
              : (k < 512) ? Wi[(k - 256) * 256 + nn]
                          : Wi[65536 + (k - 512) * 256 + nn];
        } else if (g == 1) {
            v = (k < 256) ? Wux[k * 256 + nn]
              : (k < 512) ? Wu[(k - 256) * 256 + nn]
                          : Wu[65536 + (k - 512) * 256 + nn];
        } else {
            int kf = g - 2;  // f0 / f1
            v = (k < 256) ? Wfx[k * 256 + nn]
              : (k < 512) ? Wf[((kf * 2 + 0) * 256 + (k - 256)) * 256 + nn]
                          : Wf[((kf * 2 + 1) * 256 + (k - 512)) * 256 + nn];
        }
        Wbig[i] = v;
        return;
    }
    i -= 768 * 1024;
    if (i < 1024) {
        int g = i >> 8, nn = i & 255;
        float v;
        if (g == 0)      v = bix[nn] + bi[nn] + bi[256 + nn];
        else if (g == 1) v = bux[nn] + bu[nn] + bu[256 + nn];
        else if (g == 2) v = bfx[nn] + bf[nn] + bf[256 + nn];
        else             v = bfx[nn] + bf[512 + nn] + bf[768 + nn];
        bias_big[i] = v;
        return;
    }
    i -= 1024;
    if (i < 256 * 512) {
        int k = i >> 9, n = i & 511;
        Wleaf[i] = (n < 256) ? Wcx[k * 256 + n] : Wox[k * 256 + (n - 256)];
        return;
    }
    i -= 256 * 512;
    if (i < 512) {
        bias_leaf[i] = (i < 256) ? bcx[i] : box[i - 256];
    }
}

// ---------------------------------------------------------------------------
// Split Wbig into 3 bf16 planes TRANSPOSED: Wt_s[n][k] (1024 x 768).
__global__ __launch_bounds__(256) void split_weights_T(
    const float* __restrict__ Wbig,
    ushort* __restrict__ Wth, ushort* __restrict__ Wtm, ushort* __restrict__ Wtl)
{
    __shared__ float sh[32][33];
    const int k0 = blockIdx.x * 32, n0 = blockIdx.y * 32;
    const int t = threadIdx.x;
    {
        int r = t >> 3, c4 = (t & 7) * 4;
        float4 v = *(const float4*)&Wbig[(size_t)(k0 + r) * 1024 + n0 + c4];
        sh[r][c4] = v.x; sh[r][c4 + 1] = v.y; sh[r][c4 + 2] = v.z; sh[r][c4 + 3] = v.w;
    }
    __syncthreads();
    int n = t >> 3, kc = (t & 7) * 4;
    ushort oh[4], om[4], ol[4];
#pragma unroll
    for (int j = 0; j < 4; ++j)
        split3(sh[kc + j][n], oh[j], om[j], ol[j]);
    size_t o = (size_t)(n0 + n) * 768 + k0 + kc;
    *(ushort4*)&Wth[o] = make_ushort4(oh[0], oh[1], oh[2], oh[3]);
    *(ushort4*)&Wtm[o] = make_ushort4(om[0], om[1], om[2], om[3]);
    *(ushort4*)&Wtl[o] = make_ushort4(ol[0], ol[1], ol[2], ol[3]);
}

// ---------------------------------------------------------------------------
// Split Wleaf (256x512) into 3 bf16 planes TRANSPOSED: Lt_s[n][k] (512 x 256).
// grid (8, 16).
__global__ __launch_bounds__(256) void split_wleaf_T(
    const float* __restrict__ Wleaf,
    ushort* __restrict__ Lth, ushort* __restrict__ Ltm, ushort* __restrict__ Ltl)
{
    __shared__ float sh[32][33];
    const int k0 = blockIdx.x * 32, n0 = blockIdx.y * 32;
    const int t = threadIdx.x;
    {
        int r = t >> 3, c4 = (t & 7) * 4;
        float4 v = *(const float4*)&Wleaf[(size_t)(k0 + r) * 512 + n0 + c4];
        sh[r][c4] = v.x; sh[r][c4 + 1] = v.y; sh[r][c4 + 2] = v.z; sh[r][c4 + 3] = v.w;
    }
    __syncthreads();
    int n = t >> 3, kc = (t & 7) * 4;
    ushort oh[4], om[4], ol[4];
#pragma unroll
    for (int j = 0; j < 4; ++j)
        split3(sh[kc + j][n], oh[j], om[j], ol[j]);
    size_t o = (size_t)(n0 + n) * 256 + k0 + kc;
    *(ushort4*)&Lth[o] = make_ushort4(oh[0], oh[1], oh[2], oh[3]);
    *(ushort4*)&Ltm[o] = make_ushort4(om[0], om[1], om[2], om[3]);
    *(ushort4*)&Ltl[o] = make_ushort4(ol[0], ol[1], ol[2], ol[3]);
}

// ---------------------------------------------------------------------------
// bf16x3 MFMA level kernel (round-9 proven structure).
// grid (W, 8): blockIdx.x = node (node%8 -> XCD), blockIdx.y = gy. AST=40.
__global__ __launch_bounds__(256, 2) void mfma_level_pack(
    const float* __restrict__ x_embed,
    const float* __restrict__ hChild, const float* __restrict__ cChild,
    const ushort* __restrict__ Wth, const ushort* __restrict__ Wtm,
    const ushort* __restrict__ Wtl,
    const float* __restrict__ bias,
    float* __restrict__ hOut, float* __restrict__ cOut, int nstart)
{
    constexpr int AST = 40;
    __shared__ __align__(16) ushort Wlds[3][128 * AST];
    __shared__ __align__(16) ushort Vlds[3][128 * AST];

    const int tid  = threadIdx.x;
    const int node = blockIdx.x;
    const int gy   = blockIdx.y;
    const int lane = tid & 63, wid = tid >> 6;
    const int ni = wid & 1, bw = wid >> 1;
    const int srow = tid & 127, shalf = tid >> 7;

    const float* aX = x_embed + ((size_t)srow * NNODES + (nstart + node)) * LDIM;
    const float* aL = hChild + ((size_t)(2 * node) * BATCH + srow) * LDIM;
    const float* aR = aL + (size_t)BATCH * LDIM;
    const size_t nb = (size_t)(((srow >> 5) << 8) + gy * 32 + (srow & 31)) * 768;
    const ushort* w0 = Wth + nb;
    const ushort* w1 = Wtm + nb;
    const ushort* w2 = Wtl + nb;

    f32x4 acc[4][4];
#pragma unroll
    for (int g = 0; g < 4; ++g)
#pragma unroll
        for (int t2 = 0; t2 < 4; ++t2) acc[g][t2] = (f32x4){0.f, 0.f, 0.f, 0.f};

    float4 a0, a1, a2, a3;
    int4 w00, w01, w10, w11, w20, w21;

#define TREE_LOADS(IT)                                                         \
    {                                                                          \
        const int seg_  = (IT) >> 3;                                           \
        const int koff_ = ((IT) & 7) * 32 + shalf * 16;                        \
        const float* ap_ = (seg_ == 0) ? aX : (seg_ == 1) ? aL : aR;           \
        ap_ += koff_;                                                          \
        a0 = *(const float4*)(ap_);                                            \
        a1 = *(const float4*)(ap_ + 4);                                        \
        a2 = *(const float4*)(ap_ + 8);                                        \
        a3 = *(const float4*)(ap_ + 12);                                       \
        const int bko_ = (IT) * 32 + shalf * 16;                               \
        w00 = *(const int4*)(w0 + bko_); w01 = *(const int4*)(w0 + bko_ + 8);  \
        w10 = *(const int4*)(w1 + bko_); w11 = *(const int4*)(w1 + bko_ + 8);  \
        w20 = *(const int4*)(w2 + bko_); w21 = *(const int4*)(w2 + bko_ + 8);  \
    }

    TREE_LOADS(0);
    for (int it = 0; it < 24; ++it) {
        if (it) __syncthreads();
        {
            P3 p0 = pack2v(a0.x, a0.y), p1 = pack2v(a0.z, a0.w);
            P3 p2 = pack2v(a1.x, a1.y), p3 = pack2v(a1.z, a1.w);
            P3 p4 = pack2v(a2.x, a2.y), p5 = pack2v(a2.z, a2.w);
            P3 p6 = pack2v(a3.x, a3.y), p7 = pack2v(a3.z, a3.w);
            const int base = srow * AST + shalf * 16;
            *(int4*)&Vlds[0][base]     = make_int4((int)p0.h, (int)p1.h, (int)p2.h, (int)p3.h);
            *(int4*)&Vlds[0][base + 8] = make_int4((int)p4.h, (int)p5.h, (int)p6.h, (int)p7.h);
            *(int4*)&Vlds[1][base]     = make_int4((int)p0.m, (int)p1.m, (int)p2.m, (int)p3.m);
            *(int4*)&Vlds[1][base + 8] = make_int4((int)p4.m, (int)p5.m, (int)p6.m, (int)p7.m);
            *(int4*)&Vlds[2][base]     = make_int4((int)p0.l, (int)p1.l, (int)p2.l, (int)p3.l);
            *(int4*)&Vlds[2][base + 8] = make_int4((int)p4.l, (int)p5.l, (int)p6.l, (int)p7.l);
            *(int4*)&Wlds[0][base]     = w00;
            *(int4*)&Wlds[0][base + 8] = w01;
            *(int4*)&Wlds[1][base]     = w10;
            *(int4*)&Wlds[1][base + 8] = w11;
            *(int4*)&Wlds[2][base]     = w20;
            *(int4*)&Wlds[2][base + 8] = w21;
        }
        __syncthreads();
        if (it + 1 < 24) TREE_LOADS(it + 1);
        {
            short8 vf[4][3];
#pragma unroll
            for (int Nt = 0; Nt < 4; ++Nt) {
                const int rb = (bw * 64 + Nt * 16 + (lane & 15)) * AST + (lane >> 4) * 8;
#pragma unroll
                for (int s = 0; s < 3; ++s) vf[Nt][s] = *(const short8*)&Vlds[s][rb];
            }
#pragma unroll
            for (int g = 0; g < 4; ++g) {
                const int cb = (g * 32 + ni * 16 + (lane & 15)) * AST + (lane >> 4) * 8;
                short8 wh = *(const short8*)&Wlds[0][cb];
                short8 wm = *(const short8*)&Wlds[1][cb];
                short8 wl = *(const short8*)&Wlds[2][cb];
#pragma unroll
                for (int Nt = 0; Nt < 4; ++Nt)
                    acc[g][Nt] = __builtin_amdgcn_mfma_f32_16x16x32_bf16(wl, vf[Nt][0], acc[g][Nt], 0, 0, 0);
#pragma unroll
                for (int Nt = 0; Nt < 4; ++Nt)
                    acc[g][Nt] = __builtin_amdgcn_mfma_f32_16x16x32_bf16(wh, vf[Nt][2], acc[g][Nt], 0, 0, 0);
#pragma unroll
                for (int Nt = 0; Nt < 4; ++Nt)
                    acc[g][Nt] = __builtin_amdgcn_mfma_f32_16x16x32_bf16(wm, vf[Nt][1], acc[g][Nt], 0, 0, 0);
#pragma unroll
                for (int Nt = 0; Nt < 4; ++Nt)
                    acc[g][Nt] = __builtin_amdgcn_mfma_f32_16x16x32_bf16(wm, vf[Nt][0], acc[g][Nt], 0, 0, 0);
#pragma unroll
                for (int Nt = 0; Nt < 4; ++Nt)
                    acc[g][Nt] = __builtin_amdgcn_mfma_f32_16x16x32_bf16(wh, vf[Nt][1], acc[g][Nt], 0, 0, 0);
#pragma unroll
                for (int Nt = 0; Nt < 4; ++Nt)
                    acc[g][Nt] = __builtin_amdgcn_mfma_f32_16x16x32_bf16(wh, vf[Nt][0], acc[g][Nt], 0, 0, 0);
            }
        }
    }
#undef TREE_LOADS

    const int nc = gy * 32 + ni * 16 + ((lane >> 4) << 2);
    const size_t cLb = (size_t)(2 * node) * BATCH * LDIM;
    const size_t cRb = cLb + (size_t)BATCH * LDIM;
    const size_t ob  = (size_t)node * BATCH * LDIM;
    const float4 bi4 = *(const float4*)&bias[nc];
    const float4 bu4 = *(const float4*)&bias[256 + nc];
    const float4 b04 = *(const float4*)&bias[512 + nc];
    const float4 b14 = *(const float4*)&bias[768 + nc];
    const float bi_[4] = {bi4.x, bi4.y, bi4.z, bi4.w};
    const float bu_[4] = {bu4.x, bu4.y, bu4.z, bu4.w};
    const float b0_[4] = {b04.x, b04.y, b04.z, b04.w};
    const float b1_[4] = {b14.x, b14.y, b14.z, b14.w};
#pragma unroll
    for (int Nt = 0; Nt < 4; ++Nt) {
        const int b = bw * 64 + Nt * 16 + (lane & 15);
        float4 cL = *(const float4*)&cChild[cLb + (size_t)b * LDIM + nc];
        float4 cR = *(const float4*)&cChild[cRb + (size_t)b * LDIM + nc];
        float cl4[4] = {cL.x, cL.y, cL.z, cL.w};
        float cr4[4] = {cR.x, cR.y, cR.z, cR.w};
        float4 c4, h4;
        float* cp = (float*)&c4; float* hp = (float*)&h4;
#pragma unroll
        for (int j = 0; j < 4; ++j) {
            float gi = sigmoidf_(acc[0][Nt][j] + bi_[j]);
            float gu = tanhf(acc[1][Nt][j] + bu_[j]);
            float f0 = acc[2][Nt][j] + b0_[j];
            float f1 = acc[3][Nt][j] + b1_[j];
            float c  = gi * gu + f0 * cl4[j] + f1 * cr4[j];
            cp[j] = c;
            hp[j] = tanhf(c);
        }
        *(float4*)&cOut[ob + (size_t)b * LDIM + nc] = c4;
        *(float4*)&hOut[ob + (size_t)b * LDIM + nc] = h4;
    }
}

// ---------------------------------------------------------------------------
// bf16x3 MFMA LEAF kernel: NG=2 ([c|o]), NSEG=1 (x only), NIT=8.
// grid (512, 8). LDS 46KB -> 3 blocks/CU. In-lane epilogue, float4 stores.
__global__ __launch_bounds__(256, 3) void leaf_mfma(
    const float* __restrict__ x_embed,
    const ushort* __restrict__ Lth, const ushort* __restrict__ Ltm,
    const ushort* __restrict__ Ltl,
    const float* __restrict__ bias_leaf,
    float* __restrict__ hOut, float* __restrict__ cOut)
{
    constexpr int AST = 40;
    __shared__ __align__(16) ushort Wlds[3][64 * AST];
    __shared__ __align__(16) ushort Vlds[3][128 * AST];

    const int tid = threadIdx.x;
    const int ln  = blockIdx.x;                   // leaf-local node 0..511
    const int gy  = blockIdx.y;
    const int lane = tid & 63, wid = tid >> 6;
    const int ni = wid & 1, bw = wid >> 1;
    const int srow = tid & 127, shalf = tid >> 7;
    const int wrow = tid & 63, whalf = (tid >> 6) & 1;   // weight staging (tid<128)

    const float* aX = x_embed + ((size_t)srow * NNODES + (511 + ln)) * LDIM;
    const size_t nbw = (size_t)(((wrow >> 5) << 8) + gy * 32 + (wrow & 31)) * 256;
    const ushort* l0 = Lth + nbw;
    const ushort* l1 = Ltm + nbw;
    const ushort* l2 = Ltl + nbw;

    f32x4 acc[2][4];
#pragma unroll
    for (int g = 0; g < 2; ++g)
#pragma unroll
        for (int t2 = 0; t2 < 4; ++t2) acc[g][t2] = (f32x4){0.f, 0.f, 0.f, 0.f};

    float4 a0, a1, a2, a3;
    int4 w00, w01, w10, w11, w20, w21;

#define LEAF_LOADS(IT)                                                         \
    {                                                                          \
        const float* ap_ = aX + (IT) * 32 + shalf * 16;                        \
        a0 = *(const float4*)(ap_);                                            \
        a1 = *(const float4*)(ap_ + 4);                                        \
        a2 = *(const float4*)(ap_ + 8);                                        \
        a3 = *(const float4*)(ap_ + 12);                                       \
        if (tid < 128) {                                                       \
            const int bko_ = (IT) * 32 + whalf * 16;                           \
            w00 = *(const int4*)(l0 + bko_); w01 = *(const int4*)(l0 + bko_ + 8); \
            w10 = *(const int4*)(l1 + bko_); w11 = *(const int4*)(l1 + bko_ + 8); \
            w20 = *(const int4*)(l2 + bko_); w21 = *(const int4*)(l2 + bko_ + 8); \
        }                                                                      \
    }

    LEAF_LOADS(0);
    for (int it = 0; it < 8; ++it) {
        if (it) __syncthreads();
        {
            P3 p0 = pack2v(a0.x, a0.y), p1 = pack2v(a0.z, a0.w);
            P3 p2 = pack2v(a1.x, a1.y), p3 = pack2v(a1.z, a1.w);
            P3 p4 = pack2v(a2.x, a2.y), p5 = pack2v(a2.z, a2.w);
            P3 p6 = pack2v(a3.x, a3.y), p7 = pack2v(a3.z, a3.w);
            const int base = srow * AST + shalf * 16;
            *(int4*)&Vlds[0][base]     = make_int4((int)p0.h, (int)p1.h, (int)p2.h, (int)p3.h);
            *(int4*)&Vlds[0][base + 8] = make_int4((int)p4.h, (int)p5.h, (int)p6.h, (int)p7.h);
            *(int4*)&Vlds[1][base]     = make_int4((int)p0.m, (int)p1.m, (int)p2.m, (int)p3.m);
            *(int4*)&Vlds[1][base + 8] = make_int4((int)p4.m, (int)p5.m, (int)p6.m, (int)p7.m);
            *(int4*)&Vlds[2][base]     = make_int4((int)p0.l, (int)p1.l, (int)p2.l, (int)p3.l);
            *(int4*)&Vlds[2][base + 8] = make_int4((int)p4.l, (int)p5.l, (int)p6.l, (int)p7.l);
            if (tid < 128) {
                const int bw_ = wrow * AST + whalf * 16;
                *(int4*)&Wlds[0][bw_]     = w00;
                *(int4*)&Wlds[0][bw_ + 8] = w01;
                *(int4*)&Wlds[1][bw_]     = w10;
                *(int4*)&Wlds[1][bw_ + 8] = w11;
                *(int4*)&Wlds[2][bw_]     = w20;
                *(int4*)&Wlds[2][bw_ + 8] = w21;
            }
        }
        __syncthreads();
        if (it + 1 < 8) LEAF_LOADS(it + 1);
        {
            short8 vf[4][3];
#pragma unroll
            for (int Nt = 0; Nt < 4; ++Nt) {
                const int rb = (bw * 64 + Nt * 16 + (lane & 15)) * AST + (lane >> 4) * 8;
#pragma unroll
                for (int s = 0; s < 3; ++s) vf[Nt][s] = *(const short8*)&Vlds[s][rb];
            }
#pragma unroll
            for (int g = 0; g < 2; ++g) {
                const int cb = (g * 32 + ni * 16 + (lane & 15)) * AST + (lane >> 4) * 8;
                short8 wh = *(const short8*)&Wlds[0][cb];
                short8 wm = *(const short8*)&Wlds[1][cb];
                short8 wl = *(const short8*)&Wlds[2][cb];
#pragma unroll
                for (int Nt = 0; Nt < 4; ++Nt)
                    acc[g][Nt] = __builtin_amdgcn_mfma_f32_16x16x32_bf16(wl, vf[Nt][0], acc[g][Nt], 0, 0, 0);
#pragma unroll
                for (int Nt = 0; Nt < 4; ++Nt)
                    acc[g][Nt] = __builtin_amdgcn_mfma_f32_16x16x32_bf16(wh, vf[Nt][2], acc[g][Nt], 0, 0, 0);
#pragma unroll
                for (int Nt = 0; Nt < 4; ++Nt)
                    acc[g][Nt] = __builtin_amdgcn_mfma_f32_16x16x32_bf16(wm, vf[Nt][1], acc[g][Nt], 0, 0, 0);
#pragma unroll
                for (int Nt = 0; Nt < 4; ++Nt)
                    acc[g][Nt] = __builtin_amdgcn_mfma_f32_16x16x32_bf16(wm, vf[Nt][0], acc[g][Nt], 0, 0, 0);
#pragma unroll
                for (int Nt = 0; Nt < 4; ++Nt)
                    acc[g][Nt] = __builtin_amdgcn_mfma_f32_16x16x32_bf16(wh, vf[Nt][1], acc[g][Nt], 0, 0, 0);
#pragma unroll
                for (int Nt = 0; Nt < 4; ++Nt)
                    acc[g][Nt] = __builtin_amdgcn_mfma_f32_16x16x32_bf16(wh, vf[Nt][0], acc[g][Nt], 0, 0, 0);
            }
        }
    }
#undef LEAF_LOADS

    // ----- leaf epilogue (fully in-lane: acc[0]=c lin, acc[1]=o lin) -----
    const int nc = gy * 32 + ni * 16 + ((lane >> 4) << 2);
    const size_t ob = (size_t)ln * BATCH * LDIM;
    const float4 bc4 = *(const float4*)&bias_leaf[nc];
    const float4 bo4 = *(const float4*)&bias_leaf[256 + nc];
    const float bc_[4] = {bc4.x, bc4.y, bc4.z, bc4.w};
    const float bo_[4] = {bo4.x, bo4.y, bo4.z, bo4.w};
#pragma unroll
    for (int Nt = 0; Nt < 4; ++Nt) {
        const int b = bw * 64 + Nt * 16 + (lane & 15);
        float4 c4, h4;
        float* cp = (float*)&c4; float* hp = (float*)&h4;
#pragma unroll
        for (int j = 0; j < 4; ++j) {
            float c = acc[0][Nt][j] + bc_[j];
            float o = acc[1][Nt][j] + bo_[j];
            cp[j] = c;
            hp[j] = sigmoidf_(o) * tanhf(c);
        }
        size_t po = ob + (size_t)b * LDIM + nc;
        *(float4*)&cOut[po] = c4;
        *(float4*)&hOut[po] = h4;
    }
}

// ---------------------------------------------------------------------------
// Leaf kernel (round-1/4 proven fp32 fallback). grid (1024, 4), block 256.
__global__ __launch_bounds__(256) void leaf_kernel(
    const float* __restrict__ x_embed,
    const float* __restrict__ Wleaf, const float* __restrict__ bias_leaf,
    float* __restrict__ hOut, float* __restrict__ cOut)
{
    __shared__ float As[16 * 68];
    __shared__ float Bs[2 * 16 * 64];
    float acc[2][4][4] = {};
    const int tid = threadIdx.x;
    const int ty = tid >> 4, tx = tid & 15;
    const int row0 = blockIdx.x * 64;
    const int n0 = blockIdx.y * 64;
    const int w = row0 >> 7;
    const int ar = tid >> 2;
    const int kq = (tid & 3) * 4;
    const int b = (row0 + ar) & 127;
    const float* xrow = x_embed + ((size_t)b * NNODES + 511 + w) * LDIM;

    for (int k0 = 0; k0 < 256; k0 += 16) {
        float4 av = *(const float4*)(xrow + k0 + kq);
        As[(kq + 0) * 68 + ar] = av.x;
        As[(kq + 1) * 68 + ar] = av.y;
        As[(kq + 2) * 68 + ar] = av.z;
        As[(kq + 3) * 68 + ar] = av.w;
#pragma unroll
        for (int q = 0; q < 2; ++q) {
            int L = q * 256 + tid;
            int g = L >> 8, kk = (L >> 4) & 15, n4 = (L & 15) * 4;
            float4 bv = *(const float4*)(Wleaf + (size_t)(k0 + kk) * 512 + g * 256 + n0 + n4);
            *(float4*)&Bs[(g * 16 + kk) * 64 + n4] = bv;
        }
        __syncthreads();
#pragma unroll
        for (int kk = 0; kk < 16; ++kk) {
            float4 a = *(const float4*)&As[kk * 68 + ty * 4];
            float av4[4] = {a.x, a.y, a.z, a.w};
#pragma unroll
            for (int g = 0; g < 2; ++g) {
                float4 bb = *(const float4*)&Bs[(g * 16 + kk) * 64 + tx * 4];
                float bv4[4] = {bb.x, bb.y, bb.z, bb.w};
#pragma unroll
                for (int ii = 0; ii < 4; ++ii)
#pragma unroll
                    for (int jj = 0; jj < 4; ++jj)
                        acc[g][ii][jj] += av4[ii] * bv4[jj];
            }
        }
        __syncthreads();
    }
#pragma unroll
    for (int ii = 0; ii < 4; ++ii) {
        int r = row0 + ty * 4 + ii;
        int nc = n0 + tx * 4;
        float4 c4, h4;
        float* cp = (float*)&c4; float* hp = (float*)&h4;
#pragma unroll
        for (int jj = 0; jj < 4; ++jj) {
            int n = nc + jj;
            float ac = acc[0][ii][jj] + bias_leaf[n];
            float ao = acc[1][ii][jj] + bias_leaf[256 + n];
            cp[jj] = ac;
            hp[jj] = sigmoidf_(ao) * tanhf(ac);
        }
        *(float4*)&cOut[(size_t)r * LDIM + nc] = c4;
        *(float4*)&hOut[(size_t)r * LDIM + nc] = h4;
    }
}

// ---------------------------------------------------------------------------
// fp32 level kernel (round-1/4 proven). grid (W*2, 4), block 256.
__global__ __launch_bounds__(256) void level_kernel(
    const float* __restrict__ x_embed,
    const float* __restrict__ hChild, const float* __restrict__ cChild,
    const float* __restrict__ Wbig, const float* __restrict__ bias_big,
    float* __restrict__ hOut, float* __restrict__ cOut,
    int nstart)
{
    __shared__ float As[16 * 68];
    __shared__ float Bs[4 * 16 * 64];
    float acc[4][4][4] = {};
    const int tid = threadIdx.x;
    const int ty = tid >> 4, tx = tid & 15;
    const int row0 = blockIdx.x * 64;
    const int n0 = blockIdx.y * 64;
    const int w = row0 >> 7;
    const int ar = tid >> 2;
    const int kq = (tid & 3) * 4;
    const int b = (row0 + ar) & 127;
    const float* srcX = x_embed + ((size_t)b * NNODES + nstart + w) * LDIM;
    const float* srcL = hChild + ((size_t)(2 * w) * BATCH + b) * LDIM;
    const float* srcR = hChild + ((size_t)(2 * w + 1) * BATCH + b) * LDIM;

    for (int k0 = 0; k0 < 768; k0 += 16) {
        int seg = k0 >> 8, off = k0 & 255;
        const float* src = (seg == 0) ? srcX : (seg == 1) ? srcL : srcR;
        float4 av = *(const float4*)(src + off + kq);
        As[(kq + 0) * 68 + ar] = av.x;
        As[(kq + 1) * 68 + ar] = av.y;
        As[(kq + 2) * 68 + ar] = av.z;
        As[(kq + 3) * 68 + ar] = av.w;
#pragma unroll
        for (int q = 0; q < 4; ++q) {
            int L = q * 256 + tid;
            int g = L >> 8, kk = (L >> 4) & 15, n4 = (L & 15) * 4;
            float4 bv = *(const float4*)(Wbig + (size_t)(k0 + kk) * 1024 + g * 256 + n0 + n4);
            *(float4*)&Bs[(g * 16 + kk) * 64 + n4] = bv;
        }
        __syncthreads();
#pragma unroll
        for (int kk = 0; kk < 16; ++kk) {
            float4 a = *(const float4*)&As[kk * 68 + ty * 4];
            float av4[4] = {a.x, a.y, a.z, a.w};
#pragma unroll
            for (int g = 0; g < 4; ++g) {
                float4 bb = *(const float4*)&Bs[(g * 16 + kk) * 64 + tx * 4];
                float bv4[4] = {bb.x, bb.y, bb.z, bb.w};
#pragma unroll
                for (int ii = 0; ii < 4; ++ii)
#pragma unroll
                    for (int jj = 0; jj < 4; ++jj)
                        acc[g][ii][jj] += av4[ii] * bv4[jj];
            }
        }
        __syncthreads();
    }
    const size_t cLbase = ((size_t)(2 * w) * BATCH) * LDIM;
    const size_t cRbase = ((size_t)(2 * w + 1) * BATCH) * LDIM;
#pragma unroll
    for (int ii = 0; ii < 4; ++ii) {
        int r = row0 + ty * 4 + ii;
        int bb2 = r & 127;
        int nc = n0 + tx * 4;
        float4 cL = *(const float4*)&cChild[cLbase + (size_t)bb2 * LDIM + nc];
        float4 cR = *(const float4*)&cChild[cRbase + (size_t)bb2 * LDIM + nc];
        float cl4[4] = {cL.x, cL.y, cL.z, cL.w};
        float cr4[4] = {cR.x, cR.y, cR.z, cR.w};
        float4 c4, h4;
        float* cp = (float*)&c4; float* hp = (float*)&h4;
#pragma unroll
        for (int jj = 0; jj < 4; ++jj) {
            int n = nc + jj;
            float gi = sigmoidf_(acc[0][ii][jj] + bias_big[n]);
            float gu = tanhf(acc[1][ii][jj] + bias_big[256 + n]);
            float f0 = acc[2][ii][jj] + bias_big[512 + n];
            float f1 = acc[3][ii][jj] + bias_big[768 + n];
            float c = gi * gu + f0 * cl4[jj] + f1 * cr4[jj];
            cp[jj] = c;
            hp[jj] = tanhf(c);
        }
        *(float4*)&cOut[(size_t)r * LDIM + nc] = c4;
        *(float4*)&hOut[(size_t)r * LDIM + nc] = h4;
    }
}

// ---------------------------------------------------------------------------
// Split-K partial (TM=4, one 256-wide K segment per blockIdx.z). grid (W*2,4,3).
__global__ __launch_bounds__(256) void gemm_part4(
    const float* __restrict__ x_embed, const float* __restrict__ hChild,
    const float* __restrict__ Wbig,
    float* __restrict__ part, int nstart, int rowsTotal)
{
    __shared__ float As[16 * 68];
    __shared__ float Bs[4 * 16 * 64];
    float acc[4][4][4] = {};
    const int tid = threadIdx.x;
    const int ty = tid >> 4, tx = tid & 15;
    const int row0 = blockIdx.x * 64;
    const int n0 = blockIdx.y * 64;
    const int seg = blockIdx.z;
    const int w = row0 >> 7;
    const int ar = tid >> 2;
    const int kq = (tid & 3) * 4;
    const int b = (row0 + ar) & 127;
    const float* src =
        (seg == 0) ? x_embed + ((size_t)b * NNODES + nstart + w) * LDIM
                   : hChild + ((size_t)(2 * w + (seg - 1)) * BATCH + b) * LDIM;

    for (int k0 = 0; k0 < 256; k0 += 16) {
        float4 av = *(const float4*)(src + k0 + kq);
        As[(kq + 0) * 68 + ar] = av.x;
        As[(kq + 1) * 68 + ar] = av.y;
        As[(kq + 2) * 68 + ar] = av.z;
        As[(kq + 3) * 68 + ar] = av.w;
#pragma unroll
        for (int q = 0; q < 4; ++q) {
            int L = q * 256 + tid;
            int g = L >> 8, kk = (L >> 4) & 15, n4 = (L & 15) * 4;
            float4 bv = *(const float4*)(Wbig + (size_t)(seg * 256 + k0 + kk) * 1024
                                         + g * 256 + n0 + n4);
            *(float4*)&Bs[(g * 16 + kk) * 64 + n4] = bv;
        }
        __syncthreads();
#pragma unroll
        for (int kk = 0; kk < 16; ++kk) {
            float4 a = *(const float4*)&As[kk * 68 + ty * 4];
            float av4[4] = {a.x, a.y, a.z, a.w};
#pragma unroll
            for (int g = 0; g < 4; ++g) {
                float4 bb = *(const float4*)&Bs[(g * 16 + kk) * 64 + tx * 4];
                float bv4[4] = {bb.x, bb.y, bb.z, bb.w};
#pragma unroll
                for (int ii = 0; ii < 4; ++ii)
#pragma unroll
                    for (int jj = 0; jj < 4; ++jj)
                        acc[g][ii][jj] += av4[ii] * bv4[jj];
            }
        }
        __syncthreads();
    }
#pragma unroll
    for (int ii = 0; ii < 4; ++ii) {
        int r = row0 + ty * 4 + ii;
        size_t base = ((size_t)seg * rowsTotal + r) * 1024 + n0 + tx * 4;
#pragma unroll
        for (int g = 0; g < 4; ++g)
            *(float4*)&part[base + g * 256] = *(float4*)acc[g][ii];
    }
}

// ---------------------------------------------------------------------------
// Combine 3 split-K partials + LSTM epilogue. grid (rows/4), block 256.
__global__ __launch_bounds__(256) void combine_eps(
    const float* __restrict__ part, const float* __restrict__ cChild,
    const float* __restrict__ bias,
    float* __restrict__ hOut, float* __restrict__ cOut, int rowsTotal)
{
    int idx = blockIdx.x * 256 + threadIdx.x;
    int row = idx >> 6, n = (idx & 63) * 4;
    size_t sseg = (size_t)rowsTotal * 1024;
    const float* p0 = part + (size_t)row * 1024 + n;
    float s[4][4];
#pragma unroll
    for (int g = 0; g < 4; ++g) {
        float4 a = *(const float4*)(p0 + g * 256);
        float4 b = *(const float4*)(p0 + sseg + g * 256);
        float4 c = *(const float4*)(p0 + 2 * sseg + g * 256);
        s[g][0] = a.x + b.x + c.x; s[g][1] = a.y + b.y + c.y;
        s[g][2] = a.z + b.z + c.z; s[g][3] = a.w + b.w + c.w;
    }
    int node = row >> 7, b = row & 127;
    float4 cL = *(const float4*)&cChild[((size_t)(2 * node) * BATCH + b) * LDIM + n];
    float4 cR = *(const float4*)&cChild[((size_t)(2 * node + 1) * BATCH + b) * LDIM + n];
    float cl4[4] = {cL.x, cL.y, cL.z, cL.w};
    float cr4[4] = {cR.x, cR.y, cR.z, cR.w};
    float4 c4, h4;
    float* cp = (float*)&c4; float* hp = (float*)&h4;
#pragma unroll
    for (int jj = 0; jj < 4; ++jj) {
        int nn = n + jj;
        float gi = sigmoidf_(s[0][jj] + bias[nn]);
        float gu = tanhf(s[1][jj] + bias[256 + nn]);
        float f0 = s[2][jj] + bias[512 + nn];
        float f1 = s[3][jj] + bias[768 + nn];
        float c = gi * gu + f0 * cl4[jj] + f1 * cr4[jj];
        cp[jj] = c;
        hp[jj] = tanhf(c);
    }
    *(float4*)&cOut[(size_t)row * LDIM + n] = c4;
    *(float4*)&hOut[(size_t)row * LDIM + n] = h4;
}

// ---------------------------------------------------------------------------
// Final: out[b][n] = tanh([init | c_root | h_root] @ Woend + boend). grid 128.
__global__ __launch_bounds__(256) void final_kernel(
    const float* __restrict__ init_emb,
    const float* __restrict__ cRoot, const float* __restrict__ hRoot,
    const float* __restrict__ Woend, const float* __restrict__ boend,
    float* __restrict__ out)
{
    __shared__ float sv[768];
    int b = blockIdx.x, t = threadIdx.x;
    sv[t]       = init_emb[(size_t)b * 256 + t];
    sv[256 + t] = cRoot[(size_t)b * 256 + t];
    sv[512 + t] = hRoot[(size_t)b * 256 + t];
    __syncthreads();
    float acc = boend[t];
#pragma unroll 4
    for (int d = 0; d < 768; ++d)
        acc += sv[d] * Woend[(size_t)d * 256 + t];
    out[(size_t)b * 256 + t] = tanhf(acc);
}

// ---------------------------------------------------------------------------
extern "C" void kernel_launch(void* const* d_in, const int* in_sizes, int n_in,
                              void* d_out, int out_size, void* d_ws, size_t ws_size,
                              hipStream_t stream)
{
    const float* x_embed  = (const float*)d_in[0];
    const float* init_emb = (const float*)d_in[1];
    const float* Wcx = (const float*)d_in[2];  const float* bcx = (const float*)d_in[3];
    const float* Wox = (const float*)d_in[4];  const float* box = (const float*)d_in[5];
    const float* Wix = (const float*)d_in[6];  const float* bix = (const float*)d_in[7];
    const float* Wfx = (const float*)d_in[8];  const float* bfx = (const float*)d_in[9];
    const float* Wux = (const float*)d_in[10]; const float* bux = (const float*)d_in[11];
    const float* Wi  = (const float*)d_in[12]; const float* bi  = (const float*)d_in[13];
    const float* Wf  = (const float*)d_in[14]; const float* bf  = (const float*)d_in[15];
    const float* Wu  = (const float*)d_in[16]; const float* bu  = (const float*)d_in[17];
    const float* Woend = (const float*)d_in[18]; const float* boend = (const float*)d_in[19];
    float* out = (float*)d_out;
    float* ws  = (float*)d_ws;

    size_t off = 0;
    float* hA = ws + off; off += (size_t)512 * 128 * 256;
    float* cA = ws + off; off += (size_t)512 * 128 * 256;
    float* hB = ws + off; off += (size_t)256 * 128 * 256;
    float* cB = ws + off; off += (size_t)256 * 128 * 256;
    float* Wbig      = ws + off; off += (size_t)768 * 1024;
    float* bias_big  = ws + off; off += 1024;
    float* Wleaf     = ws + off; off += (size_t)256 * 512;
    float* bias_leaf = ws + off; off += 512;
    // bf16 weight splits, transposed [n][k]
    ushort* Wth = (ushort*)(ws + off); off += (size_t)768 * 1024 / 2;
    ushort* Wtm = (ushort*)(ws + off); off += (size_t)768 * 1024 / 2;
    ushort* Wtl = (ushort*)(ws + off); off += (size_t)768 * 1024 / 2;
    // leaf weight splits, transposed [n=512][k=256]
    ushort* Lth = (ushort*)(ws + off); off += (size_t)512 * 256 / 2;
    ushort* Ltm = (ushort*)(ws + off); off += (size_t)512 * 256 / 2;
    ushort* Ltl = (ushort*)(ws + off); off += (size_t)512 * 256 / 2;
    size_t mfma_need = off * sizeof(float);
    size_t part_off = off;
    float* part = ws + part_off;

    bool mfma_ok = mfma_need <= ws_size;

    {
        int total = 768 * 1024 + 1024 + 256 * 512 + 512;
        int blocks = (total + 255) / 256;
        build_weights<<<blocks, 256, 0, stream>>>(
            Wix, bix, Wfx, bfx, Wux, bux, Wi, bi, Wf, bf, Wu, bu,
            Wcx, bcx, Wox, box, Wbig, bias_big, Wleaf, bias_leaf);
    }
    if (mfma_ok) {
        split_weights_T<<<dim3(24, 32), 256, 0, stream>>>(Wbig, Wth, Wtm, Wtl);
        split_wleaf_T<<<dim3(8, 16), 256, 0, stream>>>(Wleaf, Lth, Ltm, Ltl);
    }

    if (mfma_ok) {
        leaf_mfma<<<dim3(512, 8), 256, 0, stream>>>(
            x_embed, Lth, Ltm, Ltl, bias_leaf, hA, cA);
    } else {
        leaf_kernel<<<dim3(1024, 4), 256, 0, stream>>>(
            x_embed, Wleaf, bias_leaf, hA, cA);
    }

    float* hbufs[2] = {hA, hB};
    float* cbufs[2] = {cA, cB};
    int child = 0;  // leaves in A
    for (int lvl = 8; lvl >= 0; --lvl) {
        int W = 1 << lvl, s = W - 1;
        int outb = child ^ 1;
        size_t rows = (size_t)W * 128;
        bool split = (W <= 16) &&
                     ((part_off + 3 * rows * 1024) * sizeof(float) <= ws_size);
        if (lvl >= 5 && mfma_ok) {
            mfma_level_pack<<<dim3(W, 8), 256, 0, stream>>>(
                x_embed, hbufs[child], cbufs[child], Wth, Wtm, Wtl, bias_big,
                hbufs[outb], cbufs[outb], s);
        } else if (split) {
            gemm_part4<<<dim3(W * 2, 4, 3), 256, 0, stream>>>(
                x_embed, hbufs[child], Wbig, part, s, (int)rows);
            combine_eps<<<(int)(rows / 4), 256, 0, stream>>>(
                part, cbufs[child], bias_big, hbufs[outb], cbufs[outb], (int)rows);
        } else {
            level_kernel<<<dim3(W * 2, 4), 256, 0, stream>>>(
                x_embed, hbufs[child], cbufs[child], Wbig, bias_big,
                hbufs[outb], cbufs[outb], s);
        }
        child = outb;
    }

    final_kernel<<<128, 256, 0, stream>>>(init_emb, cbufs[child], hbufs[child],
                                          Woend, boend, out);
}

// Round 14
// 1079.532 us; speedup vs baseline: 1.3855x; 1.0074x over previous
//
#include <hip/hip_runtime.h>
#include <hip/hip_bf16.h>
#include <math.h>

// Tree-LSTM "LogicEncoder": D=10, N=1023 nodes, B=128, LD=256, K=2.
// Round 14: restructure mfma_level_pack — activations bypass LDS entirely.
// Each lane loads its own B-fragment (8 consecutive fp32 of one batch row)
// directly from global and splits in-register (wave = batch quarter; every
// element loaded+split exactly once per block). Only weights use LDS:
// 61440 -> 30720 B => 3 blocks/CU (launch_bounds(256,3), VGPR cap 170 >
// ~150 live). Same accumulation order per output -> bitwise-identical.
// Leaf + fallbacks byte-identical to round 13.

#define NNODES 1023
#define BATCH  128
#define LDIM   256

typedef __attribute__((ext_vector_type(8))) short short8;
typedef __attribute__((ext_vector_type(4))) float f32x4;

__device__ __forceinline__ float sigmoidf_(float x) {
    return 1.f / (1.f + expf(-x));
}

// fp32 -> 3x bf16, RNE at each stage; residuals exact. (weight-split kernels)
__device__ __forceinline__ void split3(float x, ushort& h, ushort& m, ushort& l) {
    unsigned u = __float_as_uint(x);
    unsigned hu = (u + 0x7FFFu + ((u >> 16) & 1u)) & 0xFFFF0000u;
    h = (ushort)(hu >> 16);
    float r = x - __uint_as_float(hu);
    unsigned ur = __float_as_uint(r);
    unsigned mu = (ur + 0x7FFFu + ((ur >> 16) & 1u)) & 0xFFFF0000u;
    m = (ushort)(mu >> 16);
    float r2 = r - __uint_as_float(mu);
    unsigned u2 = __float_as_uint(r2);
    l = (ushort)((u2 + 0x7FFFu + ((u2 >> 16) & 1u)) >> 16);
}

// HW pair convert: dst = [bf16(hi):bf16(lo)], RNE (bitwise == split3).
__device__ __forceinline__ unsigned cvt_pk_bf16(float lo, float hi) {
    unsigned r;
    asm("v_cvt_pk_bf16_f32 %0, %1, %2" : "=v"(r) : "v"(lo), "v"(hi));
    return r;
}

struct P3 { unsigned h, m, l; };
__device__ __forceinline__ P3 pack2v(float x0, float x1) {
    P3 p;
    p.h = cvt_pk_bf16(x0, x1);
    float h0 = __uint_as_float(p.h << 16);
    float h1 = __uint_as_float(p.h & 0xFFFF0000u);
    float r0 = x0 - h0, r1 = x1 - h1;
    p.m = cvt_pk_bf16(r0, r1);
    float m0 = __uint_as_float(p.m << 16);
    float m1 = __uint_as_float(p.m & 0xFFFF0000u);
    p.l = cvt_pk_bf16(r0 - m0, r1 - m1);
    return p;
}

// split 8 fp32 (two float4) into three bf16x8 MFMA fragments, by value.
struct VF { short8 h, m, l; };
__device__ __forceinline__ VF split8(float4 a, float4 b) {
    P3 p0 = pack2v(a.x, a.y), p1 = pack2v(a.z, a.w);
    P3 p2 = pack2v(b.x, b.y), p3 = pack2v(b.z, b.w);
    VF r;
    r.h = __builtin_bit_cast(short8, make_uint4(p0.h, p1.h, p2.h, p3.h));
    r.m = __builtin_bit_cast(short8, make_uint4(p0.m, p1.m, p2.m, p3.m));
    r.l = __builtin_bit_cast(short8, make_uint4(p0.l, p1.l, p2.l, p3.l));
    return r;
}

// ---------------------------------------------------------------------------
// Pack Wbig (768x1024) + bias_big(1024) + Wleaf(256x512) + bias_leaf(512).
__global__ __launch_bounds__(256) void build_weights(
    const float* __restrict__ Wix, const float* __restrict__ bix,
    const float* __restrict__ Wfx, const float* __restrict__ bfx,
    const float* __restrict__ Wux, const float* __restrict__ bux,
    const float* __restrict__ Wi,  const float* __restrict__ bi,
    const float* __restrict__ Wf,  const float* __restrict__ bf,
    const float* __restrict__ Wu,  const float* __restrict__ bu,
    const float* __restrict__ Wcx, const float* __restrict__ bcx,
    const float* __restrict__ Wox, const float* __restrict__ box,
    float* __restrict__ Wbig, float* __restrict__ bias_big,
    float* __restrict__ Wleaf, float* __restrict__ bias_leaf)
{
    int i = blockIdx.x * blockDim.x + threadIdx.x;
    if (i < 768 * 1024) {
        int k = i >> 10, n = i & 1023;
        int g = n >> 8, nn = n & 255;
        float v;
        if (g == 0) {
            v = (k < 256) ? Wix[k * 256 + nn]
              : (k < 512) ? Wi[(k - 256) * 256 + nn]
                          : Wi[65536 + (k - 512) * 256 + nn];
        } else if (g == 1) {
            v = (k < 256) ? Wux[k * 256 + nn]
              : (k < 512) ? Wu[(k - 256) * 256 + nn]
                          : Wu[65536 + (k - 512) * 256 + nn];
        } else {
            int kf = g - 2;  // f0 / f1
            v = (k < 256) ? Wfx[k * 256 + nn]
              : (k < 512) ? Wf[((kf * 2 + 0) * 256 + (k - 256)) * 256 + nn]
                          : Wf[((kf * 2 + 1) * 256 + (k - 512)) * 256 + nn];
        }
        Wbig[i] = v;
        return;
    }
    i -= 768 * 1024;
    if (i < 1024) {
        int g = i >> 8, nn = i & 255;
        float v;
        if (g == 0)      v = bix[nn] + bi[nn] + bi[256 + nn];
        else if (g == 1) v = bux[nn] + bu[nn] + bu[256 + nn];
        else if (g == 2) v = bfx[nn] + bf[nn] + bf[256 + nn];
        else             v = bfx[nn] + bf[512 + nn] + bf[768 + nn];
        bias_big[i] = v;
        return;
    }
    i -= 1024;
    if (i < 256 * 512) {
        int k = i >> 9, n = i & 511;
        Wleaf[i] = (n < 256) ? Wcx[k * 256 + n] : Wox[k * 256 + (n - 256)];
        return;
    }
    i -= 256 * 512;
    if (i < 512) {
        bias_leaf[i] = (i < 256) ? bcx[i] : box[i - 256];
    }
}

// ---------------------------------------------------------------------------
// Split Wbig into 3 bf16 planes TRANSPOSED: Wt_s[n][k] (1024 x 768).
__global__ __launch_bounds__(256) void split_weights_T(
    const float* __restrict__ Wbig,
    ushort* __restrict__ Wth, ushort* __restrict__ Wtm, ushort* __restrict__ Wtl)
{
    __shared__ float sh[32][33];
    const int k0 = blockIdx.x * 32, n0 = blockIdx.y * 32;
    const int t = threadIdx.x;
    {
        int r = t >> 3, c4 = (t & 7) * 4;
        float4 v = *(const float4*)&Wbig[(size_t)(k0 + r) * 1024 + n0 + c4];
        sh[r][c4] = v.x; sh[r][c4 + 1] = v.y; sh[r][c4 + 2] = v.z; sh[r][c4 + 3] = v.w;
    }
    __syncthreads();
    int n = t >> 3, kc = (t & 7) * 4;
    ushort oh[4], om[4], ol[4];
#pragma unroll
    for (int j = 0; j < 4; ++j)
        split3(sh[kc + j][n], oh[j], om[j], ol[j]);
    size_t o = (size_t)(n0 + n) * 768 + k0 + kc;
    *(ushort4*)&Wth[o] = make_ushort4(oh[0], oh[1], oh[2], oh[3]);
    *(ushort4*)&Wtm[o] = make_ushort4(om[0], om[1], om[2], om[3]);
    *(ushort4*)&Wtl[o] = make_ushort4(ol[0], ol[1], ol[2], ol[3]);
}

// ---------------------------------------------------------------------------
// Split Wleaf (256x512) into 3 bf16 planes TRANSPOSED: Lt_s[n][k] (512 x 256).
__global__ __launch_bounds__(256) void split_wleaf_T(
    const float* __restrict__ Wleaf,
    ushort* __restrict__ Lth, ushort* __restrict__ Ltm, ushort* __restrict__ Ltl)
{
    __shared__ float sh[32][33];
    const int k0 = blockIdx.x * 32, n0 = blockIdx.y * 32;
    const int t = threadIdx.x;
    {
        int r = t >> 3, c4 = (t & 7) * 4;
        float4 v = *(const float4*)&Wleaf[(size_t)(k0 + r) * 512 + n0 + c4];
        sh[r][c4] = v.x; sh[r][c4 + 1] = v.y; sh[r][c4 + 2] = v.z; sh[r][c4 + 3] = v.w;
    }
    __syncthreads();
    int n = t >> 3, kc = (t & 7) * 4;
    ushort oh[4], om[4], ol[4];
#pragma unroll
    for (int j = 0; j < 4; ++j)
        split3(sh[kc + j][n], oh[j], om[j], ol[j]);
    size_t o = (size_t)(n0 + n) * 256 + k0 + kc;
    *(ushort4*)&Lth[o] = make_ushort4(oh[0], oh[1], oh[2], oh[3]);
    *(ushort4*)&Ltm[o] = make_ushort4(om[0], om[1], om[2], om[3]);
    *(ushort4*)&Ltl[o] = make_ushort4(ol[0], ol[1], ol[2], ol[3]);
}

// ---------------------------------------------------------------------------
// bf16x3 MFMA level kernel, weights-only LDS + direct per-lane activation
// loads. grid (W, 8): blockIdx.x = node (node%8 -> XCD), blockIdx.y = gy.
// Wave = batch quarter (32 rows); each wave computes 8 col-tiles (4 gates x 2).
__global__ __launch_bounds__(256, 3) void mfma_level_pack(
    const float* __restrict__ x_embed,
    const float* __restrict__ hChild, const float* __restrict__ cChild,
    const ushort* __restrict__ Wth, const ushort* __restrict__ Wtm,
    const ushort* __restrict__ Wtl,
    const float* __restrict__ bias,
    float* __restrict__ hOut, float* __restrict__ cOut, int nstart)
{
    constexpr int AST = 40;
    __shared__ __align__(16) ushort Wlds[3][128 * AST];   // weights only

    const int tid  = threadIdx.x;
    const int node = blockIdx.x;
    const int gy   = blockIdx.y;
    const int lane = tid & 63, wid = tid >> 6;            // wave = batch quarter
    const int srow = tid & 127, shalf = tid >> 7;

    // weight staging source (per thread row)
    const size_t nb = (size_t)(((srow >> 5) << 8) + gy * 32 + (srow & 31)) * 768;
    const ushort* w0 = Wth + nb;
    const ushort* w1 = Wtm + nb;
    const ushort* w2 = Wtl + nb;

    // per-lane activation row pointers (pre-offset by lane's k-slice)
    const int b0 = wid * 32 + (lane & 15);                // Nt=0 row
    const int b1 = b0 + 16;                               // Nt=1 row
    const int kl = (lane >> 4) * 8;
    const float* x0p = x_embed + ((size_t)b0 * NNODES + (nstart + node)) * LDIM + kl;
    const float* x1p = x_embed + ((size_t)b1 * NNODES + (nstart + node)) * LDIM + kl;
    const float* l0p = hChild + ((size_t)(2 * node) * BATCH + b0) * LDIM + kl;
    const float* l1p = hChild + ((size_t)(2 * node) * BATCH + b1) * LDIM + kl;
    const size_t RSTEP = (size_t)BATCH * LDIM;            // hL -> hR offset

    f32x4 acc[8][2];   // [col-tile ct = gate*2+half][batch tile Nt]
#pragma unroll
    for (int ct = 0; ct < 8; ++ct)
#pragma unroll
        for (int t2 = 0; t2 < 2; ++t2) acc[ct][t2] = (f32x4){0.f, 0.f, 0.f, 0.f};

    // staging registers — named, never address-taken
    float4 v00, v01, v10, v11;                 // act Nt0 / Nt1 (8 fp32 each)
    int4 w00, w01, w10, w11, w20, w21;         // weight staging

#define TREE_LOADS(IT)                                                         \
    {                                                                          \
        const int seg_  = (IT) >> 3;                                           \
        const int koff_ = ((IT) & 7) * 32;                                     \
        const float* pa0_ = (seg_ == 0) ? x0p : (seg_ == 1) ? l0p : (l0p + RSTEP); \
        const float* pa1_ = (seg_ == 0) ? x1p : (seg_ == 1) ? l1p : (l1p + RSTEP); \
        pa0_ += koff_; pa1_ += koff_;                                          \
        v00 = *(const float4*)(pa0_);                                          \
        v01 = *(const float4*)(pa0_ + 4);                                      \
        v10 = *(const float4*)(pa1_);                                          \
        v11 = *(const float4*)(pa1_ + 4);                                      \
        const int bko_ = (IT) * 32 + shalf * 16;                               \
        w00 = *(const int4*)(w0 + bko_); w01 = *(const int4*)(w0 + bko_ + 8);  \
        w10 = *(const int4*)(w1 + bko_); w11 = *(const int4*)(w1 + bko_ + 8);  \
        w20 = *(const int4*)(w2 + bko_); w21 = *(const int4*)(w2 + bko_ + 8);  \
    }

    TREE_LOADS(0);
    for (int it = 0; it < 24; ++it) {
        if (it) __syncthreads();
        {   // stage weights (only LDS traffic)
            const int base = srow * AST + shalf * 16;
            *(int4*)&Wlds[0][base]     = w00;
            *(int4*)&Wlds[0][base + 8] = w01;
            *(int4*)&Wlds[1][base]     = w10;
            *(int4*)&Wlds[1][base + 8] = w11;
            *(int4*)&Wlds[2][base]     = w20;
            *(int4*)&Wlds[2][base + 8] = w21;
        }
        __syncthreads();
        // split current activations into fragments (in-register, no LDS)
        VF f0 = split8(v00, v01);
        VF f1 = split8(v10, v11);
        if (it + 1 < 24) TREE_LOADS(it + 1);   // prefetch next K-step
        // 96 MFMAs/wave, same small->large order per output tile as r9-r13
#pragma unroll
        for (int ct = 0; ct < 8; ++ct) {
            const int cb = (ct * 16 + (lane & 15)) * AST + (lane >> 4) * 8;
            short8 wh = *(const short8*)&Wlds[0][cb];
            short8 wm = *(const short8*)&Wlds[1][cb];
            short8 wl = *(const short8*)&Wlds[2][cb];
            acc[ct][0] = __builtin_amdgcn_mfma_f32_16x16x32_bf16(wl, f0.h, acc[ct][0], 0, 0, 0);
            acc[ct][1] = __builtin_amdgcn_mfma_f32_16x16x32_bf16(wl, f1.h, acc[ct][1], 0, 0, 0);
            acc[ct][0] = __builtin_amdgcn_mfma_f32_16x16x32_bf16(wh, f0.l, acc[ct][0], 0, 0, 0);
            acc[ct][1] = __builtin_amdgcn_mfma_f32_16x16x32_bf16(wh, f1.l, acc[ct][1], 0, 0, 0);
            acc[ct][0] = __builtin_amdgcn_mfma_f32_16x16x32_bf16(wm, f0.m, acc[ct][0], 0, 0, 0);
            acc[ct][1] = __builtin_amdgcn_mfma_f32_16x16x32_bf16(wm, f1.m, acc[ct][1], 0, 0, 0);
            acc[ct][0] = __builtin_amdgcn_mfma_f32_16x16x32_bf16(wm, f0.h, acc[ct][0], 0, 0, 0);
            acc[ct][1] = __builtin_amdgcn_mfma_f32_16x16x32_bf16(wm, f1.h, acc[ct][1], 0, 0, 0);
            acc[ct][0] = __builtin_amdgcn_mfma_f32_16x16x32_bf16(wh, f0.m, acc[ct][0], 0, 0, 0);
            acc[ct][1] = __builtin_amdgcn_mfma_f32_16x16x32_bf16(wh, f1.m, acc[ct][1], 0, 0, 0);
            acc[ct][0] = __builtin_amdgcn_mfma_f32_16x16x32_bf16(wh, f0.h, acc[ct][0], 0, 0, 0);
            acc[ct][1] = __builtin_amdgcn_mfma_f32_16x16x32_bf16(wh, f1.h, acc[ct][1], 0, 0, 0);
        }
    }
#undef TREE_LOADS

    // ----- fused LSTM epilogue (fp32 c-path, float4 stores) -----
    // D: col = batch (lane&15 within tile), row = weight col (lane>>4)*4+j.
    // gate g for col-half h lives in acc[2g+h]; cols nc..nc+3 consecutive.
    const size_t cLb = (size_t)(2 * node) * BATCH * LDIM;
    const size_t cRb = cLb + (size_t)BATCH * LDIM;
    const size_t ob  = (size_t)node * BATCH * LDIM;
#pragma unroll
    for (int half = 0; half < 2; ++half) {
        const int nc = gy * 32 + half * 16 + ((lane >> 4) << 2);
        const float4 bi4 = *(const float4*)&bias[nc];
        const float4 bu4 = *(const float4*)&bias[256 + nc];
        const float4 b04 = *(const float4*)&bias[512 + nc];
        const float4 b14 = *(const float4*)&bias[768 + nc];
        const float bi_[4] = {bi4.x, bi4.y, bi4.z, bi4.w};
        const float bu_[4] = {bu4.x, bu4.y, bu4.z, bu4.w};
        const float b0_[4] = {b04.x, b04.y, b04.z, b04.w};
        const float b1_[4] = {b14.x, b14.y, b14.z, b14.w};
#pragma unroll
        for (int Nt = 0; Nt < 2; ++Nt) {
            const int b = wid * 32 + Nt * 16 + (lane & 15);
            float4 cL = *(const float4*)&cChild[cLb + (size_t)b * LDIM + nc];
            float4 cR = *(const float4*)&cChild[cRb + (size_t)b * LDIM + nc];
            float cl4[4] = {cL.x, cL.y, cL.z, cL.w};
            float cr4[4] = {cR.x, cR.y, cR.z, cR.w};
            float4 c4, h4;
            float* cp = (float*)&c4; float* hp = (float*)&h4;
#pragma unroll
            for (int j = 0; j < 4; ++j) {
                float gi = sigmoidf_(acc[0 + half][Nt][j] + bi_[j]);
                float gu = tanhf(acc[2 + half][Nt][j] + bu_[j]);
                float f0 = acc[4 + half][Nt][j] + b0_[j];
                float f1 = acc[6 + half][Nt][j] + b1_[j];
                float c  = gi * gu + f0 * cl4[j] + f1 * cr4[j];
                cp[j] = c;
                hp[j] = tanhf(c);
            }
            *(float4*)&cOut[ob + (size_t)b * LDIM + nc] = c4;
            *(float4*)&hOut[ob + (size_t)b * LDIM + nc] = h4;
        }
    }
}

// ---------------------------------------------------------------------------
// bf16x3 MFMA LEAF kernel (round-12/13 proven): NG=2, NSEG=1, NIT=8.
// grid (512, 8). LDS 46KB -> 3 blocks/CU. In-lane epilogue, float4 stores.
__global__ __launch_bounds__(256, 3) void leaf_mfma(
    const float* __restrict__ x_embed,
    const ushort* __restrict__ Lth, const ushort* __restrict__ Ltm,
    const ushort* __restrict__ Ltl,
    const float* __restrict__ bias_leaf,
    float* __restrict__ hOut, float* __restrict__ cOut)
{
    constexpr int AST = 40;
    __shared__ __align__(16) ushort Wlds[3][64 * AST];
    __shared__ __align__(16) ushort Vlds[3][128 * AST];

    const int tid = threadIdx.x;
    const int ln  = blockIdx.x;                   // leaf-local node 0..511
    const int gy  = blockIdx.y;
    const int lane = tid & 63, wid = tid >> 6;
    const int ni = wid & 1, bw = wid >> 1;
    const int srow = tid & 127, shalf = tid >> 7;
    const int wrow = tid & 63, whalf = (tid >> 6) & 1;

    const float* aX = x_embed + ((size_t)srow * NNODES + (511 + ln)) * LDIM;
    const size_t nbw = (size_t)(((wrow >> 5) << 8) + gy * 32 + (wrow & 31)) * 256;
    const ushort* l0 = Lth + nbw;
    const ushort* l1 = Ltm + nbw;
    const ushort* l2 = Ltl + nbw;

    f32x4 acc[2][4];
#pragma unroll
    for (int g = 0; g < 2; ++g)
#pragma unroll
        for (int t2 = 0; t2 < 4; ++t2) acc[g][t2] = (f32x4){0.f, 0.f, 0.f, 0.f};

    float4 a0, a1, a2, a3;
    int4 w00, w01, w10, w11, w20, w21;

#define LEAF_LOADS(IT)                                                         \
    {                                                                          \
        const float* ap_ = aX + (IT) * 32 + shalf * 16;                        \
        a0 = *(const float4*)(ap_);                                            \
        a1 = *(const float4*)(ap_ + 4);                                        \
        a2 = *(const float4*)(ap_ + 8);                                        \
        a3 = *(const float4*)(ap_ + 12);                                       \
        if (tid < 128) {                                                       \
            const int bko_ = (IT) * 32 + whalf * 16;                           \
            w00 = *(const int4*)(l0 + bko_); w01 = *(const int4*)(l0 + bko_ + 8); \
            w10 = *(const int4*)(l1 + bko_); w11 = *(const int4*)(l1 + bko_ + 8); \
            w20 = *(const int4*)(l2 + bko_); w21 = *(const int4*)(l2 + bko_ + 8); \
        }                                                                      \
    }

    LEAF_LOADS(0);
    for (int it = 0; it < 8; ++it) {
        if (it) __syncthreads();
        {
            P3 p0 = pack2v(a0.x, a0.y), p1 = pack2v(a0.z, a0.w);
            P3 p2 = pack2v(a1.x, a1.y), p3 = pack2v(a1.z, a1.w);
            P3 p4 = pack2v(a2.x, a2.y), p5 = pack2v(a2.z, a2.w);
            P3 p6 = pack2v(a3.x, a3.y), p7 = pack2v(a3.z, a3.w);
            const int base = srow * AST + shalf * 16;
            *(int4*)&Vlds[0][base]     = make_int4((int)p0.h, (int)p1.h, (int)p2.h, (int)p3.h);
            *(int4*)&Vlds[0][base + 8] = make_int4((int)p4.h, (int)p5.h, (int)p6.h, (int)p7.h);
            *(int4*)&Vlds[1][base]     = make_int4((int)p0.m, (int)p1.m, (int)p2.m, (int)p3.m);
            *(int4*)&Vlds[1][base + 8] = make_int4((int)p4.m, (int)p5.m, (int)p6.m, (int)p7.m);
            *(int4*)&Vlds[2][base]     = make_int4((int)p0.l, (int)p1.l, (int)p2.l, (int)p3.l);
            *(int4*)&Vlds[2][base + 8] = make_int4((int)p4.l, (int)p5.l, (int)p6.l, (int)p7.l);
            if (tid < 128) {
                const int bw_ = wrow * AST + whalf * 16;
                *(int4*)&Wlds[0][bw_]     = w00;
                *(int4*)&Wlds[0][bw_ + 8] = w01;
                *(int4*)&Wlds[1][bw_]     = w10;
                *(int4*)&Wlds[1][bw_ + 8] = w11;
                *(int4*)&Wlds[2][bw_]     = w20;
                *(int4*)&Wlds[2][bw_ + 8] = w21;
            }
        }
        __syncthreads();
        if (it + 1 < 8) LEAF_LOADS(it + 1);
        {
            short8 vf[4][3];
#pragma unroll
            for (int Nt = 0; Nt < 4; ++Nt) {
                const int rb = (bw * 64 + Nt * 16 + (lane & 15)) * AST + (lane >> 4) * 8;
#pragma unroll
                for (int s = 0; s < 3; ++s) vf[Nt][s] = *(const short8*)&Vlds[s][rb];
            }
#pragma unroll
            for (int g = 0; g < 2; ++g) {
                const int cb = (g * 32 + ni * 16 + (lane & 15)) * AST + (lane >> 4) * 8;
                short8 wh = *(const short8*)&Wlds[0][cb];
                short8 wm = *(const short8*)&Wlds[1][cb];
                short8 wl = *(const short8*)&Wlds[2][cb];
#pragma unroll
                for (int Nt = 0; Nt < 4; ++Nt)
                    acc[g][Nt] = __builtin_amdgcn_mfma_f32_16x16x32_bf16(wl, vf[Nt][0], acc[g][Nt], 0, 0, 0);
#pragma unroll
                for (int Nt = 0; Nt < 4; ++Nt)
                    acc[g][Nt] = __builtin_amdgcn_mfma_f32_16x16x32_bf16(wh, vf[Nt][2], acc[g][Nt], 0, 0, 0);
#pragma unroll
                for (int Nt = 0; Nt < 4; ++Nt)
                    acc[g][Nt] = __builtin_amdgcn_mfma_f32_16x16x32_bf16(wm, vf[Nt][1], acc[g][Nt], 0, 0, 0);
#pragma unroll
                for (int Nt = 0; Nt < 4; ++Nt)
                    acc[g][Nt] = __builtin_amdgcn_mfma_f32_16x16x32_bf16(wm, vf[Nt][0], acc[g][Nt], 0, 0, 0);
#pragma unroll
                for (int Nt = 0; Nt < 4; ++Nt)
                    acc[g][Nt] = __builtin_amdgcn_mfma_f32_16x16x32_bf16(wh, vf[Nt][1], acc[g][Nt], 0, 0, 0);
#pragma unroll
                for (int Nt = 0; Nt < 4; ++Nt)
                    acc[g][Nt] = __builtin_amdgcn_mfma_f32_16x16x32_bf16(wh, vf[Nt][0], acc[g][Nt], 0, 0, 0);
            }
        }
    }
#undef LEAF_LOADS

    const int nc = gy * 32 + ni * 16 + ((lane >> 4) << 2);
    const size_t ob = (size_t)ln * BATCH * LDIM;
    const float4 bc4 = *(const float4*)&bias_leaf[nc];
    const float4 bo4 = *(const float4*)&bias_leaf[256 + nc];
    const float bc_[4] = {bc4.x, bc4.y, bc4.z, bc4.w};
    const float bo_[4] = {bo4.x, bo4.y, bo4.z, bo4.w};
#pragma unroll
    for (int Nt = 0; Nt < 4; ++Nt) {
        const int b = bw * 64 + Nt * 16 + (lane & 15);
        float4 c4, h4;
        float* cp = (float*)&c4; float* hp = (float*)&h4;
#pragma unroll
        for (int j = 0; j < 4; ++j) {
            float c = acc[0][Nt][j] + bc_[j];
            float o = acc[1][Nt][j] + bo_[j];
            cp[j] = c;
            hp[j] = sigmoidf_(o) * tanhf(c);
        }
        size_t po = ob + (size_t)b * LDIM + nc;
        *(float4*)&cOut[po] = c4;
        *(float4*)&hOut[po] = h4;
    }
}

// ---------------------------------------------------------------------------
// Leaf kernel (fp32 fallback). grid (1024, 4), block 256.
__global__ __launch_bounds__(256) void leaf_kernel(
    const float* __restrict__ x_embed,
    const float* __restrict__ Wleaf, const float* __restrict__ bias_leaf,
    float* __restrict__ hOut, float* __restrict__ cOut)
{
    __shared__ float As[16 * 68];
    __shared__ float Bs[2 * 16 * 64];
    float acc[2][4][4] = {};
    const int tid = threadIdx.x;
    const int ty = tid >> 4, tx = tid & 15;
    const int row0 = blockIdx.x * 64;
    const int n0 = blockIdx.y * 64;
    const int w = row0 >> 7;
    const int ar = tid >> 2;
    const int kq = (tid & 3) * 4;
    const int b = (row0 + ar) & 127;
    const float* xrow = x_embed + ((size_t)b * NNODES + 511 + w) * LDIM;

    for (int k0 = 0; k0 < 256; k0 += 16) {
        float4 av = *(const float4*)(xrow + k0 + kq);
        As[(kq + 0) * 68 + ar] = av.x;
        As[(kq + 1) * 68 + ar] = av.y;
        As[(kq + 2) * 68 + ar] = av.z;
        As[(kq + 3) * 68 + ar] = av.w;
#pragma unroll
        for (int q = 0; q < 2; ++q) {
            int L = q * 256 + tid;
            int g = L >> 8, kk = (L >> 4) & 15, n4 = (L & 15) * 4;
            float4 bv = *(const float4*)(Wleaf + (size_t)(k0 + kk) * 512 + g * 256 + n0 + n4);
            *(float4*)&Bs[(g * 16 + kk) * 64 + n4] = bv;
        }
        __syncthreads();
#pragma unroll
        for (int kk = 0; kk < 16; ++kk) {
            float4 a = *(const float4*)&As[kk * 68 + ty * 4];
            float av4[4] = {a.x, a.y, a.z, a.w};
#pragma unroll
            for (int g = 0; g < 2; ++g) {
                float4 bb = *(const float4*)&Bs[(g * 16 + kk) * 64 + tx * 4];
                float bv4[4] = {bb.x, bb.y, bb.z, bb.w};
#pragma unroll
                for (int ii = 0; ii < 4; ++ii)
#pragma unroll
                    for (int jj = 0; jj < 4; ++jj)
                        acc[g][ii][jj] += av4[ii] * bv4[jj];
            }
        }
        __syncthreads();
    }
#pragma unroll
    for (int ii = 0; ii < 4; ++ii) {
        int r = row0 + ty * 4 + ii;
        int nc = n0 + tx * 4;
        float4 c4, h4;
        float* cp = (float*)&c4; float* hp = (float*)&h4;
#pragma unroll
        for (int jj = 0; jj < 4; ++jj) {
            int n = nc + jj;
            float ac = acc[0][ii][jj] + bias_leaf[n];
            float ao = acc[1][ii][jj] + bias_leaf[256 + n];
            cp[jj] = ac;
            hp[jj] = sigmoidf_(ao) * tanhf(ac);
        }
        *(float4*)&cOut[(size_t)r * LDIM + nc] = c4;
        *(float4*)&hOut[(size_t)r * LDIM + nc] = h4;
    }
}

// ---------------------------------------------------------------------------
// fp32 level kernel (proven fallback). grid (W*2, 4), block 256.
__global__ __launch_bounds__(256) void level_kernel(
    const float* __restrict__ x_embed,
    const float* __restrict__ hChild, const float* __restrict__ cChild,
    const float* __restrict__ Wbig, const float* __restrict__ bias_big,
    float* __restrict__ hOut, float* __restrict__ cOut,
    int nstart)
{
    __shared__ float As[16 * 68];
    __shared__ float Bs[4 * 16 * 64];
    float acc[4][4][4] = {};
    const int tid = threadIdx.x;
    const int ty = tid >> 4, tx = tid & 15;
    const int row0 = blockIdx.x * 64;
    const int n0 = blockIdx.y * 64;
    const int w = row0 >> 7;
    const int ar = tid >> 2;
    const int kq = (tid & 3) * 4;
    const int b = (row0 + ar) & 127;
    const float* srcX = x_embed + ((size_t)b * NNODES + nstart + w) * LDIM;
    const float* srcL = hChild + ((size_t)(2 * w) * BATCH + b) * LDIM;
    const float* srcR = hChild + ((size_t)(2 * w + 1) * BATCH + b) * LDIM;

    for (int k0 = 0; k0 < 768; k0 += 16) {
        int seg = k0 >> 8, off = k0 & 255;
        const float* src = (seg == 0) ? srcX : (seg == 1) ? srcL : srcR;
        float4 av = *(const float4*)(src + off + kq);
        As[(kq + 0) * 68 + ar] = av.x;
        As[(kq + 1) * 68 + ar] = av.y;
        As[(kq + 2) * 68 + ar] = av.z;
        As[(kq + 3) * 68 + ar] = av.w;
#pragma unroll
        for (int q = 0; q < 4; ++q) {
            int L = q * 256 + tid;
            int g = L >> 8, kk = (L >> 4) & 15, n4 = (L & 15) * 4;
            float4 bv = *(const float4*)(Wbig + (size_t)(k0 + kk) * 1024 + g * 256 + n0 + n4);
            *(float4*)&Bs[(g * 16 + kk) * 64 + n4] = bv;
        }
        __syncthreads();
#pragma unroll
        for (int kk = 0; kk < 16; ++kk) {
            float4 a = *(const float4*)&As[kk * 68 + ty * 4];
            float av4[4] = {a.x, a.y, a.z, a.w};
#pragma unroll
            for (int g = 0; g < 4; ++g) {
                float4 bb = *(const float4*)&Bs[(g * 16 + kk) * 64 + tx * 4];
                float bv4[4] = {bb.x, bb.y, bb.z, bb.w};
#pragma unroll
                for (int ii = 0; ii < 4; ++ii)
#pragma unroll
                    for (int jj = 0; jj < 4; ++jj)
                        acc[g][ii][jj] += av4[ii] * bv4[jj];
            }
        }
        __syncthreads();
    }
    const size_t cLbase = ((size_t)(2 * w) * BATCH) * LDIM;
    const size_t cRbase = ((size_t)(2 * w + 1) * BATCH) * LDIM;
#pragma unroll
    for (int ii = 0; ii < 4; ++ii) {
        int r = row0 + ty * 4 + ii;
        int bb2 = r & 127;
        int nc = n0 + tx * 4;
        float4 cL = *(const float4*)&cChild[cLbase + (size_t)bb2 * LDIM + nc];
        float4 cR = *(const float4*)&cChild[cRbase + (size_t)bb2 * LDIM + nc];
        float cl4[4] = {cL.x, cL.y, cL.z, cL.w};
        float cr4[4] = {cR.x, cR.y, cR.z, cR.w};
        float4 c4, h4;
        float* cp = (float*)&c4; float* hp = (float*)&h4;
#pragma unroll
        for (int jj = 0; jj < 4; ++jj) {
            int n = nc + jj;
            float gi = sigmoidf_(acc[0][ii][jj] + bias_big[n]);
            float gu = tanhf(acc[1][ii][jj] + bias_big[256 + n]);
            float f0 = acc[2][ii][jj] + bias_big[512 + n];
            float f1 = acc[3][ii][jj] + bias_big[768 + n];
            float c = gi * gu + f0 * cl4[jj] + f1 * cr4[jj];
            cp[jj] = c;
            hp[jj] = tanhf(c);
        }
        *(float4*)&cOut[(size_t)r * LDIM + nc] = c4;
        *(float4*)&hOut[(size_t)r * LDIM + nc] = h4;
    }
}

// ---------------------------------------------------------------------------
// Split-K partial (TM=4, one 256-wide K segment per blockIdx.z). grid (W*2,4,3).
__global__ __launch_bounds__(256) void gemm_part4(
    const float* __restrict__ x_embed, const float* __restrict__ hChild,
    const float* __restrict__ Wbig,
    float* __restrict__ part, int nstart, int rowsTotal)
{
    __shared__ float As[16 * 68];
    __shared__ float Bs[4 * 16 * 64];
    float acc[4][4][4] = {};
    const int tid = threadIdx.x;
    const int ty = tid >> 4, tx = tid & 15;
    const int row0 = blockIdx.x * 64;
    const int n0 = blockIdx.y * 64;
    const int seg = blockIdx.z;
    const int w = row0 >> 7;
    const int ar = tid >> 2;
    const int kq = (tid & 3) * 4;
    const int b = (row0 + ar) & 127;
    const float* src =
        (seg == 0) ? x_embed + ((size_t)b * NNODES + nstart + w) * LDIM
                   : hChild + ((size_t)(2 * w + (seg - 1)) * BATCH + b) * LDIM;

    for (int k0 = 0; k0 < 256; k0 += 16) {
        float4 av = *(const float4*)(src + k0 + kq);
        As[(kq + 0) * 68 + ar] = av.x;
        As[(kq + 1) * 68 + ar] = av.y;
        As[(kq + 2) * 68 + ar] = av.z;
        As[(kq + 3) * 68 + ar] = av.w;
#pragma unroll
        for (int q = 0; q < 4; ++q) {
            int L = q * 256 + tid;
            int g = L >> 8, kk = (L >> 4) & 15, n4 = (L & 15) * 4;
            float4 bv = *(const float4*)(Wbig + (size_t)(seg * 256 + k0 + kk) * 1024
                                         + g * 256 + n0 + n4);
            *(float4*)&Bs[(g * 16 + kk) * 64 + n4] = bv;
        }
        __syncthreads();
#pragma unroll
        for (int kk = 0; kk < 16; ++kk) {
            float4 a = *(const float4*)&As[kk * 68 + ty * 4];
            float av4[4] = {a.x, a.y, a.z, a.w};
#pragma unroll
            for (int g = 0; g < 4; ++g) {
                float4 bb = *(const float4*)&Bs[(g * 16 + kk) * 64 + tx * 4];
                float bv4[4] = {bb.x, bb.y, bb.z, bb.w};
#pragma unroll
                for (int ii = 0; ii < 4; ++ii)
#pragma unroll
                    for (int jj = 0; jj < 4; ++jj)
                        acc[g][ii][jj] += av4[ii] * bv4[jj];
            }
        }
        __syncthreads();
    }
#pragma unroll
    for (int ii = 0; ii < 4; ++ii) {
        int r = row0 + ty * 4 + ii;
        size_t base = ((size_t)seg * rowsTotal + r) * 1024 + n0 + tx * 4;
#pragma unroll
        for (int g = 0; g < 4; ++g)
            *(float4*)&part[base + g * 256] = *(float4*)acc[g][ii];
    }
}

// ---------------------------------------------------------------------------
// Combine 3 split-K partials + LSTM epilogue. grid (rows/4), block 256.
__global__ __launch_bounds__(256) void combine_eps(
    const float* __restrict__ part, const float* __restrict__ cChild,
    const float* __restrict__ bias,
    float* __restrict__ hOut, float* __restrict__ cOut, int rowsTotal)
{
    int idx = blockIdx.x * 256 + threadIdx.x;
    int row = idx >> 6, n = (idx & 63) * 4;
    size_t sseg = (size_t)rowsTotal * 1024;
    const float* p0 = part + (size_t)row * 1024 + n;
    float s[4][4];
#pragma unroll
    for (int g = 0; g < 4; ++g) {
        float4 a = *(const float4*)(p0 + g * 256);
        float4 b = *(const float4*)(p0 + sseg + g * 256);
        float4 c = *(const float4*)(p0 + 2 * sseg + g * 256);
        s[g][0] = a.x + b.x + c.x; s[g][1] = a.y + b.y + c.y;
        s[g][2] = a.z + b.z + c.z; s[g][3] = a.w + b.w + c.w;
    }
    int node = row >> 7, b = row & 127;
    float4 cL = *(const float4*)&cChild[((size_t)(2 * node) * BATCH + b) * LDIM + n];
    float4 cR = *(const float4*)&cChild[((size_t)(2 * node + 1) * BATCH + b) * LDIM + n];
    float cl4[4] = {cL.x, cL.y, cL.z, cL.w};
    float cr4[4] = {cR.x, cR.y, cR.z, cR.w};
    float4 c4, h4;
    float* cp = (float*)&c4; float* hp = (float*)&h4;
#pragma unroll
    for (int jj = 0; jj < 4; ++jj) {
        int nn = n + jj;
        float gi = sigmoidf_(s[0][jj] + bias[nn]);
        float gu = tanhf(s[1][jj] + bias[256 + nn]);
        float f0 = s[2][jj] + bias[512 + nn];
        float f1 = s[3][jj] + bias[768 + nn];
        float c = gi * gu + f0 * cl4[jj] + f1 * cr4[jj];
        cp[jj] = c;
        hp[jj] = tanhf(c);
    }
    *(float4*)&cOut[(size_t)row * LDIM + n] = c4;
    *(float4*)&hOut[(size_t)row * LDIM + n] = h4;
}

// ---------------------------------------------------------------------------
// Final: out[b][n] = tanh([init | c_root | h_root] @ Woend + boend). grid 128.
__global__ __launch_bounds__(256) void final_kernel(
    const float* __restrict__ init_emb,
    const float* __restrict__ cRoot, const float* __restrict__ hRoot,
    const float* __restrict__ Woend, const float* __restrict__ boend,
    float* __restrict__ out)
{
    __shared__ float sv[768];
    int b = blockIdx.x, t = threadIdx.x;
    sv[t]       = init_emb[(size_t)b * 256 + t];
    sv[256 + t] = cRoot[(size_t)b * 256 + t];
    sv[512 + t] = hRoot[(size_t)b * 256 + t];
    __syncthreads();
    float acc = boend[t];
#pragma unroll 4
    for (int d = 0; d < 768; ++d)
        acc += sv[d] * Woend[(size_t)d * 256 + t];
    out[(size_t)b * 256 + t] = tanhf(acc);
}

// ---------------------------------------------------------------------------
extern "C" void kernel_launch(void* const* d_in, const int* in_sizes, int n_in,
                              void* d_out, int out_size, void* d_ws, size_t ws_size,
                              hipStream_t stream)
{
    const float* x_embed  = (const float*)d_in[0];
    const float* init_emb = (const float*)d_in[1];
    const float* Wcx = (const float*)d_in[2];  const float* bcx = (const float*)d_in[3];
    const float* Wox = (const float*)d_in[4];  const float* box = (const float*)d_in[5];
    const float* Wix = (const float*)d_in[6];  const float* bix = (const float*)d_in[7];
    const float* Wfx = (const float*)d_in[8];  const float* bfx = (const float*)d_in[9];
    const float* Wux = (const float*)d_in[10]; const float* bux = (const float*)d_in[11];
    const float* Wi  = (const float*)d_in[12]; const float* bi  = (const float*)d_in[13];
    const float* Wf  = (const float*)d_in[14]; const float* bf  = (const float*)d_in[15];
    const float* Wu  = (const float*)d_in[16]; const float* bu  = (const float*)d_in[17];
    const float* Woend = (const float*)d_in[18]; const float* boend = (const float*)d_in[19];
    float* out = (float*)d_out;
    float* ws  = (float*)d_ws;

    size_t off = 0;
    float* hA = ws + off; off += (size_t)512 * 128 * 256;
    float* cA = ws + off; off += (size_t)512 * 128 * 256;
    float* hB = ws + off; off += (size_t)256 * 128 * 256;
    float* cB = ws + off; off += (size_t)256 * 128 * 256;
    float* Wbig      = ws + off; off += (size_t)768 * 1024;
    float* bias_big  = ws + off; off += 1024;
    float* Wleaf     = ws + off; off += (size_t)256 * 512;
    float* bias_leaf = ws + off; off += 512;
    // bf16 weight splits, transposed [n][k]
    ushort* Wth = (ushort*)(ws + off); off += (size_t)768 * 1024 / 2;
    ushort* Wtm = (ushort*)(ws + off); off += (size_t)768 * 1024 / 2;
    ushort* Wtl = (ushort*)(ws + off); off += (size_t)768 * 1024 / 2;
    // leaf weight splits, transposed [n=512][k=256]
    ushort* Lth = (ushort*)(ws + off); off += (size_t)512 * 256 / 2;
    ushort* Ltm = (ushort*)(ws + off); off += (size_t)512 * 256 / 2;
    ushort* Ltl = (ushort*)(ws + off); off += (size_t)512 * 256 / 2;
    size_t mfma_need = off * sizeof(float);
    size_t part_off = off;
    float* part = ws + part_off;

    bool mfma_ok = mfma_need <= ws_size;

    {
        int total = 768 * 1024 + 1024 + 256 * 512 + 512;
        int blocks = (total + 255) / 256;
        build_weights<<<blocks, 256, 0, stream>>>(
            Wix, bix, Wfx, bfx, Wux, bux, Wi, bi, Wf, bf, Wu, bu,
            Wcx, bcx, Wox, box, Wbig, bias_big, Wleaf, bias_leaf);
    }
    if (mfma_ok) {
        split_weights_T<<<dim3(24, 32), 256, 0, stream>>>(Wbig, Wth, Wtm, Wtl);
        split_wleaf_T<<<dim3(8, 16), 256, 0, stream>>>(Wleaf, Lth, Ltm, Ltl);
    }

    if (mfma_ok) {
        leaf_mfma<<<dim3(512, 8), 256, 0, stream>>>(
            x_embed, Lth, Ltm, Ltl, bias_leaf, hA, cA);
    } else {
        leaf_kernel<<<dim3(1024, 4), 256, 0, stream>>>(
            x_embed, Wleaf, bias_leaf, hA, cA);
    }

    float* hbufs[2] = {hA, hB};
    float* cbufs[2] = {cA, cB};
    int child = 0;  // leaves in A
    for (int lvl = 8; lvl >= 0; --lvl) {
        int W = 1 << lvl, s = W - 1;
        int outb = child ^ 1;
        size_t rows = (size_t)W * 128;
        bool split = (W <= 16) &&
                     ((part_off + 3 * rows * 1024) * sizeof(float) <= ws_size);
        if (lvl >= 5 && mfma_ok) {
            mfma_level_pack<<<dim3(W, 8), 256, 0, stream>>>(
                x_embed, hbufs[child], cbufs[child], Wth, Wtm, Wtl, bias_big,
                hbufs[outb], cbufs[outb], s);
        } else if (split) {
            gemm_part4<<<dim3(W * 2, 4, 3), 256, 0, stream>>>(
                x_embed, hbufs[child], Wbig, part, s, (int)rows);
            combine_eps<<<(int)(rows / 4), 256, 0, stream>>>(
                part, cbufs[child], bias_big, hbufs[outb], cbufs[outb], (int)rows);
        } else {
            level_kernel<<<dim3(W * 2, 4), 256, 0, stream>>>(
                x_embed, hbufs[child], cbufs[child], Wbig, bias_big,
                hbufs[outb], cbufs[outb], s);
        }
        child = outb;
    }

    final_kernel<<<128, 256, 0, stream>>>(init_emb, cbufs[child], hbufs[child],
                                          Woend, boend, out);
}

// Round 16
// 1062.517 us; speedup vs baseline: 1.4077x; 1.0160x over previous
//
#include <hip/hip_runtime.h>
#include <hip/hip_bf16.h>
#include <math.h>

// Tree-LSTM "LogicEncoder": D=10, N=1023 nodes, B=128, LD=256, K=2.
// Round 16: revert r15's ONLY numerics change (lvl>=4 MFMA -> back to lvl>=5;
// lvl4..0 on fp32 split-K paths — r15 hit absmax 0.0205 > 0.02 from the 10th
// bf16x3 level). KEEP r15's scheduling work, which is bitwise-identical:
//  (1) chunk-major weight LDS [plane][chunk][row][8], contiguous 16B/lane;
//  (2) double-buffered weights, ONE barrier/K-step (49152 B -> 3 blocks/CU);
//  (3) s_setprio around the MFMA cluster.

#define NNODES 1023
#define BATCH  128
#define LDIM   256

typedef __attribute__((ext_vector_type(8))) short short8;
typedef __attribute__((ext_vector_type(4))) float f32x4;

__device__ __forceinline__ float sigmoidf_(float x) {
    return 1.f / (1.f + expf(-x));
}

// fp32 -> 3x bf16, RNE at each stage; residuals exact. (weight-split kernels)
__device__ __forceinline__ void split3(float x, ushort& h, ushort& m, ushort& l) {
    unsigned u = __float_as_uint(x);
    unsigned hu = (u + 0x7FFFu + ((u >> 16) & 1u)) & 0xFFFF0000u;
    h = (ushort)(hu >> 16);
    float r = x - __uint_as_float(hu);
    unsigned ur = __float_as_uint(r);
    unsigned mu = (ur + 0x7FFFu + ((ur >> 16) & 1u)) & 0xFFFF0000u;
    m = (ushort)(mu >> 16);
    float r2 = r - __uint_as_float(mu);
    unsigned u2 = __float_as_uint(r2);
    l = (ushort)((u2 + 0x7FFFu + ((u2 >> 16) & 1u)) >> 16);
}

// HW pair convert: dst = [bf16(hi):bf16(lo)], RNE (bitwise == split3).
__device__ __forceinline__ unsigned cvt_pk_bf16(float lo, float hi) {
    unsigned r;
    asm("v_cvt_pk_bf16_f32 %0, %1, %2" : "=v"(r) : "v"(lo), "v"(hi));
    return r;
}

struct P3 { unsigned h, m, l; };
__device__ __forceinline__ P3 pack2v(float x0, float x1) {
    P3 p;
    p.h = cvt_pk_bf16(x0, x1);
    float h0 = __uint_as_float(p.h << 16);
    float h1 = __uint_as_float(p.h & 0xFFFF0000u);
    float r0 = x0 - h0, r1 = x1 - h1;
    p.m = cvt_pk_bf16(r0, r1);
    float m0 = __uint_as_float(p.m << 16);
    float m1 = __uint_as_float(p.m & 0xFFFF0000u);
    p.l = cvt_pk_bf16(r0 - m0, r1 - m1);
    return p;
}

// split 8 fp32 (two float4) into three bf16x8 MFMA fragments, by value.
struct VF { short8 h, m, l; };
__device__ __forceinline__ VF split8(float4 a, float4 b) {
    P3 p0 = pack2v(a.x, a.y), p1 = pack2v(a.z, a.w);
    P3 p2 = pack2v(b.x, b.y), p3 = pack2v(b.z, b.w);
    VF r;
    r.h = __builtin_bit_cast(short8, make_uint4(p0.h, p1.h, p2.h, p3.h));
    r.m = __builtin_bit_cast(short8, make_uint4(p0.m, p1.m, p2.m, p3.m));
    r.l = __builtin_bit_cast(short8, make_uint4(p0.l, p1.l, p2.l, p3.l));
    return r;
}

// ---------------------------------------------------------------------------
// Pack Wbig (768x1024) + bias_big(1024) + Wleaf(256x512) + bias_leaf(512).
__global__ __launch_bounds__(256) void build_weights(
    const float* __restrict__ Wix, const float* __restrict__ bix,
    const float* __restrict__ Wfx, const float* __restrict__ bfx,
    const float* __restrict__ Wux, const float* __restrict__ bux,
    const float* __restrict__ Wi,  const float* __restrict__ bi,
    const float* __restrict__ Wf,  const float* __restrict__ bf,
    const float* __restrict__ Wu,  const float* __restrict__ bu,
    const float* __restrict__ Wcx, const float* __restrict__ bcx,
    const float* __restrict__ Wox, const float* __restrict__ box,
    float* __restrict__ Wbig, float* __restrict__ bias_big,
    float* __restrict__ Wleaf, float* __restrict__ bias_leaf)
{
    int i = blockIdx.x * blockDim.x + threadIdx.x;
    if (i < 768 * 1024) {
        int k = i >> 10, n = i & 1023;
        int g = n >> 8, nn = n & 255;
        float v;
        if (g == 0) {
            v = (k < 256) ? Wix[k * 256 + nn]
              : (k < 512) ? Wi[(k - 256) * 256 + nn]
                          : Wi[65536 + (k - 512) * 256 + nn];
        } else if (g == 1) {
            v = (k < 256) ? Wux[k * 256 + nn]
              : (k < 512) ? Wu[(k - 256) * 256 + nn]
                          : Wu[65536 + (k - 512) * 256 + nn];
        } else {
            int kf = g - 2;  // f0 / f1
            v = (k < 256) ? Wfx[k * 256 + nn]
              : (k < 512) ? Wf[((kf * 2 + 0) * 256 + (k - 256)) * 256 + nn]
                          : Wf[((kf * 2 + 1) * 256 + (k - 512)) * 256 + nn];
        }
        Wbig[i] = v;
        return;
    }
    i -= 768 * 1024;
    if (i < 1024) {
        int g = i >> 8, nn = i & 255;
        float v;
        if (g == 0)      v = bix[nn] + bi[nn] + bi[256 + nn];
        else if (g == 1) v = bux[nn] + bu[nn] + bu[256 + nn];
        else if (g == 2) v = bfx[nn] + bf[nn] + bf[256 + nn];
        else             v = bfx[nn] + bf[512 + nn] + bf[768 + nn];
        bias_big[i] = v;
        return;
    }
    i -= 1024;
    if (i < 256 * 512) {
        int k = i >> 9, n = i & 511;
        Wleaf[i] = (n < 256) ? Wcx[k * 256 + n] : Wox[k * 256 + (n - 256)];
        return;
    }
    i -= 256 * 512;
    if (i < 512) {
        bias_leaf[i] = (i < 256) ? bcx[i] : box[i - 256];
    }
}

// ---------------------------------------------------------------------------
// Split Wbig into 3 bf16 planes TRANSPOSED: Wt_s[n][k] (1024 x 768).
__global__ __launch_bounds__(256) void split_weights_T(
    const float* __restrict__ Wbig,
    ushort* __restrict__ Wth, ushort* __restrict__ Wtm, ushort* __restrict__ Wtl)
{
    __shared__ float sh[32][33];
    const int k0 = blockIdx.x * 32, n0 = blockIdx.y * 32;
    const int t = threadIdx.x;
    {
        int r = t >> 3, c4 = (t & 7) * 4;
        float4 v = *(const float4*)&Wbig[(size_t)(k0 + r) * 1024 + n0 + c4];
        sh[r][c4] = v.x; sh[r][c4 + 1] = v.y; sh[r][c4 + 2] = v.z; sh[r][c4 + 3] = v.w;
    }
    __syncthreads();
    int n = t >> 3, kc = (t & 7) * 4;
    ushort oh[4], om[4], ol[4];
#pragma unroll
    for (int j = 0; j < 4; ++j)
        split3(sh[kc + j][n], oh[j], om[j], ol[j]);
    size_t o = (size_t)(n0 + n) * 768 + k0 + kc;
    *(ushort4*)&Wth[o] = make_ushort4(oh[0], oh[1], oh[2], oh[3]);
    *(ushort4*)&Wtm[o] = make_ushort4(om[0], om[1], om[2], om[3]);
    *(ushort4*)&Wtl[o] = make_ushort4(ol[0], ol[1], ol[2], ol[3]);
}

// ---------------------------------------------------------------------------
// Split Wleaf (256x512) into 3 bf16 planes TRANSPOSED: Lt_s[n][k] (512 x 256).
__global__ __launch_bounds__(256) void split_wleaf_T(
    const float* __restrict__ Wleaf,
    ushort* __restrict__ Lth, ushort* __restrict__ Ltm, ushort* __restrict__ Ltl)
{
    __shared__ float sh[32][33];
    const int k0 = blockIdx.x * 32, n0 = blockIdx.y * 32;
    const int t = threadIdx.x;
    {
        int r = t >> 3, c4 = (t & 7) * 4;
        float4 v = *(const float4*)&Wleaf[(size_t)(k0 + r) * 512 + n0 + c4];
        sh[r][c4] = v.x; sh[r][c4 + 1] = v.y; sh[r][c4 + 2] = v.z; sh[r][c4 + 3] = v.w;
    }
    __syncthreads();
    int n = t >> 3, kc = (t & 7) * 4;
    ushort oh[4], om[4], ol[4];
#pragma unroll
    for (int j = 0; j < 4; ++j)
        split3(sh[kc + j][n], oh[j], om[j], ol[j]);
    size_t o = (size_t)(n0 + n) * 256 + k0 + kc;
    *(ushort4*)&Lth[o] = make_ushort4(oh[0], oh[1], oh[2], oh[3]);
    *(ushort4*)&Ltm[o] = make_ushort4(om[0], om[1], om[2], om[3]);
    *(ushort4*)&Ltl[o] = make_ushort4(ol[0], ol[1], ol[2], ol[3]);
}

// ---------------------------------------------------------------------------
// bf16x3 MFMA level kernel: weights in chunk-major double-buffered LDS
// ([plane(4096)][chunk(1024)][row(8)] ushorts per buffer, 24576 B), ONE
// barrier per K-step; per-lane direct global activation loads + in-register
// split. grid (W, 8): blockIdx.x = node (node%8 -> XCD), blockIdx.y = gy.
__global__ __launch_bounds__(256, 3) void mfma_level_pack(
    const float* __restrict__ x_embed,
    const float* __restrict__ hChild, const float* __restrict__ cChild,
    const ushort* __restrict__ Wth, const ushort* __restrict__ Wtm,
    const ushort* __restrict__ Wtl,
    const float* __restrict__ bias,
    float* __restrict__ hOut, float* __restrict__ cOut, int nstart)
{
    __shared__ __align__(16) ushort Wlds[2][12288];   // 2 x 24576 B

    const int tid  = threadIdx.x;
    const int node = blockIdx.x;
    const int gy   = blockIdx.y;
    const int lane = tid & 63, wid = tid >> 6;            // wave = batch quarter
    const int srow = tid & 127, shalf = tid >> 7;

    // weight staging source (per thread row)
    const size_t nb = (size_t)(((srow >> 5) << 8) + gy * 32 + (srow & 31)) * 768;
    const ushort* w0 = Wth + nb;
    const ushort* w1 = Wtm + nb;
    const ushort* w2 = Wtl + nb;

    // per-lane activation row pointers (pre-offset by lane's k-slice)
    const int b0 = wid * 32 + (lane & 15);
    const int b1 = b0 + 16;
    const int kl = (lane >> 4) * 8;
    const float* x0p = x_embed + ((size_t)b0 * NNODES + (nstart + node)) * LDIM + kl;
    const float* x1p = x_embed + ((size_t)b1 * NNODES + (nstart + node)) * LDIM + kl;
    const float* l0p = hChild + ((size_t)(2 * node) * BATCH + b0) * LDIM + kl;
    const float* l1p = hChild + ((size_t)(2 * node) * BATCH + b1) * LDIM + kl;
    const size_t RSTEP = (size_t)BATCH * LDIM;            // hL -> hR offset

    // LDS offsets (ushort units): write = chunk(2*shalf)/row srow;
    // read base = chunk(lane>>4) + row(lane&15); + s*4096 + ct*128.
    const int wbase = 2 * shalf * 1024 + srow * 8;
    const int rbase = (lane >> 4) * 1024 + (lane & 15) * 8;

    f32x4 acc[8][2];   // [col-tile ct = gate*2+half][batch tile Nt]
#pragma unroll
    for (int ct = 0; ct < 8; ++ct)
#pragma unroll
        for (int t2 = 0; t2 < 2; ++t2) acc[ct][t2] = (f32x4){0.f, 0.f, 0.f, 0.f};

    // staging registers — named, never address-taken
    float4 v00, v01, v10, v11;
    int4 w00, w01, w10, w11, w20, w21;

#define W_LOADS(IT)                                                            \
    {                                                                          \
        const int bko_ = (IT) * 32 + shalf * 16;                               \
        w00 = *(const int4*)(w0 + bko_); w01 = *(const int4*)(w0 + bko_ + 8);  \
        w10 = *(const int4*)(w1 + bko_); w11 = *(const int4*)(w1 + bko_ + 8);  \
        w20 = *(const int4*)(w2 + bko_); w21 = *(const int4*)(w2 + bko_ + 8);  \
    }
#define ACT_LOADS(IT)                                                          \
    {                                                                          \
        const int seg_  = (IT) >> 3;                                           \
        const int koff_ = ((IT) & 7) * 32;                                     \
        const float* pa0_ = (seg_ == 0) ? x0p : (seg_ == 1) ? l0p : (l0p + RSTEP); \
        const float* pa1_ = (seg_ == 0) ? x1p : (seg_ == 1) ? l1p : (l1p + RSTEP); \
        pa0_ += koff_; pa1_ += koff_;                                          \
        v00 = *(const float4*)(pa0_);                                          \
        v01 = *(const float4*)(pa0_ + 4);                                      \
        v10 = *(const float4*)(pa1_);                                          \
        v11 = *(const float4*)(pa1_ + 4);                                      \
    }
#define WRITE_W(BUF)                                                           \
    {                                                                          \
        ushort* wp_ = &Wlds[BUF][wbase];                                       \
        *(int4*)(wp_)        = w00; *(int4*)(wp_ + 1024) = w01;                \
        *(int4*)(wp_ + 4096) = w10; *(int4*)(wp_ + 5120) = w11;                \
        *(int4*)(wp_ + 8192) = w20; *(int4*)(wp_ + 9216) = w21;                \
    }

    W_LOADS(0); ACT_LOADS(0);
    WRITE_W(0);
    W_LOADS(1);
    __syncthreads();

    for (int it = 0; it < 24; ++it) {
        const int cur = it & 1;
        if (it + 1 < 24) WRITE_W(cur ^ 1);     // stage next K-step's weights
        if (it + 2 < 24) W_LOADS(it + 2);      // prefetch following weights
        VF f0 = split8(v00, v01);              // current activations, in-reg
        VF f1 = split8(v10, v11);
        if (it + 1 < 24) ACT_LOADS(it + 1);    // prefetch next activations
        const ushort* lb = &Wlds[cur][rbase];
        __builtin_amdgcn_s_setprio(1);
#pragma unroll
        for (int ct = 0; ct < 8; ++ct) {
            short8 wh = *(const short8*)(lb + ct * 128);
            short8 wm = *(const short8*)(lb + 4096 + ct * 128);
            short8 wl = *(const short8*)(lb + 8192 + ct * 128);
            acc[ct][0] = __builtin_amdgcn_mfma_f32_16x16x32_bf16(wl, f0.h, acc[ct][0], 0, 0, 0);
            acc[ct][1] = __builtin_amdgcn_mfma_f32_16x16x32_bf16(wl, f1.h, acc[ct][1], 0, 0, 0);
            acc[ct][0] = __builtin_amdgcn_mfma_f32_16x16x32_bf16(wh, f0.l, acc[ct][0], 0, 0, 0);
            acc[ct][1] = __builtin_amdgcn_mfma_f32_16x16x32_bf16(wh, f1.l, acc[ct][1], 0, 0, 0);
            acc[ct][0] = __builtin_amdgcn_mfma_f32_16x16x32_bf16(wm, f0.m, acc[ct][0], 0, 0, 0);
            acc[ct][1] = __builtin_amdgcn_mfma_f32_16x16x32_bf16(wm, f1.m, acc[ct][1], 0, 0, 0);
            acc[ct][0] = __builtin_amdgcn_mfma_f32_16x16x32_bf16(wm, f0.h, acc[ct][0], 0, 0, 0);
            acc[ct][1] = __builtin_amdgcn_mfma_f32_16x16x32_bf16(wm, f1.h, acc[ct][1], 0, 0, 0);
            acc[ct][0] = __builtin_amdgcn_mfma_f32_16x16x32_bf16(wh, f0.m, acc[ct][0], 0, 0, 0);
            acc[ct][1] = __builtin_amdgcn_mfma_f32_16x16x32_bf16(wh, f1.m, acc[ct][1], 0, 0, 0);
            acc[ct][0] = __builtin_amdgcn_mfma_f32_16x16x32_bf16(wh, f0.h, acc[ct][0], 0, 0, 0);
            acc[ct][1] = __builtin_amdgcn_mfma_f32_16x16x32_bf16(wh, f1.h, acc[ct][1], 0, 0, 0);
        }
        __builtin_amdgcn_s_setprio(0);
        __syncthreads();                       // single barrier per K-step
    }
#undef W_LOADS
#undef ACT_LOADS
#undef WRITE_W

    // ----- fused LSTM epilogue (fp32 c-path, float4 stores) -----
    const size_t cLb = (size_t)(2 * node) * BATCH * LDIM;
    const size_t cRb = cLb + (size_t)BATCH * LDIM;
    const size_t ob  = (size_t)node * BATCH * LDIM;
#pragma unroll
    for (int half = 0; half < 2; ++half) {
        const int nc = gy * 32 + half * 16 + ((lane >> 4) << 2);
        const float4 bi4 = *(const float4*)&bias[nc];
        const float4 bu4 = *(const float4*)&bias[256 + nc];
        const float4 b04 = *(const float4*)&bias[512 + nc];
        const float4 b14 = *(const float4*)&bias[768 + nc];
        const float bi_[4] = {bi4.x, bi4.y, bi4.z, bi4.w};
        const float bu_[4] = {bu4.x, bu4.y, bu4.z, bu4.w};
        const float b0_[4] = {b04.x, b04.y, b04.z, b04.w};
        const float b1_[4] = {b14.x, b14.y, b14.z, b14.w};
#pragma unroll
        for (int Nt = 0; Nt < 2; ++Nt) {
            const int b = wid * 32 + Nt * 16 + (lane & 15);
            float4 cL = *(const float4*)&cChild[cLb + (size_t)b * LDIM + nc];
            float4 cR = *(const float4*)&cChild[cRb + (size_t)b * LDIM + nc];
            float cl4[4] = {cL.x, cL.y, cL.z, cL.w};
            float cr4[4] = {cR.x, cR.y, cR.z, cR.w};
            float4 c4, h4;
            float* cp = (float*)&c4; float* hp = (float*)&h4;
#pragma unroll
            for (int j = 0; j < 4; ++j) {
                float gi = sigmoidf_(acc[0 + half][Nt][j] + bi_[j]);
                float gu = tanhf(acc[2 + half][Nt][j] + bu_[j]);
                float f0 = acc[4 + half][Nt][j] + b0_[j];
                float f1 = acc[6 + half][Nt][j] + b1_[j];
                float c  = gi * gu + f0 * cl4[j] + f1 * cr4[j];
                cp[j] = c;
                hp[j] = tanhf(c);
            }
            *(float4*)&cOut[ob + (size_t)b * LDIM + nc] = c4;
            *(float4*)&hOut[ob + (size_t)b * LDIM + nc] = h4;
        }
    }
}

// ---------------------------------------------------------------------------
// bf16x3 MFMA LEAF kernel (round-12/13 proven): NG=2, NSEG=1, NIT=8.
// grid (512, 8). LDS 46KB -> 3 blocks/CU. In-lane epilogue, float4 stores.
__global__ __launch_bounds__(256, 3) void leaf_mfma(
    const float* __restrict__ x_embed,
    const ushort* __restrict__ Lth, const ushort* __restrict__ Ltm,
    const ushort* __restrict__ Ltl,
    const float* __restrict__ bias_leaf,
    float* __restrict__ hOut, float* __restrict__ cOut)
{
    constexpr int AST = 40;
    __shared__ __align__(16) ushort Wlds[3][64 * AST];
    __shared__ __align__(16) ushort Vlds[3][128 * AST];

    const int tid = threadIdx.x;
    const int ln  = blockIdx.x;                   // leaf-local node 0..511
    const int gy  = blockIdx.y;
    const int lane = tid & 63, wid = tid >> 6;
    const int ni = wid & 1, bw = wid >> 1;
    const int srow = tid & 127, shalf = tid >> 7;
    const int wrow = tid & 63, whalf = (tid >> 6) & 1;

    const float* aX = x_embed + ((size_t)srow * NNODES + (511 + ln)) * LDIM;
    const size_t nbw = (size_t)(((wrow >> 5) << 8) + gy * 32 + (wrow & 31)) * 256;
    const ushort* l0 = Lth + nbw;
    const ushort* l1 = Ltm + nbw;
    const ushort* l2 = Ltl + nbw;

    f32x4 acc[2][4];
#pragma unroll
    for (int g = 0; g < 2; ++g)
#pragma unroll
        for (int t2 = 0; t2 < 4; ++t2) acc[g][t2] = (f32x4){0.f, 0.f, 0.f, 0.f};

    float4 a0, a1, a2, a3;
    int4 w00, w01, w10, w11, w20, w21;

#define LEAF_LOADS(IT)                                                         \
    {                                                                          \
        const float* ap_ = aX + (IT) * 32 + shalf * 16;                        \
        a0 = *(const float4*)(ap_);                                            \
        a1 = *(const float4*)(ap_ + 4);                                        \
        a2 = *(const float4*)(ap_ + 8);                                        \
        a3 = *(const float4*)(ap_ + 12);                                       \
        if (tid < 128) {                                                       \
            const int bko_ = (IT) * 32 + whalf * 16;                           \
            w00 = *(const int4*)(l0 + bko_); w01 = *(const int4*)(l0 + bko_ + 8); \
            w10 = *(const int4*)(l1 + bko_); w11 = *(const int4*)(l1 + bko_ + 8); \
            w20 = *(const int4*)(l2 + bko_); w21 = *(const int4*)(l2 + bko_ + 8); \
        }                                                                      \
    }

    LEAF_LOADS(0);
    for (int it = 0; it < 8; ++it) {
        if (it) __syncthreads();
        {
            P3 p0 = pack2v(a0.x, a0.y), p1 = pack2v(a0.z, a0.w);
            P3 p2 = pack2v(a1.x, a1.y), p3 = pack2v(a1.z, a1.w);
            P3 p4 = pack2v(a2.x, a2.y), p5 = pack2v(a2.z, a2.w);
            P3 p6 = pack2v(a3.x, a3.y), p7 = pack2v(a3.z, a3.w);
            const int base = srow * AST + shalf * 16;
            *(int4*)&Vlds[0][base]     = make_int4((int)p0.h, (int)p1.h, (int)p2.h, (int)p3.h);
            *(int4*)&Vlds[0][base + 8] = make_int4((int)p4.h, (int)p5.h, (int)p6.h, (int)p7.h);
            *(int4*)&Vlds[1][base]     = make_int4((int)p0.m, (int)p1.m, (int)p2.m, (int)p3.m);
            *(int4*)&Vlds[1][base + 8] = make_int4((int)p4.m, (int)p5.m, (int)p6.m, (int)p7.m);
            *(int4*)&Vlds[2][base]     = make_int4((int)p0.l, (int)p1.l, (int)p2.l, (int)p3.l);
            *(int4*)&Vlds[2][base + 8] = make_int4((int)p4.l, (int)p5.l, (int)p6.l, (int)p7.l);
            if (tid < 128) {
                const int bw_ = wrow * AST + whalf * 16;
                *(int4*)&Wlds[0][bw_]     = w00;
                *(int4*)&Wlds[0][bw_ + 8] = w01;
                *(int4*)&Wlds[1][bw_]     = w10;
                *(int4*)&Wlds[1][bw_ + 8] = w11;
                *(int4*)&Wlds[2][bw_]     = w20;
                *(int4*)&Wlds[2][bw_ + 8] = w21;
            }
        }
        __syncthreads();
        if (it + 1 < 8) LEAF_LOADS(it + 1);
        {
            short8 vf[4][3];
#pragma unroll
            for (int Nt = 0; Nt < 4; ++Nt) {
                const int rb = (bw * 64 + Nt * 16 + (lane & 15)) * AST + (lane >> 4) * 8;
#pragma unroll
                for (int s = 0; s < 3; ++s) vf[Nt][s] = *(const short8*)&Vlds[s][rb];
            }
#pragma unroll
            for (int g = 0; g < 2; ++g) {
                const int cb = (g * 32 + ni * 16 + (lane & 15)) * AST + (lane >> 4) * 8;
                short8 wh = *(const short8*)&Wlds[0][cb];
                short8 wm = *(const short8*)&Wlds[1][cb];
                short8 wl = *(const short8*)&Wlds[2][cb];
#pragma unroll
                for (int Nt = 0; Nt < 4; ++Nt)
                    acc[g][Nt] = __builtin_amdgcn_mfma_f32_16x16x32_bf16(wl, vf[Nt][0], acc[g][Nt], 0, 0, 0);
#pragma unroll
                for (int Nt = 0; Nt < 4; ++Nt)
                    acc[g][Nt] = __builtin_amdgcn_mfma_f32_16x16x32_bf16(wh, vf[Nt][2], acc[g][Nt], 0, 0, 0);
#pragma unroll
                for (int Nt = 0; Nt < 4; ++Nt)
                    acc[g][Nt] = __builtin_amdgcn_mfma_f32_16x16x32_bf16(wm, vf[Nt][1], acc[g][Nt], 0, 0, 0);
#pragma unroll
                for (int Nt = 0; Nt < 4; ++Nt)
                    acc[g][Nt] = __builtin_amdgcn_mfma_f32_16x16x32_bf16(wm, vf[Nt][0], acc[g][Nt], 0, 0, 0);
#pragma unroll
                for (int Nt = 0; Nt < 4; ++Nt)
                    acc[g][Nt] = __builtin_amdgcn_mfma_f32_16x16x32_bf16(wh, vf[Nt][1], acc[g][Nt], 0, 0, 0);
#pragma unroll
                for (int Nt = 0; Nt < 4; ++Nt)
                    acc[g][Nt] = __builtin_amdgcn_mfma_f32_16x16x32_bf16(wh, vf[Nt][0], acc[g][Nt], 0, 0, 0);
            }
        }
    }
#undef LEAF_LOADS

    const int nc = gy * 32 + ni * 16 + ((lane >> 4) << 2);
    const size_t ob = (size_t)ln * BATCH * LDIM;
    const float4 bc4 = *(const float4*)&bias_leaf[nc];
    const float4 bo4 = *(const float4*)&bias_leaf[256 + nc];
    const float bc_[4] = {bc4.x, bc4.y, bc4.z, bc4.w};
    const float bo_[4] = {bo4.x, bo4.y, bo4.z, bo4.w};
#pragma unroll
    for (int Nt = 0; Nt < 4; ++Nt) {
        const int b = bw * 64 + Nt * 16 + (lane & 15);
        float4 c4, h4;
        float* cp = (float*)&c4; float* hp = (float*)&h4;
#pragma unroll
        for (int j = 0; j < 4; ++j) {
            float c = acc[0][Nt][j] + bc_[j];
            float o = acc[1][Nt][j] + bo_[j];
            cp[j] = c;
            hp[j] = sigmoidf_(o) * tanhf(c);
        }
        size_t po = ob + (size_t)b * LDIM + nc;
        *(float4*)&cOut[po] = c4;
        *(float4*)&hOut[po] = h4;
    }
}

// ---------------------------------------------------------------------------
// Leaf kernel (fp32 fallback). grid (1024, 4), block 256.
__global__ __launch_bounds__(256) void leaf_kernel(
    const float* __restrict__ x_embed,
    const float* __restrict__ Wleaf, const float* __restrict__ bias_leaf,
    float* __restrict__ hOut, float* __restrict__ cOut)
{
    __shared__ float As[16 * 68];
    __shared__ float Bs[2 * 16 * 64];
    float acc[2][4][4] = {};
    const int tid = threadIdx.x;
    const int ty = tid >> 4, tx = tid & 15;
    const int row0 = blockIdx.x * 64;
    const int n0 = blockIdx.y * 64;
    const int w = row0 >> 7;
    const int ar = tid >> 2;
    const int kq = (tid & 3) * 4;
    const int b = (row0 + ar) & 127;
    const float* xrow = x_embed + ((size_t)b * NNODES + 511 + w) * LDIM;

    for (int k0 = 0; k0 < 256; k0 += 16) {
        float4 av = *(const float4*)(xrow + k0 + kq);
        As[(kq + 0) * 68 + ar] = av.x;
        As[(kq + 1) * 68 + ar] = av.y;
        As[(kq + 2) * 68 + ar] = av.z;
        As[(kq + 3) * 68 + ar] = av.w;
#pragma unroll
        for (int q = 0; q < 2; ++q) {
            int L = q * 256 + tid;
            int g = L >> 8, kk = (L >> 4) & 15, n4 = (L & 15) * 4;
            float4 bv = *(const float4*)(Wleaf + (size_t)(k0 + kk) * 512 + g * 256 + n0 + n4);
            *(float4*)&Bs[(g * 16 + kk) * 64 + n4] = bv;
        }
        __syncthreads();
#pragma unroll
        for (int kk = 0; kk < 16; ++kk) {
            float4 a = *(const float4*)&As[kk * 68 + ty * 4];
            float av4[4] = {a.x, a.y, a.z, a.w};
#pragma unroll
            for (int g = 0; g < 2; ++g) {
                float4 bb = *(const float4*)&Bs[(g * 16 + kk) * 64 + tx * 4];
                float bv4[4] = {bb.x, bb.y, bb.z, bb.w};
#pragma unroll
                for (int ii = 0; ii < 4; ++ii)
#pragma unroll
                    for (int jj = 0; jj < 4; ++jj)
                        acc[g][ii][jj] += av4[ii] * bv4[jj];
            }
        }
        __syncthreads();
    }
#pragma unroll
    for (int ii = 0; ii < 4; ++ii) {
        int r = row0 + ty * 4 + ii;
        int nc = n0 + tx * 4;
        float4 c4, h4;
        float* cp = (float*)&c4; float* hp = (float*)&h4;
#pragma unroll
        for (int jj = 0; jj < 4; ++jj) {
            int n = nc + jj;
            float ac = acc[0][ii][jj] + bias_leaf[n];
            float ao = acc[1][ii][jj] + bias_leaf[256 + n];
            cp[jj] = ac;
            hp[jj] = sigmoidf_(ao) * tanhf(ac);
        }
        *(float4*)&cOut[(size_t)r * LDIM + nc] = c4;
        *(float4*)&hOut[(size_t)r * LDIM + nc] = h4;
    }
}

// ---------------------------------------------------------------------------
// fp32 level kernel (proven fallback). grid (W*2, 4), block 256.
__global__ __launch_bounds__(256) void level_kernel(
    const float* __restrict__ x_embed,
    const float* __restrict__ hChild, const float* __restrict__ cChild,
    const float* __restrict__ Wbig, const float* __restrict__ bias_big,
    float* __restrict__ hOut, float* __restrict__ cOut,
    int nstart)
{
    __shared__ float As[16 * 68];
    __shared__ float Bs[4 * 16 * 64];
    float acc[4][4][4] = {};
    const int tid = threadIdx.x;
    const int ty = tid >> 4, tx = tid & 15;
    const int row0 = blockIdx.x * 64;
    const int n0 = blockIdx.y * 64;
    const int w = row0 >> 7;
    const int ar = tid >> 2;
    const int kq = (tid & 3) * 4;
    const int b = (row0 + ar) & 127;
    const float* srcX = x_embed + ((size_t)b * NNODES + nstart + w) * LDIM;
    const float* srcL = hChild + ((size_t)(2 * w) * BATCH + b) * LDIM;
    const float* srcR = hChild + ((size_t)(2 * w + 1) * BATCH + b) * LDIM;

    for (int k0 = 0; k0 < 768; k0 += 16) {
        int seg = k0 >> 8, off = k0 & 255;
        const float* src = (seg == 0) ? srcX : (seg == 1) ? srcL : srcR;
        float4 av = *(const float4*)(src + off + kq);
        As[(kq + 0) * 68 + ar] = av.x;
        As[(kq + 1) * 68 + ar] = av.y;
        As[(kq + 2) * 68 + ar] = av.z;
        As[(kq + 3) * 68 + ar] = av.w;
#pragma unroll
        for (int q = 0; q < 4; ++q) {
            int L = q * 256 + tid;
            int g = L >> 8, kk = (L >> 4) & 15, n4 = (L & 15) * 4;
            float4 bv = *(const float4*)(Wbig + (size_t)(k0 + kk) * 1024 + g * 256 + n0 + n4);
            *(float4*)&Bs[(g * 16 + kk) * 64 + n4] = bv;
        }
        __syncthreads();
#pragma unroll
        for (int kk = 0; kk < 16; ++kk) {
            float4 a = *(const float4*)&As[kk * 68 + ty * 4];
            float av4[4] = {a.x, a.y, a.z, a.w};
#pragma unroll
            for (int g = 0; g < 4; ++g) {
                float4 bb = *(const float4*)&Bs[(g * 16 + kk) * 64 + tx * 4];
                float bv4[4] = {bb.x, bb.y, bb.z, bb.w};
#pragma unroll
                for (int ii = 0; ii < 4; ++ii)
#pragma unroll
                    for (int jj = 0; jj < 4; ++jj)
                        acc[g][ii][jj] += av4[ii] * bv4[jj];
            }
        }
        __syncthreads();
    }
    const size_t cLbase = ((size_t)(2 * w) * BATCH) * LDIM;
    const size_t cRbase = ((size_t)(2 * w + 1) * BATCH) * LDIM;
#pragma unroll
    for (int ii = 0; ii < 4; ++ii) {
        int r = row0 + ty * 4 + ii;
        int bb2 = r & 127;
        int nc = n0 + tx * 4;
        float4 cL = *(const float4*)&cChild[cLbase + (size_t)bb2 * LDIM + nc];
        float4 cR = *(const float4*)&cChild[cRbase + (size_t)bb2 * LDIM + nc];
        float cl4[4] = {cL.x, cL.y, cL.z, cL.w};
        float cr4[4] = {cR.x, cR.y, cR.z, cR.w};
        float4 c4, h4;
        float* cp = (float*)&c4; float* hp = (float*)&h4;
#pragma unroll
        for (int jj = 0; jj < 4; ++jj) {
            int n = nc + jj;
            float gi = sigmoidf_(acc[0][ii][jj] + bias_big[n]);
            float gu = tanhf(acc[1][ii][jj] + bias_big[256 + n]);
            float f0 = acc[2][ii][jj] + bias_big[512 + n];
            float f1 = acc[3][ii][jj] + bias_big[768 + n];
            float c = gi * gu + f0 * cl4[jj] + f1 * cr4[jj];
            cp[jj] = c;
            hp[jj] = tanhf(c);
        }
        *(float4*)&cOut[(size_t)r * LDIM + nc] = c4;
        *(float4*)&hOut[(size_t)r * LDIM + nc] = h4;
    }
}

// ---------------------------------------------------------------------------
// Split-K partial (TM=4, one 256-wide K segment per blockIdx.z). grid (W*2,4,3).
__global__ __launch_bounds__(256) void gemm_part4(
    const float* __restrict__ x_embed, const float* __restrict__ hChild,
    const float* __restrict__ Wbig,
    float* __restrict__ part, int nstart, int rowsTotal)
{
    __shared__ float As[16 * 68];
    __shared__ float Bs[4 * 16 * 64];
    float acc[4][4][4] = {};
    const int tid = threadIdx.x;
    const int ty = tid >> 4, tx = tid & 15;
    const int row0 = blockIdx.x * 64;
    const int n0 = blockIdx.y * 64;
    const int seg = blockIdx.z;
    const int w = row0 >> 7;
    const int ar = tid >> 2;
    const int kq = (tid & 3) * 4;
    const int b = (row0 + ar) & 127;
    const float* src =
        (seg == 0) ? x_embed + ((size_t)b * NNODES + nstart + w) * LDIM
                   : hChild + ((size_t)(2 * w + (seg - 1)) * BATCH + b) * LDIM;

    for (int k0 = 0; k0 < 256; k0 += 16) {
        float4 av = *(const float4*)(src + k0 + kq);
        As[(kq + 0) * 68 + ar] = av.x;
        As[(kq + 1) * 68 + ar] = av.y;
        As[(kq + 2) * 68 + ar] = av.z;
        As[(kq + 3) * 68 + ar] = av.w;
#pragma unroll
        for (int q = 0; q < 4; ++q) {
            int L = q * 256 + tid;
            int g = L >> 8, kk = (L >> 4) & 15, n4 = (L & 15) * 4;
            float4 bv = *(const float4*)(Wbig + (size_t)(seg * 256 + k0 + kk) * 1024
                                         + g * 256 + n0 + n4);
            *(float4*)&Bs[(g * 16 + kk) * 64 + n4] = bv;
        }
        __syncthreads();
#pragma unroll
        for (int kk = 0; kk < 16; ++kk) {
            float4 a = *(const float4*)&As[kk * 68 + ty * 4];
            float av4[4] = {a.x, a.y, a.z, a.w};
#pragma unroll
            for (int g = 0; g < 4; ++g) {
                float4 bb = *(const float4*)&Bs[(g * 16 + kk) * 64 + tx * 4];
                float bv4[4] = {bb.x, bb.y, bb.z, bb.w};
#pragma unroll
                for (int ii = 0; ii < 4; ++ii)
#pragma unroll
                    for (int jj = 0; jj < 4; ++jj)
                        acc[g][ii][jj] += av4[ii] * bv4[jj];
            }
        }
        __syncthreads();
    }
#pragma unroll
    for (int ii = 0; ii < 4; ++ii) {
        int r = row0 + ty * 4 + ii;
        size_t base = ((size_t)seg * rowsTotal + r) * 1024 + n0 + tx * 4;
#pragma unroll
        for (int g = 0; g < 4; ++g)
            *(float4*)&part[base + g * 256] = *(float4*)acc[g][ii];
    }
}

// ---------------------------------------------------------------------------
// Combine 3 split-K partials + LSTM epilogue. grid (rows/4), block 256.
__global__ __launch_bounds__(256) void combine_eps(
    const float* __restrict__ part, const float* __restrict__ cChild,
    const float* __restrict__ bias,
    float* __restrict__ hOut, float* __restrict__ cOut, int rowsTotal)
{
    int idx = blockIdx.x * 256 + threadIdx.x;
    int row = idx >> 6, n = (idx & 63) * 4;
    size_t sseg = (size_t)rowsTotal * 1024;
    const float* p0 = part + (size_t)row * 1024 + n;
    float s[4][4];
#pragma unroll
    for (int g = 0; g < 4; ++g) {
        float4 a = *(const float4*)(p0 + g * 256);
        float4 b = *(const float4*)(p0 + sseg + g * 256);
        float4 c = *(const float4*)(p0 + 2 * sseg + g * 256);
        s[g][0] = a.x + b.x + c.x; s[g][1] = a.y + b.y + c.y;
        s[g][2] = a.z + b.z + c.z; s[g][3] = a.w + b.w + c.w;
    }
    int node = row >> 7, b = row & 127;
    float4 cL = *(const float4*)&cChild[((size_t)(2 * node) * BATCH + b) * LDIM + n];
    float4 cR = *(const float4*)&cChild[((size_t)(2 * node + 1) * BATCH + b) * LDIM + n];
    float cl4[4] = {cL.x, cL.y, cL.z, cL.w};
    float cr4[4] = {cR.x, cR.y, cR.z, cR.w};
    float4 c4, h4;
    float* cp = (float*)&c4; float* hp = (float*)&h4;
#pragma unroll
    for (int jj = 0; jj < 4; ++jj) {
        int nn = n + jj;
        float gi = sigmoidf_(s[0][jj] + bias[nn]);
        float gu = tanhf(s[1][jj] + bias[256 + nn]);
        float f0 = s[2][jj] + bias[512 + nn];
        float f1 = s[3][jj] + bias[768 + nn];
        float c = gi * gu + f0 * cl4[jj] + f1 * cr4[jj];
        cp[jj] = c;
        hp[jj] = tanhf(c);
    }
    *(float4*)&cOut[(size_t)row * LDIM + n] = c4;
    *(float4*)&hOut[(size_t)row * LDIM + n] = h4;
}

// ---------------------------------------------------------------------------
// Final: out[b][n] = tanh([init | c_root | h_root] @ Woend + boend). grid 128.
__global__ __launch_bounds__(256) void final_kernel(
    const float* __restrict__ init_emb,
    const float* __restrict__ cRoot, const float* __restrict__ hRoot,
    const float* __restrict__ Woend, const float* __restrict__ boend,
    float* __restrict__ out)
{
    __shared__ float sv[768];
    int b = blockIdx.x, t = threadIdx.x;
    sv[t]       = init_emb[(size_t)b * 256 + t];
    sv[256 + t] = cRoot[(size_t)b * 256 + t];
    sv[512 + t] = hRoot[(size_t)b * 256 + t];
    __syncthreads();
    float acc = boend[t];
#pragma unroll 4
    for (int d = 0; d < 768; ++d)
        acc += sv[d] * Woend[(size_t)d * 256 + t];
    out[(size_t)b * 256 + t] = tanhf(acc);
}

// ---------------------------------------------------------------------------
extern "C" void kernel_launch(void* const* d_in, const int* in_sizes, int n_in,
                              void* d_out, int out_size, void* d_ws, size_t ws_size,
                              hipStream_t stream)
{
    const float* x_embed  = (const float*)d_in[0];
    const float* init_emb = (const float*)d_in[1];
    const float* Wcx = (const float*)d_in[2];  const float* bcx = (const float*)d_in[3];
    const float* Wox = (const float*)d_in[4];  const float* box = (const float*)d_in[5];
    const float* Wix = (const float*)d_in[6];  const float* bix = (const float*)d_in[7];
    const float* Wfx = (const float*)d_in[8];  const float* bfx = (const float*)d_in[9];
    const float* Wux = (const float*)d_in[10]; const float* bux = (const float*)d_in[11];
    const float* Wi  = (const float*)d_in[12]; const float* bi  = (const float*)d_in[13];
    const float* Wf  = (const float*)d_in[14]; const float* bf  = (const float*)d_in[15];
    const float* Wu  = (const float*)d_in[16]; const float* bu  = (const float*)d_in[17];
    const float* Woend = (const float*)d_in[18]; const float* boend = (const float*)d_in[19];
    float* out = (float*)d_out;
    float* ws  = (float*)d_ws;

    size_t off = 0;
    float* hA = ws + off; off += (size_t)512 * 128 * 256;
    float* cA = ws + off; off += (size_t)512 * 128 * 256;
    float* hB = ws + off; off += (size_t)256 * 128 * 256;
    float* cB = ws + off; off += (size_t)256 * 128 * 256;
    float* Wbig      = ws + off; off += (size_t)768 * 1024;
    float* bias_big  = ws + off; off += 1024;
    float* Wleaf     = ws + off; off += (size_t)256 * 512;
    float* bias_leaf = ws + off; off += 512;
    // bf16 weight splits, transposed [n][k]
    ushort* Wth = (ushort*)(ws + off); off += (size_t)768 * 1024 / 2;
    ushort* Wtm = (ushort*)(ws + off); off += (size_t)768 * 1024 / 2;
    ushort* Wtl = (ushort*)(ws + off); off += (size_t)768 * 1024 / 2;
    // leaf weight splits, transposed [n=512][k=256]
    ushort* Lth = (ushort*)(ws + off); off += (size_t)512 * 256 / 2;
    ushort* Ltm = (ushort*)(ws + off); off += (size_t)512 * 256 / 2;
    ushort* Ltl = (ushort*)(ws + off); off += (size_t)512 * 256 / 2;
    size_t mfma_need = off * sizeof(float);
    size_t part_off = off;
    float* part = ws + part_off;

    bool mfma_ok = mfma_need <= ws_size;

    {
        int total = 768 * 1024 + 1024 + 256 * 512 + 512;
        int blocks = (total + 255) / 256;
        build_weights<<<blocks, 256, 0, stream>>>(
            Wix, bix, Wfx, bfx, Wux, bux, Wi, bi, Wf, bf, Wu, bu,
            Wcx, bcx, Wox, box, Wbig, bias_big, Wleaf, bias_leaf);
    }
    if (mfma_ok) {
        split_weights_T<<<dim3(24, 32), 256, 0, stream>>>(Wbig, Wth, Wtm, Wtl);
        split_wleaf_T<<<dim3(8, 16), 256, 0, stream>>>(Wleaf, Lth, Ltm, Ltl);
    }

    if (mfma_ok) {
        leaf_mfma<<<dim3(512, 8), 256, 0, stream>>>(
            x_embed, Lth, Ltm, Ltl, bias_leaf, hA, cA);
    } else {
        leaf_kernel<<<dim3(1024, 4), 256, 0, stream>>>(
            x_embed, Wleaf, bias_leaf, hA, cA);
    }

    float* hbufs[2] = {hA, hB};
    float* cbufs[2] = {cA, cB};
    int child = 0;  // leaves in A
    for (int lvl = 8; lvl >= 0; --lvl) {
        int W = 1 << lvl, s = W - 1;
        int outb = child ^ 1;
        size_t rows = (size_t)W * 128;
        bool split = (W <= 16) &&
                     ((part_off + 3 * rows * 1024) * sizeof(float) <= ws_size);
        if (lvl >= 5 && mfma_ok) {
            mfma_level_pack<<<dim3(W, 8), 256, 0, stream>>>(
                x_embed, hbufs[child], cbufs[child], Wth, Wtm, Wtl, bias_big,
                hbufs[outb], cbufs[outb], s);
        } else if (split) {
            gemm_part4<<<dim3(W * 2, 4, 3), 256, 0, stream>>>(
                x_embed, hbufs[child], Wbig, part, s, (int)rows);
            combine_eps<<<(int)(rows / 4), 256, 0, stream>>>(
                part, cbufs[child], bias_big, hbufs[outb], cbufs[outb], (int)rows);
        } else {
            level_kernel<<<dim3(W * 2, 4), 256, 0, stream>>>(
                x_embed, hbufs[child], cbufs[child], Wbig, bias_big,
                hbufs[outb], cbufs[outb], s);
        }
        child = outb;
    }

    final_kernel<<<128, 256, 0, stream>>>(init_emb, cbufs[child], hbufs[child],
                                          Woend, boend, out);
}